// Round 2
// baseline (10073.844 us; speedup 1.0000x reference)
//
#include <hip/hip_runtime.h>

// ---------------------------------------------------------------------------
// TransMIL forward, f32 correctness-first baseline (round 2: fits in <193MiB ws).
// Shapes: B=1, N=16384, IN=1024, C=512, heads=8, dh=64, tokens NT=16385,
// padded NP=16640, landmarks M=256, l=65, pinv iters=6, res conv k=33.
// ---------------------------------------------------------------------------

#define NT 16385
#define NP 16640
#define PAD 255
#define CDIM 512
#define HEADS 8
#define DH 64
#define LM 256
#define LSEG 65

// ---------------- reductions ----------------
__device__ __forceinline__ float wredSum(float v){
#pragma unroll
  for (int o = 32; o > 0; o >>= 1) v += __shfl_xor(v, o, 64);
  return v;
}
__device__ __forceinline__ float wredMax(float v){
#pragma unroll
  for (int o = 32; o > 0; o >>= 1) v = fmaxf(v, __shfl_xor(v, o, 64));
  return v;
}
// block of 256 threads
__device__ __forceinline__ float bredSum(float v, float* sm){
  v = wredSum(v);
  int w = threadIdx.x >> 6, l = threadIdx.x & 63;
  __syncthreads();
  if (l == 0) sm[w] = v;
  __syncthreads();
  return sm[0] + sm[1] + sm[2] + sm[3];
}
__device__ __forceinline__ float bredMax(float v, float* sm){
  v = wredMax(v);
  int w = threadIdx.x >> 6, l = threadIdx.x & 63;
  __syncthreads();
  if (l == 0) sm[w] = v;
  __syncthreads();
  return fmaxf(fmaxf(sm[0], sm[1]), fmaxf(sm[2], sm[3]));
}

// ---------------- utility ----------------
__global__ __launch_bounds__(256) void zero_k(float* __restrict__ p, long long n){
  long long i = (long long)blockIdx.x * 256 + threadIdx.x;
  long long stride = (long long)gridDim.x * 256;
  for (; i < n; i += stride) p[i] = 0.f;
}
__global__ __launch_bounds__(256) void copy_cls_k(const float* __restrict__ cls,
                                                  float* __restrict__ h){
  h[threadIdx.x] = cls[threadIdx.x];
  h[threadIdx.x + 256] = cls[threadIdx.x + 256];
}

// ---------------- generic GEMM ----------------
#define GF_TRANSB 1
#define GF_RELU   2
#define GF_ACCUM  4

__global__ __launch_bounds__(256) void gemm_k(
    const float* __restrict__ A, const float* __restrict__ B, float* __restrict__ C,
    int M, int N, int K, int lda, int ldb, int ldc,
    long long sA, long long sB, long long sC,
    const float* __restrict__ bias,
    const float* __restrict__ rowdiv, int sRow,
    float alpha, int flags, int ksplit)
{
  __shared__ __align__(16) float As[16][68];
  __shared__ __align__(16) float Bs[16][68];
  int zb = blockIdx.z / ksplit;
  int ks = blockIdx.z - zb * ksplit;
  A += (long long)zb * sA; B += (long long)zb * sB; C += (long long)zb * sC;
  int klen = K / ksplit;
  int kbeg = ks * klen, kend = kbeg + klen;
  int tid = threadIdx.x;
  int tx = tid & 15, ty = tid >> 4;
  int row0 = blockIdx.y * 64, col0 = blockIdx.x * 64;
  float acc[4][4] = {};
  for (int k0 = kbeg; k0 < kend; k0 += 16){
#pragma unroll
    for (int i = 0; i < 4; i++){
      int idx = tid + i * 256;
      int mm = idx >> 4, kk = idx & 15;
      int gm = row0 + mm;
      As[kk][mm] = (gm < M) ? A[(long long)gm * lda + (k0 + kk)] : 0.f;
    }
    if (!(flags & GF_TRANSB)){
#pragma unroll
      for (int i = 0; i < 4; i++){
        int idx = tid + i * 256;
        int kk = idx >> 6, nn = idx & 63;
        int gn = col0 + nn;
        Bs[kk][nn] = (gn < N) ? B[(long long)(k0 + kk) * ldb + gn] : 0.f;
      }
    } else {
#pragma unroll
      for (int i = 0; i < 4; i++){
        int idx = tid + i * 256;
        int nn = idx >> 4, kk = idx & 15;
        int gn = col0 + nn;
        Bs[kk][nn] = (gn < N) ? B[(long long)gn * ldb + (k0 + kk)] : 0.f;
      }
    }
    __syncthreads();
#pragma unroll
    for (int kk = 0; kk < 16; kk++){
      float4 av = *(const float4*)&As[kk][ty * 4];
      float4 bv = *(const float4*)&Bs[kk][tx * 4];
      float a[4] = {av.x, av.y, av.z, av.w};
      float b[4] = {bv.x, bv.y, bv.z, bv.w};
#pragma unroll
      for (int i = 0; i < 4; i++)
#pragma unroll
        for (int j = 0; j < 4; j++)
          acc[i][j] = fmaf(a[i], b[j], acc[i][j]);
    }
    __syncthreads();
  }
#pragma unroll
  for (int i = 0; i < 4; i++){
    int gm = row0 + ty * 4 + i;
    if (gm >= M) continue;
    float rd = rowdiv ? rowdiv[(long long)zb * sRow + gm] : 1.f;
#pragma unroll
    for (int j = 0; j < 4; j++){
      int gn = col0 + tx * 4 + j;
      if (gn >= N) continue;
      float v = alpha * acc[i][j];
      if (rowdiv) v /= rd;
      if (bias) v += bias[gn];
      if (flags & GF_RELU) v = fmaxf(v, 0.f);
      long long cidx = (long long)gm * ldc + gn;
      if (ksplit > 1) atomicAdd(&C[cidx], v);
      else if (flags & GF_ACCUM) C[cidx] += v;
      else C[cidx] = v;
    }
  }
}

// ---------------- batched 256x256x256 GEMM for pinv ----------------
// C = dterm*I + sterm*(A@B) + eterm*A   (per head, stride 65536)
__global__ __launch_bounds__(256) void bgemm256_k(
    const float* __restrict__ A, const float* __restrict__ B, float* __restrict__ C,
    float dterm, float sterm, float eterm)
{
  __shared__ __align__(16) float As[16][68];
  __shared__ __align__(16) float Bs[16][68];
  long long off = (long long)blockIdx.z << 16;
  A += off; B += off; C += off;
  int tid = threadIdx.x;
  int tx = tid & 15, ty = tid >> 4;
  int row0 = blockIdx.y * 64, col0 = blockIdx.x * 64;
  float acc[4][4] = {};
  for (int k0 = 0; k0 < 256; k0 += 16){
#pragma unroll
    for (int i = 0; i < 4; i++){
      int idx = tid + i * 256;
      int mm = idx >> 4, kk = idx & 15;
      As[kk][mm] = A[(row0 + mm) * 256 + k0 + kk];
    }
#pragma unroll
    for (int i = 0; i < 4; i++){
      int idx = tid + i * 256;
      int kk = idx >> 6, nn = idx & 63;
      Bs[kk][nn] = B[(k0 + kk) * 256 + col0 + nn];
    }
    __syncthreads();
#pragma unroll
    for (int kk = 0; kk < 16; kk++){
      float4 av = *(const float4*)&As[kk][ty * 4];
      float4 bv = *(const float4*)&Bs[kk][tx * 4];
      float a[4] = {av.x, av.y, av.z, av.w};
      float b[4] = {bv.x, bv.y, bv.z, bv.w};
#pragma unroll
      for (int i = 0; i < 4; i++)
#pragma unroll
        for (int j = 0; j < 4; j++)
          acc[i][j] = fmaf(a[i], b[j], acc[i][j]);
    }
    __syncthreads();
  }
#pragma unroll
  for (int i = 0; i < 4; i++){
    int gm = row0 + ty * 4 + i;
#pragma unroll
    for (int j = 0; j < 4; j++){
      int gn = col0 + tx * 4 + j;
      float v = sterm * acc[i][j] + eterm * A[gm * 256 + gn];
      if (gm == gn) v += dterm;
      C[gm * 256 + gn] = v;
    }
  }
}

// ---------------- layernorm + front-pad into xq (NP x 512) ----------------
__global__ __launch_bounds__(256) void ln_pad_k(
    const float* __restrict__ h, const float* __restrict__ g,
    const float* __restrict__ b, float* __restrict__ out)
{
  __shared__ float sm[4];
  int row = blockIdx.x, tid = threadIdx.x;
  float* o = out + (long long)row * CDIM;
  if (row < PAD){ o[tid] = 0.f; o[tid + 256] = 0.f; return; }
  const float* x = h + (long long)(row - PAD) * CDIM;
  float v0 = x[tid], v1 = x[tid + 256];
  float s = bredSum(v0 + v1, sm);
  float s2 = bredSum(v0 * v0 + v1 * v1, sm);
  float mean = s * (1.f / 512.f);
  float var = s2 * (1.f / 512.f) - mean * mean;
  float rstd = rsqrtf(var + 1e-5f);
  o[tid] = (v0 - mean) * rstd * g[tid] + b[tid];
  o[tid + 256] = (v1 - mean) * rstd * g[tid + 256] + b[tid + 256];
}

// ---------------- landmark means (q scaled by 1/8) ----------------
__global__ __launch_bounds__(64) void landmark_k(
    const float* __restrict__ qkv, float* __restrict__ ql, float* __restrict__ kl)
{
  int m = blockIdx.x, h = blockIdx.y, d = threadIdx.x;
  const float* base = qkv + (long long)(m * LSEG) * 1536 + h * DH + d;
  float sq = 0.f, sk = 0.f;
  for (int j = 0; j < LSEG; j++){
    sq += base[(long long)j * 1536];
    sk += base[(long long)j * 1536 + 512];
  }
  ql[(h * LM + m) * DH + d] = sq * (0.125f / 65.f);
  kl[(h * LM + m) * DH + d] = sk * (1.f / 65.f);
}

// ---------------- softmax over rows of 256 (in place) ----------------
__global__ __launch_bounds__(256) void softmax256_k(float* __restrict__ S)
{
  __shared__ float sm[4];
  int i = blockIdx.x, h = blockIdx.y, j = threadIdx.x;
  float* row = S + ((long long)h * LM + i) * 256;
  float v = row[j];
  float m = bredMax(v, sm);
  float e = __expf(v - m);
  float s = bredSum(e, sm);
  row[j] = e / s;
}

// ---------------- row exp (stable) + rowsum, arbitrary ncols ----------------
__global__ __launch_bounds__(256) void rowexp_k(
    float* __restrict__ S, float* __restrict__ rowsum, int ncols)
{
  __shared__ float sm[4];
  int row = blockIdx.x, tid = threadIdx.x;
  float* r = S + (long long)row * ncols;
  float lm = -3.0e38f;
  for (int j = tid; j < ncols; j += 256) lm = fmaxf(lm, r[j]);
  float m = bredMax(lm, sm);
  float ls = 0.f;
  for (int j = tid; j < ncols; j += 256){
    float e = __expf(r[j] - m);
    r[j] = e;
    ls += e;
  }
  float s = bredSum(ls, sm);
  if (tid == 0) rowsum[row] = s;
}

// ---------------- pinv scale factors ----------------
__global__ __launch_bounds__(256) void pinv_scal_k(
    const float* __restrict__ a2, float* __restrict__ scal)
{
  __shared__ float sm[4];
  int h = blockIdx.x, i = threadIdx.x;
  const float* Ah = a2 + (long long)h * 65536;
  float rs = 0.f, cs = 0.f;
  for (int j = 0; j < 256; j++){
    rs += fabsf(Ah[i * 256 + j]);
    cs += fabsf(Ah[j * 256 + i]);
  }
  float rmax = bredMax(rs, sm);
  __syncthreads();
  float cmax = bredMax(cs, sm);
  if (i == 0){
    atomicMax((int*)&scal[0], __float_as_int(rmax));
    atomicMax((int*)&scal[1], __float_as_int(cmax));
  }
}

// z0 = a2^T / (scal0*scal1)
__global__ __launch_bounds__(256) void z0_k(
    const float* __restrict__ a2, float* __restrict__ z, const float* __restrict__ scal)
{
  int j = blockIdx.x, h = blockIdx.y, i = threadIdx.x;
  float inv = 1.f / (scal[0] * scal[1]);
  z[((long long)h * LM + j) * 256 + i] = a2[((long long)h * LM + i) * 256 + j] * inv;
}

// ---------------- depthwise 33-tap residual conv on v, added into attn ------
__global__ __launch_bounds__(256) void resconv_k(
    const float* __restrict__ qkv, const float* __restrict__ rw,
    float* __restrict__ attn)
{
  int c = blockIdx.x * 256 + threadIdx.x;   // 0..511
  int s0 = blockIdx.y * 8;
  int h = c >> 6;
  float w[33];
#pragma unroll
  for (int t = 0; t < 33; t++) w[t] = rw[h * 33 + t];
  float acc[8] = {};
  for (int t = 0; t < 40; t++){
    int s = s0 - 16 + t;
    float v = (s >= 0 && s < NP) ? qkv[(long long)s * 1536 + 1024 + c] : 0.f;
    int ilo = t - 32; if (ilo < 0) ilo = 0;
    int ihi = t; if (ihi > 7) ihi = 7;
    for (int i = ilo; i <= ihi; i++) acc[i] = fmaf(v, w[t - i], acc[i]);
  }
#pragma unroll
  for (int i = 0; i < 8; i++)
    attn[(long long)(s0 + i) * CDIM + c] += acc[i];
}

// ---------------- 32x32 tiled transpose: out[c][r] = in[r][c] ----------------
__global__ __launch_bounds__(256) void transpose_k(
    const float* __restrict__ in, float* __restrict__ out, int R, int Cc)
{
  __shared__ float t[32][33];
  int bx = blockIdx.x * 32, by = blockIdx.y * 32;
  int x = threadIdx.x & 31, y4 = threadIdx.x >> 5;
  for (int yy = y4; yy < 32; yy += 8){
    int r = by + yy, c = bx + x;
    if (r < R && c < Cc) t[yy][x] = in[(long long)r * Cc + c];
  }
  __syncthreads();
  for (int yy = y4; yy < 32; yy += 8){
    int r = bx + yy, c = by + x;
    if (r < Cc && c < R) out[(long long)r * R + c] = t[x][yy];
  }
}

// ---------------- fused PPEG: y = x + dw7 + dw5 + dw3 (+biases) -------------
__global__ __launch_bounds__(256) void ppeg_k(
    const float* __restrict__ cf, float* __restrict__ yt,
    const float* __restrict__ w7, const float* __restrict__ b7,
    const float* __restrict__ w5, const float* __restrict__ b5,
    const float* __restrict__ w3, const float* __restrict__ b3)
{
  __shared__ float tile[22][23];
  int c = blockIdx.z;
  int ty0 = blockIdx.y * 16, tx0 = blockIdx.x * 16;
  const float* img = cf + (long long)c * 16384;
  for (int i = threadIdx.x; i < 22 * 22; i += 256){
    int yy = i / 22, xx = i - yy * 22;
    int gy = ty0 - 3 + yy, gx = tx0 - 3 + xx;
    tile[yy][xx] = (gy >= 0 && gy < 128 && gx >= 0 && gx < 128) ? img[gy * 128 + gx] : 0.f;
  }
  __syncthreads();
  int lx = threadIdx.x & 15, ly = threadIdx.x >> 4;
  float o = tile[ly + 3][lx + 3] + b7[c] + b5[c] + b3[c];
  const float* W7 = w7 + c * 49;
#pragma unroll
  for (int ky = 0; ky < 7; ky++)
#pragma unroll
    for (int kx = 0; kx < 7; kx++)
      o = fmaf(tile[ly + ky][lx + kx], W7[ky * 7 + kx], o);
  const float* W5 = w5 + c * 25;
#pragma unroll
  for (int ky = 0; ky < 5; ky++)
#pragma unroll
    for (int kx = 0; kx < 5; kx++)
      o = fmaf(tile[ly + 1 + ky][lx + 1 + kx], W5[ky * 5 + kx], o);
  const float* W3 = w3 + c * 9;
#pragma unroll
  for (int ky = 0; ky < 3; ky++)
#pragma unroll
    for (int kx = 0; kx < 3; kx++)
      o = fmaf(tile[ly + 2 + ky][lx + 2 + kx], W3[ky * 3 + kx], o);
  yt[(long long)c * 16384 + (ty0 + ly) * 128 + (tx0 + lx)] = o;
}

// ---------------- final: LN(h[0]) @ fc2 + b ----------------
__global__ __launch_bounds__(256) void final_k(
    const float* __restrict__ h, const float* __restrict__ g,
    const float* __restrict__ b, const float* __restrict__ w,
    const float* __restrict__ bias, float* __restrict__ out)
{
  __shared__ float sm[4];
  __shared__ float pj[256][4];
  int tid = threadIdx.x;
  float v0 = h[tid], v1 = h[tid + 256];
  float s = bredSum(v0 + v1, sm);
  float s2 = bredSum(v0 * v0 + v1 * v1, sm);
  float mean = s * (1.f / 512.f);
  float var = s2 * (1.f / 512.f) - mean * mean;
  float rstd = rsqrtf(var + 1e-5f);
  float n0 = (v0 - mean) * rstd * g[tid] + b[tid];
  float n1 = (v1 - mean) * rstd * g[tid + 256] + b[tid + 256];
#pragma unroll
  for (int j = 0; j < 4; j++)
    pj[tid][j] = n0 * w[tid * 4 + j] + n1 * w[(tid + 256) * 4 + j];
  __syncthreads();
  if (tid < 4){
    float acc = 0.f;
    for (int k = 0; k < 256; k++) acc += pj[k][tid];
    out[tid] = acc + bias[tid];
  }
}

// ===========================================================================
// host side
// ===========================================================================
static inline void gemm(hipStream_t st, const float* A, const float* B, float* C,
                        int M, int N, int K, int lda, int ldb, int ldc,
                        long long sA, long long sB, long long sC, int batch,
                        const float* bias, const float* rowdiv, int sRow,
                        float alpha, int flags, int ksplit)
{
  dim3 grid((N + 63) / 64, (M + 63) / 64, batch * ksplit);
  gemm_k<<<grid, 256, 0, st>>>(A, B, C, M, N, K, lda, ldb, ldc, sA, sB, sC,
                               bias, rowdiv, sRow, alpha, flags, ksplit);
}

// workspace offsets (floats) — total 50,414,594 floats = 192.3 MiB
#define OFF_H    0LL
#define OFF_QKV  8389120LL
#define OFF_XQ   33948160LL          /* also attn */
#define OFF_SH   42467840LL          /* per-head S slab (LM*NP) */
#define OFF_QL   46727680LL
#define OFF_KL   46858752LL
#define OFF_A2   46989824LL
#define OFF_Z0   47514112LL
#define OFF_Z1   48038400LL
#define OFF_AZ   48562688LL
#define OFF_TA   49086976LL
#define OFF_TB   49611264LL
#define OFF_A3V  50135552LL
#define OFF_Z2   50266624LL
#define OFF_RS3  50397696LL
#define OFF_RS1  50397952LL
#define OFF_SCAL 50414592LL
#define WS_REQ_FLOATS 50414594LL

extern "C" void kernel_launch(void* const* d_in, const int* in_sizes, int n_in,
                              void* d_out, int out_size, void* d_ws, size_t ws_size,
                              hipStream_t stream)
{
  (void)in_sizes; (void)n_in; (void)out_size;
  // diagnostic guard: if workspace is too small, fail cleanly (absmax) not crash
  if (ws_size < (size_t)(WS_REQ_FLOATS * 4)) return;

  const float* x      = (const float*)d_in[0];
  const float* fc1_w  = (const float*)d_in[1];
  const float* fc1_b  = (const float*)d_in[2];
  const float* cls    = (const float*)d_in[3];
  const float* l_ng[2]  = {(const float*)d_in[4],  (const float*)d_in[10]};
  const float* l_nb[2]  = {(const float*)d_in[5],  (const float*)d_in[11]};
  const float* l_qkv[2] = {(const float*)d_in[6],  (const float*)d_in[12]};
  const float* l_ow[2]  = {(const float*)d_in[7],  (const float*)d_in[13]};
  const float* l_ob[2]  = {(const float*)d_in[8],  (const float*)d_in[14]};
  const float* l_rw[2]  = {(const float*)d_in[9],  (const float*)d_in[15]};
  const float* w7 = (const float*)d_in[16];
  const float* b7 = (const float*)d_in[17];
  const float* w5 = (const float*)d_in[18];
  const float* b5 = (const float*)d_in[19];
  const float* w3 = (const float*)d_in[20];
  const float* b3 = (const float*)d_in[21];
  const float* norm_g = (const float*)d_in[22];
  const float* norm_b = (const float*)d_in[23];
  const float* fc2_w  = (const float*)d_in[24];
  const float* fc2_b  = (const float*)d_in[25];
  float* out = (float*)d_out;

  float* W    = (float*)d_ws;
  float* h    = W + OFF_H;
  float* qkv  = W + OFF_QKV;
  float* xq   = W + OFF_XQ;
  float* attn = W + OFF_XQ;               // alias: xq dead once qkv computed
  float* Sh   = W + OFF_SH;               // per-head score slab
  float* cf   = W + OFF_QKV;              // alias: qkv dead when PPEG runs
  float* yt   = W + OFF_QKV + 8388608LL;
  float* ql   = W + OFF_QL;
  float* kl   = W + OFF_KL;
  float* a2   = W + OFF_A2;
  float* z0b  = W + OFF_Z0;
  float* z1b  = W + OFF_Z1;
  float* az   = W + OFF_AZ;
  float* tA   = W + OFF_TA;
  float* tB   = W + OFF_TB;
  float* a3v  = W + OFF_A3V;
  float* Z2   = W + OFF_Z2;
  float* rs3  = W + OFF_RS3;
  float* rs1  = W + OFF_RS1;
  float* scal = W + OFF_SCAL;

  // h[0] = cls token; h[1..] = relu(x @ fc1_w + fc1_b)
  copy_cls_k<<<1, 256, 0, stream>>>(cls, h);
  gemm(stream, x, fc1_w, h + CDIM, 16384, CDIM, 1024, 1024, CDIM, CDIM,
       0, 0, 0, 1, fc1_b, nullptr, 0, 1.f, GF_RELU, 1);

  for (int L = 0; L < 2; L++){
    // xq = pad( layernorm(h) )
    ln_pad_k<<<NP, 256, 0, stream>>>(h, l_ng[L], l_nb[L], xq);
    // qkv = xq @ qkv_w
    gemm(stream, xq, l_qkv[L], qkv, NP, 1536, CDIM, CDIM, 1536, 1536,
         0, 0, 0, 1, nullptr, nullptr, 0, 1.f, 0, 1);
    // landmarks
    landmark_k<<<dim3(LM, HEADS), 64, 0, stream>>>(qkv, ql, kl);
    // a2 = softmax(ql @ kl^T)
    gemm(stream, ql, kl, a2, LM, LM, DH, DH, DH, LM,
         16384, 16384, 65536, HEADS, nullptr, nullptr, 0, 1.f, GF_TRANSB, 1);
    softmax256_k<<<dim3(LM, HEADS), 256, 0, stream>>>(a2);
    // pinv init
    zero_k<<<1, 256, 0, stream>>>(scal, 2);
    pinv_scal_k<<<HEADS, 256, 0, stream>>>(a2, scal);
    z0_k<<<dim3(LM, HEADS), 256, 0, stream>>>(a2, z0b, scal);
    // 6 Newton-Schulz iterations
    float* zc = z0b; float* za = z1b;
    dim3 bg(4, 4, HEADS);
    for (int it = 0; it < 6; it++){
      bgemm256_k<<<bg, 256, 0, stream>>>(a2, zc, az, 0.f, 1.f, 0.f);        // az = a2@z
      bgemm256_k<<<bg, 256, 0, stream>>>(az, az, tA, 15.f, 1.f, -7.f);      // tA = 15I -7az + az@az
      bgemm256_k<<<bg, 256, 0, stream>>>(az, tA, tB, 13.f, -1.f, 0.f);      // tB = 13I - az@tA
      bgemm256_k<<<bg, 256, 0, stream>>>(zc, tB, za, 0.f, 0.25f, 0.f);      // z' = 0.25 z@tB
      float* tmp = zc; zc = za; za = tmp;
    }
    // ---- per-head: a3v = softmax(ql @ k^T) @ v ----
    zero_k<<<128, 256, 0, stream>>>(a3v, (long long)HEADS * LM * DH);
    for (int hh = 0; hh < HEADS; hh++){
      gemm(stream, ql + hh * 16384, qkv + 512 + hh * 64, Sh, LM, NP, DH,
           DH, 1536, NP, 0, 0, 0, 1, nullptr, nullptr, 0, 1.f, GF_TRANSB, 1);
      rowexp_k<<<LM, 256, 0, stream>>>(Sh, rs3, NP);
      gemm(stream, Sh, qkv + 1024 + hh * 64, a3v + hh * 16384, LM, DH, NP,
           NP, 1536, DH, 0, 0, 0, 1, nullptr, rs3, LM, 1.f, 0, 8);
    }
    // Z2 = pinv(a2) @ a3v
    gemm(stream, zc, a3v, Z2, LM, DH, LM, LM, DH, DH,
         65536, (long long)LM * DH, (long long)LM * DH, HEADS,
         nullptr, nullptr, 0, 1.f, 0, 1);
    // ---- per-head: attn[:, h*64:] = softmax(0.125 q @ kl^T) @ Z2 ----
    for (int hh = 0; hh < HEADS; hh++){
      gemm(stream, qkv + hh * 64, kl + hh * 16384, Sh, NP, LM, DH,
           1536, DH, LM, 0, 0, 0, 1, nullptr, nullptr, 0, 0.125f, GF_TRANSB, 1);
      rowexp_k<<<NP, 256, 0, stream>>>(Sh, rs1, LM);
      gemm(stream, Sh, Z2 + hh * 16384, attn + hh * 64, NP, DH, LM,
           LM, DH, CDIM, 0, 0, 0, 1, nullptr, rs1, NP, 1.f, 0, 1);
    }
    // attn += depthwise 33-tap conv of v
    resconv_k<<<dim3(2, NP / 8), 256, 0, stream>>>(qkv, l_rw[L], attn);
    // h += attn[-NT:] @ out_w + out_b
    gemm(stream, attn + (long long)PAD * CDIM, l_ow[L], h, NT, CDIM, CDIM,
         CDIM, CDIM, CDIM, 0, 0, 0, 1, l_ob[L], nullptr, 0, 1.f, GF_ACCUM, 1);

    if (L == 0){
      // PPEG on feature rows of h (cf/yt alias the now-dead qkv slab)
      transpose_k<<<dim3(16, 512), 256, 0, stream>>>(h + CDIM, cf, 16384, CDIM);
      ppeg_k<<<dim3(8, 8, CDIM), 256, 0, stream>>>(cf, yt, w7, b7, w5, b5, w3, b3);
      transpose_k<<<dim3(512, 16), 256, 0, stream>>>(yt, h + CDIM, CDIM, 16384);
    }
  }

  final_k<<<1, 256, 0, stream>>>(h, norm_g, norm_b, fc2_w, fc2_b, out);
}

// Round 3
// 4188.189 us; speedup vs baseline: 2.4053x; 2.4053x over previous
//
#include <hip/hip_runtime.h>

// ---------------------------------------------------------------------------
// TransMIL forward. Round 3: bf16 MFMA for all large GEMMs, f32 elsewhere.
// B=1, N=16384, IN=1024, C=512, heads=8, dh=64, NT=16385, NP=16640,
// landmarks M=256, l=65, pinv iters=6 (f32), res conv k=33.
// ---------------------------------------------------------------------------

#define NT 16385
#define NP 16640
#define PAD 255
#define CDIM 512
#define HEADS 8
#define DH 64
#define LM 256
#define LSEG 65

typedef unsigned short u16;
typedef unsigned int u32;
typedef __attribute__((ext_vector_type(8))) short bf16x8;
typedef __attribute__((ext_vector_type(4))) float f32x4;

__device__ __forceinline__ u16 f2b(float f){
  u32 u = __float_as_uint(f);
  u32 r = (u + 0x7FFFu + ((u >> 16) & 1u)) >> 16;
  return (u16)r;
}
__device__ __forceinline__ float b2f(u16 h){ return __uint_as_float(((u32)h) << 16); }

// ---------------- reductions ----------------
__device__ __forceinline__ float wredSum(float v){
#pragma unroll
  for (int o = 32; o > 0; o >>= 1) v += __shfl_xor(v, o, 64);
  return v;
}
__device__ __forceinline__ float wredMax(float v){
#pragma unroll
  for (int o = 32; o > 0; o >>= 1) v = fmaxf(v, __shfl_xor(v, o, 64));
  return v;
}
__device__ __forceinline__ float bredSum(float v, float* sm){
  v = wredSum(v);
  int w = threadIdx.x >> 6, l = threadIdx.x & 63;
  __syncthreads();
  if (l == 0) sm[w] = v;
  __syncthreads();
  return sm[0] + sm[1] + sm[2] + sm[3];
}
__device__ __forceinline__ float bredMax(float v, float* sm){
  v = wredMax(v);
  int w = threadIdx.x >> 6, l = threadIdx.x & 63;
  __syncthreads();
  if (l == 0) sm[w] = v;
  __syncthreads();
  return fmaxf(fmaxf(sm[0], sm[1]), fmaxf(sm[2], sm[3]));
}

// ---------------- utility ----------------
__global__ __launch_bounds__(256) void zero_k(float* __restrict__ p, long long n){
  long long i = (long long)blockIdx.x * 256 + threadIdx.x;
  long long stride = (long long)gridDim.x * 256;
  for (; i < n; i += stride) p[i] = 0.f;
}
__global__ __launch_bounds__(256) void copy_cls_k(const float* __restrict__ cls,
                                                  float* __restrict__ h){
  h[threadIdx.x] = cls[threadIdx.x];
  h[threadIdx.x + 256] = cls[threadIdx.x + 256];
}
// f32 -> bf16 elementwise (n multiple of 4)
__global__ __launch_bounds__(256) void cvtbf_k(const float* __restrict__ in,
                                               u16* __restrict__ out, long long n){
  long long i = ((long long)blockIdx.x * 256 + threadIdx.x) * 4;
  long long stride = (long long)gridDim.x * 256 * 4;
  for (; i < n; i += stride){
    float4 v = *(const float4*)(in + i);
    out[i]     = f2b(v.x);
    out[i + 1] = f2b(v.y);
    out[i + 2] = f2b(v.z);
    out[i + 3] = f2b(v.w);
  }
}
// f32 [R][ldin] -> bf16 transposed [C][ldout]
__global__ __launch_bounds__(256) void tcbf_k(const float* __restrict__ in,
    u16* __restrict__ out, int R, int C, int ldin, int ldout,
    long long sIn, long long sOut){
  __shared__ float t[32][33];
  in += (long long)blockIdx.z * sIn; out += (long long)blockIdx.z * sOut;
  int c0 = blockIdx.x * 32, r0 = blockIdx.y * 32;
  int x = threadIdx.x & 31, y = threadIdx.x >> 5;
  for (int yy = y; yy < 32; yy += 8){
    int r = r0 + yy, c = c0 + x;
    if (r < R && c < C) t[yy][x] = in[(long long)r * ldin + c];
  }
  __syncthreads();
  for (int yy = y; yy < 32; yy += 8){
    int c = c0 + yy, r = r0 + x;
    if (c < C && r < R) out[(long long)c * ldout + r] = f2b(t[x][yy]);
  }
}
// bf16 [R][ldin] -> bf16 transposed [C][ldout]
__global__ __launch_bounds__(256) void tc16_k(const u16* __restrict__ in,
    u16* __restrict__ out, int R, int C, int ldin, int ldout,
    long long sIn, long long sOut){
  __shared__ u16 t[32][33];
  in += (long long)blockIdx.z * sIn; out += (long long)blockIdx.z * sOut;
  int c0 = blockIdx.x * 32, r0 = blockIdx.y * 32;
  int x = threadIdx.x & 31, y = threadIdx.x >> 5;
  for (int yy = y; yy < 32; yy += 8){
    int r = r0 + yy, c = c0 + x;
    if (r < R && c < C) t[yy][x] = in[(long long)r * ldin + c];
  }
  __syncthreads();
  for (int yy = y; yy < 32; yy += 8){
    int c = c0 + yy, r = r0 + x;
    if (c < C && r < R) out[(long long)c * ldout + r] = t[x][yy];
  }
}

// ---------------- bf16 MFMA GEMM: C = alpha * A @ B^T (+bias)(/rowdiv) -----
// A [M,K] bf16 row-major lda; B [N,K] bf16 row-major ldb (i.e. B^T form).
// Tile 128x128, BK=64, 4 waves; each wave 32 rows x 128 cols via 16x16x32.
#define GB_STOREBF 1
#define GB_RELU    2
#define GB_ACCUM   4
#define GB_ATOMIC  8

__global__ __launch_bounds__(256) void gemmbf_k(
    const u16* __restrict__ A, const u16* __restrict__ B, void* __restrict__ Cv,
    int M, int N, int K, int lda, int ldb, int ldc,
    long long sA, long long sB, long long sC,
    const float* __restrict__ bias, const float* __restrict__ rowdiv,
    float alpha, int flags, int ksplit)
{
  __shared__ u16 As[128][72];
  __shared__ u16 Bs[128][72];
  int zb = blockIdx.z / ksplit;
  int ks = blockIdx.z - zb * ksplit;
  A += (long long)zb * sA; B += (long long)zb * sB;
  float* Cf = (float*)Cv + (long long)zb * sC;
  u16*   Ch = (u16*)Cv + (long long)zb * sC;
  int klen = K / ksplit;
  int kbeg = ks * klen, kend = kbeg + klen;
  int tid = threadIdx.x;
  int w = tid >> 6, l = tid & 63;
  int row0 = blockIdx.y * 128, col0 = blockIdx.x * 128;
  int srow = tid >> 3, scol = (tid & 7) * 8;
  f32x4 acc[2][8];
#pragma unroll
  for (int i = 0; i < 2; i++)
#pragma unroll
    for (int j = 0; j < 8; j++) acc[i][j] = (f32x4){0.f, 0.f, 0.f, 0.f};

  int mrow = l & 15, q = l >> 4;
  for (int k0 = kbeg; k0 < kend; k0 += 64){
#pragma unroll
    for (int c = 0; c < 4; c++){
      int r = srow + 32 * c;
      int gm = row0 + r; if (gm >= M) gm = M - 1;
      *(uint4*)&As[r][scol] = *(const uint4*)(A + (long long)gm * lda + k0 + scol);
      int gn = col0 + r; if (gn >= N) gn = N - 1;
      *(uint4*)&Bs[r][scol] = *(const uint4*)(B + (long long)gn * ldb + k0 + scol);
    }
    __syncthreads();
#pragma unroll
    for (int ks2 = 0; ks2 < 2; ks2++){
      bf16x8 af[2], bfr[8];
#pragma unroll
      for (int i = 0; i < 2; i++)
        af[i] = *(const bf16x8*)&As[w * 32 + i * 16 + mrow][ks2 * 32 + q * 8];
#pragma unroll
      for (int j = 0; j < 8; j++)
        bfr[j] = *(const bf16x8*)&Bs[j * 16 + mrow][ks2 * 32 + q * 8];
#pragma unroll
      for (int i = 0; i < 2; i++)
#pragma unroll
        for (int j = 0; j < 8; j++)
          acc[i][j] = __builtin_amdgcn_mfma_f32_16x16x32_bf16(af[i], bfr[j], acc[i][j], 0, 0, 0);
    }
    __syncthreads();
  }
  // epilogue: D row = q*4 + reg, col = lane&15
#pragma unroll
  for (int i = 0; i < 2; i++){
#pragma unroll
    for (int r = 0; r < 4; r++){
      int gm = row0 + w * 32 + i * 16 + q * 4 + r;
      if (gm >= M) continue;
      float rd = rowdiv ? rowdiv[gm] : 1.f;
#pragma unroll
      for (int j = 0; j < 8; j++){
        int gn = col0 + j * 16 + mrow;
        if (gn >= N) continue;
        float v = alpha * acc[i][j][r];
        if (rowdiv) v /= rd;
        if (bias) v += bias[gn];
        if (flags & GB_RELU) v = fmaxf(v, 0.f);
        long long ci = (long long)gm * ldc + gn;
        if (flags & GB_ATOMIC) atomicAdd(&Cf[ci], v);
        else if (flags & GB_STOREBF) Ch[ci] = f2b(v);
        else if (flags & GB_ACCUM) Cf[ci] += v;
        else Cf[ci] = v;
      }
    }
  }
}

// ---------------- f32 GEMM (small: a2, Z2) ----------------
#define GF_TRANSB 1
__global__ __launch_bounds__(256) void gemm_k(
    const float* __restrict__ A, const float* __restrict__ B, float* __restrict__ C,
    int M, int N, int K, int lda, int ldb, int ldc,
    long long sA, long long sB, long long sC, float alpha, int flags)
{
  __shared__ __align__(16) float As[16][68];
  __shared__ __align__(16) float Bs[16][68];
  int zb = blockIdx.z;
  A += (long long)zb * sA; B += (long long)zb * sB; C += (long long)zb * sC;
  int tid = threadIdx.x;
  int tx = tid & 15, ty = tid >> 4;
  int row0 = blockIdx.y * 64, col0 = blockIdx.x * 64;
  float acc[4][4] = {};
  for (int k0 = 0; k0 < K; k0 += 16){
#pragma unroll
    for (int i = 0; i < 4; i++){
      int idx = tid + i * 256;
      int mm = idx >> 4, kk = idx & 15;
      int gm = row0 + mm;
      As[kk][mm] = (gm < M) ? A[(long long)gm * lda + (k0 + kk)] : 0.f;
    }
    if (!(flags & GF_TRANSB)){
#pragma unroll
      for (int i = 0; i < 4; i++){
        int idx = tid + i * 256;
        int kk = idx >> 6, nn = idx & 63;
        int gn = col0 + nn;
        Bs[kk][nn] = (gn < N) ? B[(long long)(k0 + kk) * ldb + gn] : 0.f;
      }
    } else {
#pragma unroll
      for (int i = 0; i < 4; i++){
        int idx = tid + i * 256;
        int nn = idx >> 4, kk = idx & 15;
        int gn = col0 + nn;
        Bs[kk][nn] = (gn < N) ? B[(long long)gn * ldb + (k0 + kk)] : 0.f;
      }
    }
    __syncthreads();
#pragma unroll
    for (int kk = 0; kk < 16; kk++){
      float4 av = *(const float4*)&As[kk][ty * 4];
      float4 bv = *(const float4*)&Bs[kk][tx * 4];
      float a[4] = {av.x, av.y, av.z, av.w};
      float b[4] = {bv.x, bv.y, bv.z, bv.w};
#pragma unroll
      for (int i = 0; i < 4; i++)
#pragma unroll
        for (int j = 0; j < 4; j++)
          acc[i][j] = fmaf(a[i], b[j], acc[i][j]);
    }
    __syncthreads();
  }
#pragma unroll
  for (int i = 0; i < 4; i++){
    int gm = row0 + ty * 4 + i;
    if (gm >= M) continue;
#pragma unroll
    for (int j = 0; j < 4; j++){
      int gn = col0 + tx * 4 + j;
      if (gn >= N) continue;
      C[(long long)gm * ldc + gn] = alpha * acc[i][j];
    }
  }
}

// ---------------- batched 256x256x256 f32 GEMM for pinv --------------------
__global__ __launch_bounds__(256) void bgemm256_k(
    const float* __restrict__ A, const float* __restrict__ B, float* __restrict__ C,
    float dterm, float sterm, float eterm)
{
  __shared__ __align__(16) float As[16][68];
  __shared__ __align__(16) float Bs[16][68];
  long long off = (long long)blockIdx.z << 16;
  A += off; B += off; C += off;
  int tid = threadIdx.x;
  int tx = tid & 15, ty = tid >> 4;
  int row0 = blockIdx.y * 64, col0 = blockIdx.x * 64;
  float acc[4][4] = {};
  for (int k0 = 0; k0 < 256; k0 += 16){
#pragma unroll
    for (int i = 0; i < 4; i++){
      int idx = tid + i * 256;
      int mm = idx >> 4, kk = idx & 15;
      As[kk][mm] = A[(row0 + mm) * 256 + k0 + kk];
    }
#pragma unroll
    for (int i = 0; i < 4; i++){
      int idx = tid + i * 256;
      int kk = idx >> 6, nn = idx & 63;
      Bs[kk][nn] = B[(k0 + kk) * 256 + col0 + nn];
    }
    __syncthreads();
#pragma unroll
    for (int kk = 0; kk < 16; kk++){
      float4 av = *(const float4*)&As[kk][ty * 4];
      float4 bv = *(const float4*)&Bs[kk][tx * 4];
      float a[4] = {av.x, av.y, av.z, av.w};
      float b[4] = {bv.x, bv.y, bv.z, bv.w};
#pragma unroll
      for (int i = 0; i < 4; i++)
#pragma unroll
        for (int j = 0; j < 4; j++)
          acc[i][j] = fmaf(a[i], b[j], acc[i][j]);
    }
    __syncthreads();
  }
#pragma unroll
  for (int i = 0; i < 4; i++){
    int gm = row0 + ty * 4 + i;
#pragma unroll
    for (int j = 0; j < 4; j++){
      int gn = col0 + tx * 4 + j;
      float v = sterm * acc[i][j] + eterm * A[gm * 256 + gn];
      if (gm == gn) v += dterm;
      C[gm * 256 + gn] = v;
    }
  }
}

// ---------------- layernorm + front-pad -> bf16 xq (NP x 512) --------------
__global__ __launch_bounds__(256) void ln_pad_k(
    const float* __restrict__ h, const float* __restrict__ g,
    const float* __restrict__ b, u16* __restrict__ out)
{
  __shared__ float sm[4];
  int row = blockIdx.x, tid = threadIdx.x;
  u16* o = out + (long long)row * CDIM;
  if (row < PAD){ o[tid] = 0; o[tid + 256] = 0; return; }
  const float* x = h + (long long)(row - PAD) * CDIM;
  float v0 = x[tid], v1 = x[tid + 256];
  float s = bredSum(v0 + v1, sm);
  float s2 = bredSum(v0 * v0 + v1 * v1, sm);
  float mean = s * (1.f / 512.f);
  float var = s2 * (1.f / 512.f) - mean * mean;
  float rstd = rsqrtf(var + 1e-5f);
  o[tid] = f2b((v0 - mean) * rstd * g[tid] + b[tid]);
  o[tid + 256] = f2b((v1 - mean) * rstd * g[tid + 256] + b[tid + 256]);
}

// ---------------- landmark means (q pre-scaled by 1/8), f32 + bf16 outputs --
__global__ __launch_bounds__(64) void landmark_k(
    const u16* __restrict__ qkv, float* __restrict__ ql, float* __restrict__ kl,
    u16* __restrict__ qlh, u16* __restrict__ klh)
{
  int m = blockIdx.x, h = blockIdx.y, d = threadIdx.x;
  const u16* base = qkv + (long long)(m * LSEG) * 1536 + h * DH + d;
  float sq = 0.f, sk = 0.f;
  for (int j = 0; j < LSEG; j++){
    sq += b2f(base[(long long)j * 1536]);
    sk += b2f(base[(long long)j * 1536 + 512]);
  }
  float qv = sq * (0.125f / 65.f);
  float kv = sk * (1.f / 65.f);
  int idx = (h * LM + m) * DH + d;
  ql[idx] = qv; kl[idx] = kv;
  qlh[idx] = f2b(qv); klh[idx] = f2b(kv);
}

// ---------------- softmax over rows of 256 f32 (in place) ----------------
__global__ __launch_bounds__(256) void softmax256_k(float* __restrict__ S)
{
  __shared__ float sm[4];
  int i = blockIdx.x, h = blockIdx.y, j = threadIdx.x;
  float* row = S + ((long long)h * LM + i) * 256;
  float v = row[j];
  float m = bredMax(v, sm);
  float e = __expf(v - m);
  float s = bredSum(e, sm);
  row[j] = e / s;
}

// ---------------- bf16 row exp (stable) + f32 rowsum ----------------
__global__ __launch_bounds__(256) void expbf_k(
    u16* __restrict__ S, float* __restrict__ rowsum, int ncols)
{
  __shared__ float sm[4];
  int row = blockIdx.x, tid = threadIdx.x;
  u16* r = S + (long long)row * ncols;
  float lm = -3.0e38f;
  for (int j = tid; j < ncols; j += 256) lm = fmaxf(lm, b2f(r[j]));
  float m = bredMax(lm, sm);
  float ls = 0.f;
  for (int j = tid; j < ncols; j += 256){
    float e = __expf(b2f(r[j]) - m);
    r[j] = f2b(e);
    ls += e;
  }
  float s = bredSum(ls, sm);
  if (tid == 0) rowsum[row] = s;
}

// ---------------- pinv scale factors ----------------
__global__ __launch_bounds__(256) void pinv_scal_k(
    const float* __restrict__ a2, float* __restrict__ scal)
{
  __shared__ float sm[4];
  int h = blockIdx.x, i = threadIdx.x;
  const float* Ah = a2 + (long long)h * 65536;
  float rs = 0.f, cs = 0.f;
  for (int j = 0; j < 256; j++){
    rs += fabsf(Ah[i * 256 + j]);
    cs += fabsf(Ah[j * 256 + i]);
  }
  float rmax = bredMax(rs, sm);
  __syncthreads();
  float cmax = bredMax(cs, sm);
  if (i == 0){
    atomicMax((int*)&scal[0], __float_as_int(rmax));
    atomicMax((int*)&scal[1], __float_as_int(cmax));
  }
}

__global__ __launch_bounds__(256) void z0_k(
    const float* __restrict__ a2, float* __restrict__ z, const float* __restrict__ scal)
{
  int j = blockIdx.x, h = blockIdx.y, i = threadIdx.x;
  float inv = 1.f / (scal[0] * scal[1]);
  z[((long long)h * LM + j) * 256 + i] = a2[((long long)h * LM + i) * 256 + j] * inv;
}

// ---------------- depthwise 33-tap residual conv (bf16 v, bf16 attn RMW) ---
__global__ __launch_bounds__(256) void resconv_k(
    const u16* __restrict__ qkv, const float* __restrict__ rw,
    u16* __restrict__ attn)
{
  int c = blockIdx.x * 256 + threadIdx.x;   // 0..511
  int s0 = blockIdx.y * 8;
  int h = c >> 6;
  float w[33];
#pragma unroll
  for (int t = 0; t < 33; t++) w[t] = rw[h * 33 + t];
  float acc[8] = {};
  for (int t = 0; t < 40; t++){
    int s = s0 - 16 + t;
    float v = (s >= 0 && s < NP) ? b2f(qkv[(long long)s * 1536 + 1024 + c]) : 0.f;
    int ilo = t - 32; if (ilo < 0) ilo = 0;
    int ihi = t; if (ihi > 7) ihi = 7;
    for (int i = ilo; i <= ihi; i++) acc[i] = fmaf(v, w[t - i], acc[i]);
  }
#pragma unroll
  for (int i = 0; i < 8; i++){
    long long idx = (long long)(s0 + i) * CDIM + c;
    attn[idx] = f2b(b2f(attn[idx]) + acc[i]);
  }
}

// ---------------- f32 32x32 transpose ----------------
__global__ __launch_bounds__(256) void transpose_k(
    const float* __restrict__ in, float* __restrict__ out, int R, int Cc)
{
  __shared__ float t[32][33];
  int bx = blockIdx.x * 32, by = blockIdx.y * 32;
  int x = threadIdx.x & 31, y4 = threadIdx.x >> 5;
  for (int yy = y4; yy < 32; yy += 8){
    int r = by + yy, c = bx + x;
    if (r < R && c < Cc) t[yy][x] = in[(long long)r * Cc + c];
  }
  __syncthreads();
  for (int yy = y4; yy < 32; yy += 8){
    int r = bx + yy, c = by + x;
    if (r < Cc && c < R) out[(long long)r * R + c] = t[x][yy];
  }
}

// ---------------- fused PPEG ----------------
__global__ __launch_bounds__(256) void ppeg_k(
    const float* __restrict__ cf, float* __restrict__ yt,
    const float* __restrict__ w7, const float* __restrict__ b7,
    const float* __restrict__ w5, const float* __restrict__ b5,
    const float* __restrict__ w3, const float* __restrict__ b3)
{
  __shared__ float tile[22][23];
  int c = blockIdx.z;
  int ty0 = blockIdx.y * 16, tx0 = blockIdx.x * 16;
  const float* img = cf + (long long)c * 16384;
  for (int i = threadIdx.x; i < 22 * 22; i += 256){
    int yy = i / 22, xx = i - yy * 22;
    int gy = ty0 - 3 + yy, gx = tx0 - 3 + xx;
    tile[yy][xx] = (gy >= 0 && gy < 128 && gx >= 0 && gx < 128) ? img[gy * 128 + gx] : 0.f;
  }
  __syncthreads();
  int lx = threadIdx.x & 15, ly = threadIdx.x >> 4;
  float o = tile[ly + 3][lx + 3] + b7[c] + b5[c] + b3[c];
  const float* W7 = w7 + c * 49;
#pragma unroll
  for (int ky = 0; ky < 7; ky++)
#pragma unroll
    for (int kx = 0; kx < 7; kx++)
      o = fmaf(tile[ly + ky][lx + kx], W7[ky * 7 + kx], o);
  const float* W5 = w5 + c * 25;
#pragma unroll
  for (int ky = 0; ky < 5; ky++)
#pragma unroll
    for (int kx = 0; kx < 5; kx++)
      o = fmaf(tile[ly + 1 + ky][lx + 1 + kx], W5[ky * 5 + kx], o);
  const float* W3 = w3 + c * 9;
#pragma unroll
  for (int ky = 0; ky < 3; ky++)
#pragma unroll
    for (int kx = 0; kx < 3; kx++)
      o = fmaf(tile[ly + 2 + ky][lx + 2 + kx], W3[ky * 3 + kx], o);
  yt[(long long)c * 16384 + (ty0 + ly) * 128 + (tx0 + lx)] = o;
}

// ---------------- final: LN(h[0]) @ fc2 + b ----------------
__global__ __launch_bounds__(256) void final_k(
    const float* __restrict__ h, const float* __restrict__ g,
    const float* __restrict__ b, const float* __restrict__ w,
    const float* __restrict__ bias, float* __restrict__ out)
{
  __shared__ float sm[4];
  __shared__ float pj[256][4];
  int tid = threadIdx.x;
  float v0 = h[tid], v1 = h[tid + 256];
  float s = bredSum(v0 + v1, sm);
  float s2 = bredSum(v0 * v0 + v1 * v1, sm);
  float mean = s * (1.f / 512.f);
  float var = s2 * (1.f / 512.f) - mean * mean;
  float rstd = rsqrtf(var + 1e-5f);
  float n0 = (v0 - mean) * rstd * g[tid] + b[tid];
  float n1 = (v1 - mean) * rstd * g[tid + 256] + b[tid + 256];
#pragma unroll
  for (int j = 0; j < 4; j++)
    pj[tid][j] = n0 * w[tid * 4 + j] + n1 * w[(tid + 256) * 4 + j];
  __syncthreads();
  if (tid < 4){
    float acc = 0.f;
    for (int k = 0; k < 256; k++) acc += pj[k][tid];
    out[tid] = acc + bias[tid];
  }
}

// ===========================================================================
// host side
// ===========================================================================
static inline void gemmbf(hipStream_t st, const u16* A, const u16* B, void* C,
                          int M, int N, int K, int lda, int ldb, int ldc,
                          long long sA, long long sB, long long sC, int batch,
                          const float* bias, const float* rowdiv,
                          float alpha, int flags, int ksplit)
{
  dim3 grid((N + 127) / 128, (M + 127) / 128, batch * ksplit);
  gemmbf_k<<<grid, 256, 0, st>>>(A, B, C, M, N, K, lda, ldb, ldc, sA, sB, sC,
                                 bias, rowdiv, alpha, flags, ksplit);
}

// workspace byte offsets
#define B_H     0LL
#define B_XQ    33556480LL
#define B_ATTN  50595840LL
#define B_QKV   67635200LL     /* also xb; also cf/yt for PPEG */
#define B_VT    118753280LL
#define B_SH    135792640LL
#define B_QL    144312320LL
#define B_KL    144836608LL
#define B_QLH   145360896LL
#define B_KLH   145623040LL
#define B_A2    145885184LL
#define B_Z0    147982336LL
#define B_Z1    150079488LL
#define B_AZ    152176640LL
#define B_TA    154273792LL
#define B_TB    156370944LL
#define B_A3V   158468096LL
#define B_Z2    158992384LL
#define B_Z2T   159516672LL
#define B_RS    159778816LL
#define B_SCAL  159845376LL
#define B_W1T   159845632LL
#define B_WQT   160894208LL
#define B_WOT   162467072LL
#define WS_REQ  162991360LL

extern "C" void kernel_launch(void* const* d_in, const int* in_sizes, int n_in,
                              void* d_out, int out_size, void* d_ws, size_t ws_size,
                              hipStream_t stream)
{
  (void)in_sizes; (void)n_in; (void)out_size;
  if (ws_size < (size_t)WS_REQ) return;   // fail cleanly, not with a fault

  const float* x      = (const float*)d_in[0];
  const float* fc1_w  = (const float*)d_in[1];
  const float* fc1_b  = (const float*)d_in[2];
  const float* cls    = (const float*)d_in[3];
  const float* l_ng[2]  = {(const float*)d_in[4],  (const float*)d_in[10]};
  const float* l_nb[2]  = {(const float*)d_in[5],  (const float*)d_in[11]};
  const float* l_qkv[2] = {(const float*)d_in[6],  (const float*)d_in[12]};
  const float* l_ow[2]  = {(const float*)d_in[7],  (const float*)d_in[13]};
  const float* l_ob[2]  = {(const float*)d_in[8],  (const float*)d_in[14]};
  const float* l_rw[2]  = {(const float*)d_in[9],  (const float*)d_in[15]};
  const float* w7 = (const float*)d_in[16];
  const float* b7 = (const float*)d_in[17];
  const float* w5 = (const float*)d_in[18];
  const float* b5 = (const float*)d_in[19];
  const float* w3 = (const float*)d_in[20];
  const float* b3 = (const float*)d_in[21];
  const float* norm_g = (const float*)d_in[22];
  const float* norm_b = (const float*)d_in[23];
  const float* fc2_w  = (const float*)d_in[24];
  const float* fc2_b  = (const float*)d_in[25];
  float* out = (float*)d_out;

  char* WB = (char*)d_ws;
  float* h    = (float*)(WB + B_H);
  u16*   xq   = (u16*)(WB + B_XQ);
  u16*   attnb= (u16*)(WB + B_ATTN);
  u16*   qkvb = (u16*)(WB + B_QKV);
  u16*   xb   = (u16*)(WB + B_QKV);        // alias (dead before qkvb written)
  float* cf   = (float*)(WB + B_QKV);      // alias for PPEG
  float* yt   = (float*)(WB + B_QKV + 33554432LL);
  u16*   vT   = (u16*)(WB + B_VT);
  u16*   Sh   = (u16*)(WB + B_SH);
  float* ql   = (float*)(WB + B_QL);
  float* kl   = (float*)(WB + B_KL);
  u16*   qlh  = (u16*)(WB + B_QLH);
  u16*   klh  = (u16*)(WB + B_KLH);
  float* a2   = (float*)(WB + B_A2);
  float* z0b  = (float*)(WB + B_Z0);
  float* z1b  = (float*)(WB + B_Z1);
  float* az   = (float*)(WB + B_AZ);
  float* tA   = (float*)(WB + B_TA);
  float* tB   = (float*)(WB + B_TB);
  float* a3v  = (float*)(WB + B_A3V);
  float* Z2   = (float*)(WB + B_Z2);
  u16*   Z2T  = (u16*)(WB + B_Z2T);
  float* rs   = (float*)(WB + B_RS);
  float* scal = (float*)(WB + B_SCAL);
  u16*   w1T  = (u16*)(WB + B_W1T);
  u16*   wqT  = (u16*)(WB + B_WQT);
  u16*   woT  = (u16*)(WB + B_WOT);

  // ---- fc1: h[0]=cls; h[1..] = relu(x @ fc1_w + b) via bf16 MFMA ----
  copy_cls_k<<<1, 256, 0, stream>>>(cls, h);
  cvtbf_k<<<4096, 256, 0, stream>>>(x, xb, 16384LL * 1024);
  tcbf_k<<<dim3(16, 32, 1), 256, 0, stream>>>(fc1_w, w1T, 1024, 512, 512, 1024, 0, 0);
  gemmbf(stream, xb, w1T, h + CDIM, 16384, 512, 1024, 1024, 1024, 512,
         0, 0, 0, 1, fc1_b, nullptr, 1.f, GB_RELU, 1);

  for (int L = 0; L < 2; L++){
    // xq = pad(LN(h)) in bf16
    ln_pad_k<<<NP, 256, 0, stream>>>(h, l_ng[L], l_nb[L], xq);
    // qkv (bf16 out)
    tcbf_k<<<dim3(48, 16, 1), 256, 0, stream>>>(l_qkv[L], wqT, 512, 1536, 1536, 512, 0, 0);
    gemmbf(stream, xq, wqT, qkvb, NP, 1536, 512, 512, 512, 1536,
           0, 0, 0, 1, nullptr, nullptr, 1.f, GB_STOREBF, 1);
    // landmarks (f32 + bf16)
    landmark_k<<<dim3(LM, HEADS), 64, 0, stream>>>(qkvb, ql, kl, qlh, klh);
    // vT: per-head [64][NP] bf16
    tc16_k<<<dim3(2, 520, 8), 256, 0, stream>>>(qkvb + 1024, vT, NP, 64, 1536, NP,
                                                64, 64LL * NP);
    // a2 = softmax(ql @ kl^T) f32
    gemm_k<<<dim3(4, 4, 8), 256, 0, stream>>>(ql, kl, a2, LM, LM, DH, DH, DH, LM,
                                              16384, 16384, 65536, 1.f, GF_TRANSB);
    softmax256_k<<<dim3(LM, HEADS), 256, 0, stream>>>(a2);
    // pinv init + 6 Newton-Schulz iterations (f32)
    zero_k<<<1, 256, 0, stream>>>(scal, 2);
    pinv_scal_k<<<HEADS, 256, 0, stream>>>(a2, scal);
    z0_k<<<dim3(LM, HEADS), 256, 0, stream>>>(a2, z0b, scal);
    float* zc = z0b; float* za = z1b;
    dim3 bg(4, 4, HEADS);
    for (int it = 0; it < 6; it++){
      bgemm256_k<<<bg, 256, 0, stream>>>(a2, zc, az, 0.f, 1.f, 0.f);
      bgemm256_k<<<bg, 256, 0, stream>>>(az, az, tA, 15.f, 1.f, -7.f);
      bgemm256_k<<<bg, 256, 0, stream>>>(az, tA, tB, 13.f, -1.f, 0.f);
      bgemm256_k<<<bg, 256, 0, stream>>>(zc, tB, za, 0.f, 0.25f, 0.f);
      float* tmp = zc; zc = za; za = tmp;
    }
    // ---- S3 per head: a3v = softmax(ql @ k^T) @ v ----
    zero_k<<<128, 256, 0, stream>>>(a3v, (long long)HEADS * LM * DH);
    for (int hh = 0; hh < HEADS; hh++){
      gemmbf(stream, qlh + hh * 16384, qkvb + 512 + hh * 64, Sh,
             LM, NP, DH, DH, 1536, NP, 0, 0, 0, 1,
             nullptr, nullptr, 1.f, GB_STOREBF, 1);
      expbf_k<<<LM, 256, 0, stream>>>(Sh, rs, NP);
      gemmbf(stream, Sh, vT + (long long)hh * 64 * NP, a3v + hh * 16384,
             LM, DH, NP, NP, NP, DH, 0, 0, 0, 1,
             nullptr, rs, 1.f, GB_ATOMIC, 65);
    }
    // Z2 = pinv(a2) @ a3v (f32), then bf16 transpose per head
    gemm_k<<<dim3(1, 4, 8), 256, 0, stream>>>(zc, a3v, Z2, LM, DH, LM, LM, DH, DH,
                                              65536, 16384, 16384, 1.f, 0);
    tcbf_k<<<dim3(2, 8, 8), 256, 0, stream>>>(Z2, Z2T, 256, 64, 64, 256, 16384, 16384);
    // ---- S1 per head: attn[:, h*64:] = softmax(0.125 q @ kl^T) @ Z2 ----
    for (int hh = 0; hh < HEADS; hh++){
      gemmbf(stream, qkvb + hh * 64, klh + hh * 16384, Sh,
             NP, LM, DH, 1536, DH, LM, 0, 0, 0, 1,
             nullptr, nullptr, 0.125f, GB_STOREBF, 1);
      expbf_k<<<NP, 256, 0, stream>>>(Sh, rs, LM);
      gemmbf(stream, Sh, Z2T + hh * 16384, attnb + hh * 64,
             NP, DH, LM, LM, LM, CDIM, 0, 0, 0, 1,
             nullptr, rs, 1.f, GB_STOREBF, 1);
    }
    // attn += depthwise 33-tap conv of v
    resconv_k<<<dim3(2, NP / 8), 256, 0, stream>>>(qkvb, l_rw[L], attnb);
    // h += attn[-NT:] @ out_w + out_b  (bf16 MFMA, f32 accumulate into h)
    tcbf_k<<<dim3(16, 16, 1), 256, 0, stream>>>(l_ow[L], woT, 512, 512, 512, 512, 0, 0);
    gemmbf(stream, attnb + (long long)PAD * CDIM, woT, h, NT, CDIM, CDIM,
           CDIM, CDIM, CDIM, 0, 0, 0, 1, l_ob[L], nullptr, 1.f, GB_ACCUM, 1);

    if (L == 0){
      // PPEG (f32) — cf/yt alias the now-dead qkvb/vT region
      transpose_k<<<dim3(16, 512), 256, 0, stream>>>(h + CDIM, cf, 16384, CDIM);
      ppeg_k<<<dim3(8, 8, CDIM), 256, 0, stream>>>(cf, yt, w7, b7, w5, b5, w3, b3);
      transpose_k<<<dim3(512, 16), 256, 0, stream>>>(yt, h + CDIM, CDIM, 16384);
    }
  }

  final_k<<<1, 256, 0, stream>>>(h, norm_g, norm_b, fc2_w, fc2_b, out);
}

// Round 4
// 2884.652 us; speedup vs baseline: 3.4922x; 1.4519x over previous
//
#include <hip/hip_runtime.h>

// ---------------------------------------------------------------------------
// TransMIL forward. Round 4: unrolled resconv + 4-head-batched S3/S1 chains.
// B=1, N=16384, IN=1024, C=512, heads=8, dh=64, NT=16385, NP=16640,
// landmarks M=256, l=65, pinv iters=6 (f32), res conv k=33.
// ---------------------------------------------------------------------------

#define NT 16385
#define NP 16640
#define PAD 255
#define CDIM 512
#define HEADS 8
#define DH 64
#define LM 256
#define LSEG 65

typedef unsigned short u16;
typedef unsigned int u32;
typedef __attribute__((ext_vector_type(8))) short bf16x8;
typedef __attribute__((ext_vector_type(4))) float f32x4;

__device__ __forceinline__ u16 f2b(float f){
  u32 u = __float_as_uint(f);
  u32 r = (u + 0x7FFFu + ((u >> 16) & 1u)) >> 16;
  return (u16)r;
}
__device__ __forceinline__ float b2f(u16 h){ return __uint_as_float(((u32)h) << 16); }

// ---------------- reductions ----------------
__device__ __forceinline__ float wredSum(float v){
#pragma unroll
  for (int o = 32; o > 0; o >>= 1) v += __shfl_xor(v, o, 64);
  return v;
}
__device__ __forceinline__ float wredMax(float v){
#pragma unroll
  for (int o = 32; o > 0; o >>= 1) v = fmaxf(v, __shfl_xor(v, o, 64));
  return v;
}
__device__ __forceinline__ float bredSum(float v, float* sm){
  v = wredSum(v);
  int w = threadIdx.x >> 6, l = threadIdx.x & 63;
  __syncthreads();
  if (l == 0) sm[w] = v;
  __syncthreads();
  return sm[0] + sm[1] + sm[2] + sm[3];
}
__device__ __forceinline__ float bredMax(float v, float* sm){
  v = wredMax(v);
  int w = threadIdx.x >> 6, l = threadIdx.x & 63;
  __syncthreads();
  if (l == 0) sm[w] = v;
  __syncthreads();
  return fmaxf(fmaxf(sm[0], sm[1]), fmaxf(sm[2], sm[3]));
}

// ---------------- utility ----------------
__global__ __launch_bounds__(256) void zero_k(float* __restrict__ p, long long n){
  long long i = (long long)blockIdx.x * 256 + threadIdx.x;
  long long stride = (long long)gridDim.x * 256;
  for (; i < n; i += stride) p[i] = 0.f;
}
__global__ __launch_bounds__(256) void copy_cls_k(const float* __restrict__ cls,
                                                  float* __restrict__ h){
  h[threadIdx.x] = cls[threadIdx.x];
  h[threadIdx.x + 256] = cls[threadIdx.x + 256];
}
// f32 -> bf16 elementwise (n multiple of 4)
__global__ __launch_bounds__(256) void cvtbf_k(const float* __restrict__ in,
                                               u16* __restrict__ out, long long n){
  long long i = ((long long)blockIdx.x * 256 + threadIdx.x) * 4;
  long long stride = (long long)gridDim.x * 256 * 4;
  for (; i < n; i += stride){
    float4 v = *(const float4*)(in + i);
    out[i]     = f2b(v.x);
    out[i + 1] = f2b(v.y);
    out[i + 2] = f2b(v.z);
    out[i + 3] = f2b(v.w);
  }
}
// f32 [R][ldin] -> bf16 transposed [C][ldout]
__global__ __launch_bounds__(256) void tcbf_k(const float* __restrict__ in,
    u16* __restrict__ out, int R, int C, int ldin, int ldout,
    long long sIn, long long sOut){
  __shared__ float t[32][33];
  in += (long long)blockIdx.z * sIn; out += (long long)blockIdx.z * sOut;
  int c0 = blockIdx.x * 32, r0 = blockIdx.y * 32;
  int x = threadIdx.x & 31, y = threadIdx.x >> 5;
  for (int yy = y; yy < 32; yy += 8){
    int r = r0 + yy, c = c0 + x;
    if (r < R && c < C) t[yy][x] = in[(long long)r * ldin + c];
  }
  __syncthreads();
  for (int yy = y; yy < 32; yy += 8){
    int c = c0 + yy, r = r0 + x;
    if (c < C && r < R) out[(long long)c * ldout + r] = f2b(t[x][yy]);
  }
}
// bf16 [R][ldin] -> bf16 transposed [C][ldout]
__global__ __launch_bounds__(256) void tc16_k(const u16* __restrict__ in,
    u16* __restrict__ out, int R, int C, int ldin, int ldout,
    long long sIn, long long sOut){
  __shared__ u16 t[32][33];
  in += (long long)blockIdx.z * sIn; out += (long long)blockIdx.z * sOut;
  int c0 = blockIdx.x * 32, r0 = blockIdx.y * 32;
  int x = threadIdx.x & 31, y = threadIdx.x >> 5;
  for (int yy = y; yy < 32; yy += 8){
    int r = r0 + yy, c = c0 + x;
    if (r < R && c < C) t[yy][x] = in[(long long)r * ldin + c];
  }
  __syncthreads();
  for (int yy = y; yy < 32; yy += 8){
    int c = c0 + yy, r = r0 + x;
    if (c < C && r < R) out[(long long)c * ldout + r] = t[x][yy];
  }
}

// ---------------- bf16 MFMA GEMM: C = alpha * A @ B^T (+bias)(/rowdiv) -----
// A [M,K] bf16 row-major lda; B [N,K] bf16 row-major ldb (bt form).
// Tile 128x128, BK=64, 4 waves.
#define GB_STOREBF 1
#define GB_RELU    2
#define GB_ACCUM   4
#define GB_ATOMIC  8

__global__ __launch_bounds__(256) void gemmbf_k(
    const u16* __restrict__ A, const u16* __restrict__ B, void* __restrict__ Cv,
    int M, int N, int K, int lda, int ldb, int ldc,
    long long sA, long long sB, long long sC,
    const float* __restrict__ bias, const float* __restrict__ rowdiv, int sRow,
    float alpha, int flags, int ksplit)
{
  __shared__ u16 As[128][72];
  __shared__ u16 Bs[128][72];
  int zb = blockIdx.z / ksplit;
  int ks = blockIdx.z - zb * ksplit;
  A += (long long)zb * sA; B += (long long)zb * sB;
  float* Cf = (float*)Cv + (long long)zb * sC;
  u16*   Ch = (u16*)Cv + (long long)zb * sC;
  int klen = K / ksplit;
  int kbeg = ks * klen, kend = kbeg + klen;
  int tid = threadIdx.x;
  int w = tid >> 6, l = tid & 63;
  int row0 = blockIdx.y * 128, col0 = blockIdx.x * 128;
  int srow = tid >> 3, scol = (tid & 7) * 8;
  f32x4 acc[2][8];
#pragma unroll
  for (int i = 0; i < 2; i++)
#pragma unroll
    for (int j = 0; j < 8; j++) acc[i][j] = (f32x4){0.f, 0.f, 0.f, 0.f};

  int mrow = l & 15, q = l >> 4;
  for (int k0 = kbeg; k0 < kend; k0 += 64){
#pragma unroll
    for (int c = 0; c < 4; c++){
      int r = srow + 32 * c;
      int gm = row0 + r; if (gm >= M) gm = M - 1;
      *(uint4*)&As[r][scol] = *(const uint4*)(A + (long long)gm * lda + k0 + scol);
      int gn = col0 + r; if (gn >= N) gn = N - 1;
      *(uint4*)&Bs[r][scol] = *(const uint4*)(B + (long long)gn * ldb + k0 + scol);
    }
    __syncthreads();
#pragma unroll
    for (int ks2 = 0; ks2 < 2; ks2++){
      bf16x8 af[2], bfr[8];
#pragma unroll
      for (int i = 0; i < 2; i++)
        af[i] = *(const bf16x8*)&As[w * 32 + i * 16 + mrow][ks2 * 32 + q * 8];
#pragma unroll
      for (int j = 0; j < 8; j++)
        bfr[j] = *(const bf16x8*)&Bs[j * 16 + mrow][ks2 * 32 + q * 8];
#pragma unroll
      for (int i = 0; i < 2; i++)
#pragma unroll
        for (int j = 0; j < 8; j++)
          acc[i][j] = __builtin_amdgcn_mfma_f32_16x16x32_bf16(af[i], bfr[j], acc[i][j], 0, 0, 0);
    }
    __syncthreads();
  }
#pragma unroll
  for (int i = 0; i < 2; i++){
#pragma unroll
    for (int r = 0; r < 4; r++){
      int gm = row0 + w * 32 + i * 16 + q * 4 + r;
      if (gm >= M) continue;
      float rd = rowdiv ? rowdiv[(long long)zb * sRow + gm] : 1.f;
#pragma unroll
      for (int j = 0; j < 8; j++){
        int gn = col0 + j * 16 + mrow;
        if (gn >= N) continue;
        float v = alpha * acc[i][j][r];
        if (rowdiv) v /= rd;
        if (bias) v += bias[gn];
        if (flags & GB_RELU) v = fmaxf(v, 0.f);
        long long ci = (long long)gm * ldc + gn;
        if (flags & GB_ATOMIC) atomicAdd(&Cf[ci], v);
        else if (flags & GB_STOREBF) Ch[ci] = f2b(v);
        else if (flags & GB_ACCUM) Cf[ci] += v;
        else Cf[ci] = v;
      }
    }
  }
}

// ---------------- f32 GEMM (small: a2, Z2) ----------------
#define GF_TRANSB 1
__global__ __launch_bounds__(256) void gemm_k(
    const float* __restrict__ A, const float* __restrict__ B, float* __restrict__ C,
    int M, int N, int K, int lda, int ldb, int ldc,
    long long sA, long long sB, long long sC, float alpha, int flags)
{
  __shared__ __align__(16) float As[16][68];
  __shared__ __align__(16) float Bs[16][68];
  int zb = blockIdx.z;
  A += (long long)zb * sA; B += (long long)zb * sB; C += (long long)zb * sC;
  int tid = threadIdx.x;
  int tx = tid & 15, ty = tid >> 4;
  int row0 = blockIdx.y * 64, col0 = blockIdx.x * 64;
  float acc[4][4] = {};
  for (int k0 = 0; k0 < K; k0 += 16){
#pragma unroll
    for (int i = 0; i < 4; i++){
      int idx = tid + i * 256;
      int mm = idx >> 4, kk = idx & 15;
      int gm = row0 + mm;
      As[kk][mm] = (gm < M) ? A[(long long)gm * lda + (k0 + kk)] : 0.f;
    }
    if (!(flags & GF_TRANSB)){
#pragma unroll
      for (int i = 0; i < 4; i++){
        int idx = tid + i * 256;
        int kk = idx >> 6, nn = idx & 63;
        int gn = col0 + nn;
        Bs[kk][nn] = (gn < N) ? B[(long long)(k0 + kk) * ldb + gn] : 0.f;
      }
    } else {
#pragma unroll
      for (int i = 0; i < 4; i++){
        int idx = tid + i * 256;
        int nn = idx >> 4, kk = idx & 15;
        int gn = col0 + nn;
        Bs[kk][nn] = (gn < N) ? B[(long long)gn * ldb + (k0 + kk)] : 0.f;
      }
    }
    __syncthreads();
#pragma unroll
    for (int kk = 0; kk < 16; kk++){
      float4 av = *(const float4*)&As[kk][ty * 4];
      float4 bv = *(const float4*)&Bs[kk][tx * 4];
      float a[4] = {av.x, av.y, av.z, av.w};
      float b[4] = {bv.x, bv.y, bv.z, bv.w};
#pragma unroll
      for (int i = 0; i < 4; i++)
#pragma unroll
        for (int j = 0; j < 4; j++)
          acc[i][j] = fmaf(a[i], b[j], acc[i][j]);
    }
    __syncthreads();
  }
#pragma unroll
  for (int i = 0; i < 4; i++){
    int gm = row0 + ty * 4 + i;
    if (gm >= M) continue;
#pragma unroll
    for (int j = 0; j < 4; j++){
      int gn = col0 + tx * 4 + j;
      if (gn >= N) continue;
      C[(long long)gm * ldc + gn] = alpha * acc[i][j];
    }
  }
}

// ---------------- batched 256x256x256 f32 GEMM for pinv --------------------
__global__ __launch_bounds__(256) void bgemm256_k(
    const float* __restrict__ A, const float* __restrict__ B, float* __restrict__ C,
    float dterm, float sterm, float eterm)
{
  __shared__ __align__(16) float As[16][68];
  __shared__ __align__(16) float Bs[16][68];
  long long off = (long long)blockIdx.z << 16;
  A += off; B += off; C += off;
  int tid = threadIdx.x;
  int tx = tid & 15, ty = tid >> 4;
  int row0 = blockIdx.y * 64, col0 = blockIdx.x * 64;
  float acc[4][4] = {};
  for (int k0 = 0; k0 < 256; k0 += 16){
#pragma unroll
    for (int i = 0; i < 4; i++){
      int idx = tid + i * 256;
      int mm = idx >> 4, kk = idx & 15;
      As[kk][mm] = A[(row0 + mm) * 256 + k0 + kk];
    }
#pragma unroll
    for (int i = 0; i < 4; i++){
      int idx = tid + i * 256;
      int kk = idx >> 6, nn = idx & 63;
      Bs[kk][nn] = B[(k0 + kk) * 256 + col0 + nn];
    }
    __syncthreads();
#pragma unroll
    for (int kk = 0; kk < 16; kk++){
      float4 av = *(const float4*)&As[kk][ty * 4];
      float4 bv = *(const float4*)&Bs[kk][tx * 4];
      float a[4] = {av.x, av.y, av.z, av.w};
      float b[4] = {bv.x, bv.y, bv.z, bv.w};
#pragma unroll
      for (int i = 0; i < 4; i++)
#pragma unroll
        for (int j = 0; j < 4; j++)
          acc[i][j] = fmaf(a[i], b[j], acc[i][j]);
    }
    __syncthreads();
  }
#pragma unroll
  for (int i = 0; i < 4; i++){
    int gm = row0 + ty * 4 + i;
#pragma unroll
    for (int j = 0; j < 4; j++){
      int gn = col0 + tx * 4 + j;
      float v = sterm * acc[i][j] + eterm * A[gm * 256 + gn];
      if (gm == gn) v += dterm;
      C[gm * 256 + gn] = v;
    }
  }
}

// ---------------- layernorm + front-pad -> bf16 xq (NP x 512) --------------
__global__ __launch_bounds__(256) void ln_pad_k(
    const float* __restrict__ h, const float* __restrict__ g,
    const float* __restrict__ b, u16* __restrict__ out)
{
  __shared__ float sm[4];
  int row = blockIdx.x, tid = threadIdx.x;
  u16* o = out + (long long)row * CDIM;
  if (row < PAD){ o[tid] = 0; o[tid + 256] = 0; return; }
  const float* x = h + (long long)(row - PAD) * CDIM;
  float v0 = x[tid], v1 = x[tid + 256];
  float s = bredSum(v0 + v1, sm);
  float s2 = bredSum(v0 * v0 + v1 * v1, sm);
  float mean = s * (1.f / 512.f);
  float var = s2 * (1.f / 512.f) - mean * mean;
  float rstd = rsqrtf(var + 1e-5f);
  o[tid] = f2b((v0 - mean) * rstd * g[tid] + b[tid]);
  o[tid + 256] = f2b((v1 - mean) * rstd * g[tid + 256] + b[tid + 256]);
}

// ---------------- landmark means (q pre-scaled by 1/8) ----------------
__global__ __launch_bounds__(64) void landmark_k(
    const u16* __restrict__ qkv, float* __restrict__ ql, float* __restrict__ kl,
    u16* __restrict__ qlh, u16* __restrict__ klh)
{
  int m = blockIdx.x, h = blockIdx.y, d = threadIdx.x;
  const u16* base = qkv + (long long)(m * LSEG) * 1536 + h * DH + d;
  float sq = 0.f, sk = 0.f;
  for (int j = 0; j < LSEG; j++){
    sq += b2f(base[(long long)j * 1536]);
    sk += b2f(base[(long long)j * 1536 + 512]);
  }
  float qv = sq * (0.125f / 65.f);
  float kv = sk * (1.f / 65.f);
  int idx = (h * LM + m) * DH + d;
  ql[idx] = qv; kl[idx] = kv;
  qlh[idx] = f2b(qv); klh[idx] = f2b(kv);
}

// ---------------- softmax over rows of 256 f32 (in place) ----------------
__global__ __launch_bounds__(256) void softmax256_k(float* __restrict__ S)
{
  __shared__ float sm[4];
  int i = blockIdx.x, h = blockIdx.y, j = threadIdx.x;
  float* row = S + ((long long)h * LM + i) * 256;
  float v = row[j];
  float m = bredMax(v, sm);
  float e = __expf(v - m);
  float s = bredSum(e, sm);
  row[j] = e / s;
}

// ---------------- bf16 row exp (stable) + f32 rowsum, batched --------------
__global__ __launch_bounds__(256) void expbf_k(
    u16* __restrict__ S, float* __restrict__ rowsum, int ncols,
    long long sBatch, int nrows)
{
  __shared__ float sm[4];
  int row = blockIdx.x, zb = blockIdx.y, tid = threadIdx.x;
  u16* r = S + (long long)zb * sBatch + (long long)row * ncols;
  float lm = -3.0e38f;
  for (int j = tid; j < ncols; j += 256) lm = fmaxf(lm, b2f(r[j]));
  float m = bredMax(lm, sm);
  float ls = 0.f;
  for (int j = tid; j < ncols; j += 256){
    float e = __expf(b2f(r[j]) - m);
    r[j] = f2b(e);
    ls += e;
  }
  float s = bredSum(ls, sm);
  if (tid == 0) rowsum[(long long)zb * nrows + row] = s;
}

// ---------------- pinv scale factors ----------------
__global__ __launch_bounds__(256) void pinv_scal_k(
    const float* __restrict__ a2, float* __restrict__ scal)
{
  __shared__ float sm[4];
  int h = blockIdx.x, i = threadIdx.x;
  const float* Ah = a2 + (long long)h * 65536;
  float rs = 0.f, cs = 0.f;
  for (int j = 0; j < 256; j++){
    rs += fabsf(Ah[i * 256 + j]);
    cs += fabsf(Ah[j * 256 + i]);
  }
  float rmax = bredMax(rs, sm);
  __syncthreads();
  float cmax = bredMax(cs, sm);
  if (i == 0){
    atomicMax((int*)&scal[0], __float_as_int(rmax));
    atomicMax((int*)&scal[1], __float_as_int(cmax));
  }
}

__global__ __launch_bounds__(256) void z0_k(
    const float* __restrict__ a2, float* __restrict__ z, const float* __restrict__ scal)
{
  int j = blockIdx.x, h = blockIdx.y, i = threadIdx.x;
  float inv = 1.f / (scal[0] * scal[1]);
  z[((long long)h * LM + j) * 256 + i] = a2[((long long)h * LM + i) * 256 + j] * inv;
}

// ---------------- depthwise 33-tap residual conv (fully unrolled) ----------
__global__ __launch_bounds__(256) void resconv_k(
    const u16* __restrict__ qkv, const float* __restrict__ rw,
    u16* __restrict__ attn)
{
  int c = blockIdx.x * 256 + threadIdx.x;   // 0..511
  int s0 = blockIdx.y * 8;
  int h = c >> 6;
  float w[33];
#pragma unroll
  for (int t = 0; t < 33; t++) w[t] = rw[h * 33 + t];
  float vr[40];
#pragma unroll
  for (int j = 0; j < 40; j++){
    int s = s0 - 16 + j;
    vr[j] = (s >= 0 && s < NP) ? b2f(qkv[(long long)s * 1536 + 1024 + c]) : 0.f;
  }
#pragma unroll
  for (int i = 0; i < 8; i++){
    float a = 0.f;
#pragma unroll
    for (int t = 0; t < 33; t++) a = fmaf(vr[i + t], w[t], a);
    long long idx = (long long)(s0 + i) * CDIM + c;
    attn[idx] = f2b(b2f(attn[idx]) + a);
  }
}

// ---------------- f32 32x32 transpose ----------------
__global__ __launch_bounds__(256) void transpose_k(
    const float* __restrict__ in, float* __restrict__ out, int R, int Cc)
{
  __shared__ float t[32][33];
  int bx = blockIdx.x * 32, by = blockIdx.y * 32;
  int x = threadIdx.x & 31, y4 = threadIdx.x >> 5;
  for (int yy = y4; yy < 32; yy += 8){
    int r = by + yy, c = bx + x;
    if (r < R && c < Cc) t[yy][x] = in[(long long)r * Cc + c];
  }
  __syncthreads();
  for (int yy = y4; yy < 32; yy += 8){
    int r = bx + yy, c = by + x;
    if (r < Cc && c < R) out[(long long)r * R + c] = t[x][yy];
  }
}

// ---------------- fused PPEG ----------------
__global__ __launch_bounds__(256) void ppeg_k(
    const float* __restrict__ cf, float* __restrict__ yt,
    const float* __restrict__ w7, const float* __restrict__ b7,
    const float* __restrict__ w5, const float* __restrict__ b5,
    const float* __restrict__ w3, const float* __restrict__ b3)
{
  __shared__ float tile[22][23];
  int c = blockIdx.z;
  int ty0 = blockIdx.y * 16, tx0 = blockIdx.x * 16;
  const float* img = cf + (long long)c * 16384;
  for (int i = threadIdx.x; i < 22 * 22; i += 256){
    int yy = i / 22, xx = i - yy * 22;
    int gy = ty0 - 3 + yy, gx = tx0 - 3 + xx;
    tile[yy][xx] = (gy >= 0 && gy < 128 && gx >= 0 && gx < 128) ? img[gy * 128 + gx] : 0.f;
  }
  __syncthreads();
  int lx = threadIdx.x & 15, ly = threadIdx.x >> 4;
  float o = tile[ly + 3][lx + 3] + b7[c] + b5[c] + b3[c];
  const float* W7 = w7 + c * 49;
#pragma unroll
  for (int ky = 0; ky < 7; ky++)
#pragma unroll
    for (int kx = 0; kx < 7; kx++)
      o = fmaf(tile[ly + ky][lx + kx], W7[ky * 7 + kx], o);
  const float* W5 = w5 + c * 25;
#pragma unroll
  for (int ky = 0; ky < 5; ky++)
#pragma unroll
    for (int kx = 0; kx < 5; kx++)
      o = fmaf(tile[ly + 1 + ky][lx + 1 + kx], W5[ky * 5 + kx], o);
  const float* W3 = w3 + c * 9;
#pragma unroll
  for (int ky = 0; ky < 3; ky++)
#pragma unroll
    for (int kx = 0; kx < 3; kx++)
      o = fmaf(tile[ly + 2 + ky][lx + 2 + kx], W3[ky * 3 + kx], o);
  yt[(long long)c * 16384 + (ty0 + ly) * 128 + (tx0 + lx)] = o;
}

// ---------------- final: LN(h[0]) @ fc2 + b ----------------
__global__ __launch_bounds__(256) void final_k(
    const float* __restrict__ h, const float* __restrict__ g,
    const float* __restrict__ b, const float* __restrict__ w,
    const float* __restrict__ bias, float* __restrict__ out)
{
  __shared__ float sm[4];
  __shared__ float pj[256][4];
  int tid = threadIdx.x;
  float v0 = h[tid], v1 = h[tid + 256];
  float s = bredSum(v0 + v1, sm);
  float s2 = bredSum(v0 * v0 + v1 * v1, sm);
  float mean = s * (1.f / 512.f);
  float var = s2 * (1.f / 512.f) - mean * mean;
  float rstd = rsqrtf(var + 1e-5f);
  float n0 = (v0 - mean) * rstd * g[tid] + b[tid];
  float n1 = (v1 - mean) * rstd * g[tid + 256] + b[tid + 256];
#pragma unroll
  for (int j = 0; j < 4; j++)
    pj[tid][j] = n0 * w[tid * 4 + j] + n1 * w[(tid + 256) * 4 + j];
  __syncthreads();
  if (tid < 4){
    float acc = 0.f;
    for (int k = 0; k < 256; k++) acc += pj[k][tid];
    out[tid] = acc + bias[tid];
  }
}

// ===========================================================================
// host side
// ===========================================================================
static inline void gemmbf(hipStream_t st, const u16* A, const u16* B, void* C,
                          int M, int N, int K, int lda, int ldb, int ldc,
                          long long sA, long long sB, long long sC, int batch,
                          const float* bias, const float* rowdiv, int sRow,
                          float alpha, int flags, int ksplit)
{
  dim3 grid((N + 127) / 128, (M + 127) / 128, batch * ksplit);
  gemmbf_k<<<grid, 256, 0, st>>>(A, B, C, M, N, K, lda, ldb, ldc, sA, sB, sC,
                                 bias, rowdiv, sRow, alpha, flags, ksplit);
}

// workspace byte offsets (total 188,750,080 B = 180.0 MiB; 192.3 MiB known ok)
#define B_H     0LL
#define B_XQ    33556480LL
#define B_ATTN  50595840LL
#define B_QKV   67635200LL     /* also xb; also cf/yt for PPEG */
#define B_VT    118753280LL
#define B_SH    135792640LL    /* 4-head score slab: 4 * LM*NP or 4 * NP*LM bf16 */
#define B_QL    169871360LL
#define B_KL    170395648LL
#define B_QLH   170919936LL
#define B_KLH   171182080LL
#define B_A2    171444224LL
#define B_Z0    173541376LL
#define B_Z1    175638528LL
#define B_AZ    177735680LL
#define B_TA    179832832LL
#define B_TB    181929984LL
#define B_A3V   184027136LL
#define B_Z2    184551424LL
#define B_Z2T   185075712LL
#define B_RS    185337856LL
#define B_SCAL  185604096LL
#define B_W1T   185604352LL
#define B_WQT   186652928LL
#define B_WOT   188225792LL
#define WS_REQ  188750080LL

extern "C" void kernel_launch(void* const* d_in, const int* in_sizes, int n_in,
                              void* d_out, int out_size, void* d_ws, size_t ws_size,
                              hipStream_t stream)
{
  (void)in_sizes; (void)n_in; (void)out_size;
  if (ws_size < (size_t)WS_REQ) return;   // fail cleanly, not with a fault

  const float* x      = (const float*)d_in[0];
  const float* fc1_w  = (const float*)d_in[1];
  const float* fc1_b  = (const float*)d_in[2];
  const float* cls    = (const float*)d_in[3];
  const float* l_ng[2]  = {(const float*)d_in[4],  (const float*)d_in[10]};
  const float* l_nb[2]  = {(const float*)d_in[5],  (const float*)d_in[11]};
  const float* l_qkv[2] = {(const float*)d_in[6],  (const float*)d_in[12]};
  const float* l_ow[2]  = {(const float*)d_in[7],  (const float*)d_in[13]};
  const float* l_ob[2]  = {(const float*)d_in[8],  (const float*)d_in[14]};
  const float* l_rw[2]  = {(const float*)d_in[9],  (const float*)d_in[15]};
  const float* w7 = (const float*)d_in[16];
  const float* b7 = (const float*)d_in[17];
  const float* w5 = (const float*)d_in[18];
  const float* b5 = (const float*)d_in[19];
  const float* w3 = (const float*)d_in[20];
  const float* b3 = (const float*)d_in[21];
  const float* norm_g = (const float*)d_in[22];
  const float* norm_b = (const float*)d_in[23];
  const float* fc2_w  = (const float*)d_in[24];
  const float* fc2_b  = (const float*)d_in[25];
  float* out = (float*)d_out;

  char* WB = (char*)d_ws;
  float* h    = (float*)(WB + B_H);
  u16*   xq   = (u16*)(WB + B_XQ);
  u16*   attnb= (u16*)(WB + B_ATTN);
  u16*   qkvb = (u16*)(WB + B_QKV);
  u16*   xb   = (u16*)(WB + B_QKV);        // alias (dead before qkvb written)
  float* cf   = (float*)(WB + B_QKV);      // alias for PPEG
  float* yt   = (float*)(WB + B_QKV + 33554432LL);
  u16*   vT   = (u16*)(WB + B_VT);
  u16*   Sh   = (u16*)(WB + B_SH);
  float* ql   = (float*)(WB + B_QL);
  float* kl   = (float*)(WB + B_KL);
  u16*   qlh  = (u16*)(WB + B_QLH);
  u16*   klh  = (u16*)(WB + B_KLH);
  float* a2   = (float*)(WB + B_A2);
  float* z0b  = (float*)(WB + B_Z0);
  float* z1b  = (float*)(WB + B_Z1);
  float* az   = (float*)(WB + B_AZ);
  float* tA   = (float*)(WB + B_TA);
  float* tB   = (float*)(WB + B_TB);
  float* a3v  = (float*)(WB + B_A3V);
  float* Z2   = (float*)(WB + B_Z2);
  u16*   Z2T  = (u16*)(WB + B_Z2T);
  float* rs   = (float*)(WB + B_RS);
  float* scal = (float*)(WB + B_SCAL);
  u16*   w1T  = (u16*)(WB + B_W1T);
  u16*   wqT  = (u16*)(WB + B_WQT);
  u16*   woT  = (u16*)(WB + B_WOT);

  // ---- fc1: h[0]=cls; h[1..] = relu(x @ fc1_w + b) via bf16 MFMA ----
  copy_cls_k<<<1, 256, 0, stream>>>(cls, h);
  cvtbf_k<<<4096, 256, 0, stream>>>(x, xb, 16384LL * 1024);
  tcbf_k<<<dim3(16, 32, 1), 256, 0, stream>>>(fc1_w, w1T, 1024, 512, 512, 1024, 0, 0);
  gemmbf(stream, xb, w1T, h + CDIM, 16384, 512, 1024, 1024, 1024, 512,
         0, 0, 0, 1, fc1_b, nullptr, 0, 1.f, GB_RELU, 1);

  for (int L = 0; L < 2; L++){
    // xq = pad(LN(h)) in bf16
    ln_pad_k<<<NP, 256, 0, stream>>>(h, l_ng[L], l_nb[L], xq);
    // qkv (bf16 out)
    tcbf_k<<<dim3(48, 16, 1), 256, 0, stream>>>(l_qkv[L], wqT, 512, 1536, 1536, 512, 0, 0);
    gemmbf(stream, xq, wqT, qkvb, NP, 1536, 512, 512, 512, 1536,
           0, 0, 0, 1, nullptr, nullptr, 0, 1.f, GB_STOREBF, 1);
    // landmarks (f32 + bf16)
    landmark_k<<<dim3(LM, HEADS), 64, 0, stream>>>(qkvb, ql, kl, qlh, klh);
    // vT: per-head [64][NP] bf16
    tc16_k<<<dim3(2, 520, 8), 256, 0, stream>>>(qkvb + 1024, vT, NP, 64, 1536, NP,
                                                64, 64LL * NP);
    // a2 = softmax(ql @ kl^T) f32
    gemm_k<<<dim3(4, 4, 8), 256, 0, stream>>>(ql, kl, a2, LM, LM, DH, DH, DH, LM,
                                              16384, 16384, 65536, 1.f, GF_TRANSB);
    softmax256_k<<<dim3(LM, HEADS), 256, 0, stream>>>(a2);
    // pinv init + 6 Newton-Schulz iterations (f32)
    zero_k<<<1, 256, 0, stream>>>(scal, 2);
    pinv_scal_k<<<HEADS, 256, 0, stream>>>(a2, scal);
    z0_k<<<dim3(LM, HEADS), 256, 0, stream>>>(a2, z0b, scal);
    float* zc = z0b; float* za = z1b;
    dim3 bg(4, 4, HEADS);
    for (int it = 0; it < 6; it++){
      bgemm256_k<<<bg, 256, 0, stream>>>(a2, zc, az, 0.f, 1.f, 0.f);
      bgemm256_k<<<bg, 256, 0, stream>>>(az, az, tA, 15.f, 1.f, -7.f);
      bgemm256_k<<<bg, 256, 0, stream>>>(az, tA, tB, 13.f, -1.f, 0.f);
      bgemm256_k<<<bg, 256, 0, stream>>>(zc, tB, za, 0.f, 0.25f, 0.f);
      float* tmp = zc; zc = za; za = tmp;
    }
    // ---- S3 chain, 4 heads per launch: a3v = softmax(ql @ k^T) @ v ----
    zero_k<<<128, 256, 0, stream>>>(a3v, (long long)HEADS * LM * DH);
    for (int g = 0; g < 2; g++){
      int hb = g * 4;
      gemmbf(stream, qlh + hb * 16384, qkvb + 512 + hb * 64, Sh,
             LM, NP, DH, DH, 1536, NP, 16384, 64, (long long)LM * NP, 4,
             nullptr, nullptr, 0, 1.f, GB_STOREBF, 1);
      expbf_k<<<dim3(LM, 4), 256, 0, stream>>>(Sh, rs, NP, (long long)LM * NP, LM);
      gemmbf(stream, Sh, vT + (long long)hb * 64 * NP, a3v + hb * 16384,
             LM, DH, NP, NP, NP, DH,
             (long long)LM * NP, 64LL * NP, 16384, 4,
             nullptr, rs, LM, 1.f, GB_ATOMIC, 65);
    }
    // Z2 = pinv(a2) @ a3v (f32), then bf16 transpose per head
    gemm_k<<<dim3(1, 4, 8), 256, 0, stream>>>(zc, a3v, Z2, LM, DH, LM, LM, DH, DH,
                                              65536, 16384, 16384, 1.f, 0);
    tcbf_k<<<dim3(2, 8, 8), 256, 0, stream>>>(Z2, Z2T, 256, 64, 64, 256, 16384, 16384);
    // ---- S1 chain, 4 heads per launch: attn = softmax(q/8 @ kl^T) @ Z2 ----
    for (int g = 0; g < 2; g++){
      int hb = g * 4;
      gemmbf(stream, qkvb + hb * 64, klh + hb * 16384, Sh,
             NP, LM, DH, 1536, DH, LM, 64, 16384, (long long)NP * LM, 4,
             nullptr, nullptr, 0, 0.125f, GB_STOREBF, 1);
      expbf_k<<<dim3(NP, 4), 256, 0, stream>>>(Sh, rs, LM, (long long)NP * LM, NP);
      gemmbf(stream, Sh, Z2T + hb * 16384, attnb + hb * 64,
             NP, DH, LM, LM, LM, CDIM,
             (long long)NP * LM, 16384, 64, 4,
             nullptr, rs, NP, 1.f, GB_STOREBF, 1);
    }
    // attn += depthwise 33-tap conv of v
    resconv_k<<<dim3(2, NP / 8), 256, 0, stream>>>(qkvb, l_rw[L], attnb);
    // h += attn[-NT:] @ out_w + out_b  (bf16 MFMA, f32 accumulate into h)
    tcbf_k<<<dim3(16, 16, 1), 256, 0, stream>>>(l_ow[L], woT, 512, 512, 512, 512, 0, 0);
    gemmbf(stream, attnb + (long long)PAD * CDIM, woT, h, NT, CDIM, CDIM,
           CDIM, CDIM, CDIM, 0, 0, 0, 1, l_ob[L], nullptr, 0, 1.f, GB_ACCUM, 1);

    if (L == 0){
      // PPEG (f32) — cf/yt alias the now-dead qkvb/vT region
      transpose_k<<<dim3(16, 512), 256, 0, stream>>>(h + CDIM, cf, 16384, CDIM);
      ppeg_k<<<dim3(8, 8, CDIM), 256, 0, stream>>>(cf, yt, w7, b7, w5, b5, w3, b3);
      transpose_k<<<dim3(512, 16), 256, 0, stream>>>(yt, h + CDIM, CDIM, 16384);
    }
  }

  final_k<<<1, 256, 0, stream>>>(h, norm_g, norm_b, fc2_w, fc2_b, out);
}

// Round 5
// 2834.447 us; speedup vs baseline: 3.5541x; 1.0177x over previous
//
#include <hip/hip_runtime.h>

// ---------------------------------------------------------------------------
// TransMIL forward. Round 5: m97-style gemmbf (global_load_lds + XOR swizzle).
// B=1, N=16384, IN=1024, C=512, heads=8, dh=64, NT=16385, NP=16640,
// landmarks M=256, l=65, pinv iters=6 (f32), res conv k=33.
// ---------------------------------------------------------------------------

#define NT 16385
#define NP 16640
#define PAD 255
#define CDIM 512
#define HEADS 8
#define DH 64
#define LM 256
#define LSEG 65

typedef unsigned short u16;
typedef unsigned int u32;
typedef __attribute__((ext_vector_type(8))) short bf16x8;
typedef __attribute__((ext_vector_type(4))) float f32x4;

__device__ __forceinline__ u16 f2b(float f){
  u32 u = __float_as_uint(f);
  u32 r = (u + 0x7FFFu + ((u >> 16) & 1u)) >> 16;
  return (u16)r;
}
__device__ __forceinline__ float b2f(u16 h){ return __uint_as_float(((u32)h) << 16); }

// async global->LDS, 16 B per lane; lds dest = wave-uniform base + lane*16
__device__ __forceinline__ void gload16(const u16* g, u16* l){
  __builtin_amdgcn_global_load_lds(
      (const __attribute__((address_space(1))) u32*)g,
      (__attribute__((address_space(3))) u32*)l, 16, 0, 0);
}

// ---------------- reductions ----------------
__device__ __forceinline__ float wredSum(float v){
#pragma unroll
  for (int o = 32; o > 0; o >>= 1) v += __shfl_xor(v, o, 64);
  return v;
}
__device__ __forceinline__ float wredMax(float v){
#pragma unroll
  for (int o = 32; o > 0; o >>= 1) v = fmaxf(v, __shfl_xor(v, o, 64));
  return v;
}
__device__ __forceinline__ float bredSum(float v, float* sm){
  v = wredSum(v);
  int w = threadIdx.x >> 6, l = threadIdx.x & 63;
  __syncthreads();
  if (l == 0) sm[w] = v;
  __syncthreads();
  return sm[0] + sm[1] + sm[2] + sm[3];
}
__device__ __forceinline__ float bredMax(float v, float* sm){
  v = wredMax(v);
  int w = threadIdx.x >> 6, l = threadIdx.x & 63;
  __syncthreads();
  if (l == 0) sm[w] = v;
  __syncthreads();
  return fmaxf(fmaxf(sm[0], sm[1]), fmaxf(sm[2], sm[3]));
}

// ---------------- utility ----------------
__global__ __launch_bounds__(256) void zero_k(float* __restrict__ p, long long n){
  long long i = (long long)blockIdx.x * 256 + threadIdx.x;
  long long stride = (long long)gridDim.x * 256;
  for (; i < n; i += stride) p[i] = 0.f;
}
__global__ __launch_bounds__(256) void copy_cls_k(const float* __restrict__ cls,
                                                  float* __restrict__ h){
  h[threadIdx.x] = cls[threadIdx.x];
  h[threadIdx.x + 256] = cls[threadIdx.x + 256];
}
__global__ __launch_bounds__(256) void cvtbf_k(const float* __restrict__ in,
                                               u16* __restrict__ out, long long n){
  long long i = ((long long)blockIdx.x * 256 + threadIdx.x) * 4;
  long long stride = (long long)gridDim.x * 256 * 4;
  for (; i < n; i += stride){
    float4 v = *(const float4*)(in + i);
    out[i]     = f2b(v.x);
    out[i + 1] = f2b(v.y);
    out[i + 2] = f2b(v.z);
    out[i + 3] = f2b(v.w);
  }
}
// f32 [R][ldin] -> bf16 transposed [C][ldout]
__global__ __launch_bounds__(256) void tcbf_k(const float* __restrict__ in,
    u16* __restrict__ out, int R, int C, int ldin, int ldout,
    long long sIn, long long sOut){
  __shared__ float t[32][33];
  in += (long long)blockIdx.z * sIn; out += (long long)blockIdx.z * sOut;
  int c0 = blockIdx.x * 32, r0 = blockIdx.y * 32;
  int x = threadIdx.x & 31, y = threadIdx.x >> 5;
  for (int yy = y; yy < 32; yy += 8){
    int r = r0 + yy, c = c0 + x;
    if (r < R && c < C) t[yy][x] = in[(long long)r * ldin + c];
  }
  __syncthreads();
  for (int yy = y; yy < 32; yy += 8){
    int c = c0 + yy, r = r0 + x;
    if (c < C && r < R) out[(long long)c * ldout + r] = f2b(t[x][yy]);
  }
}
// bf16 [R][ldin] -> bf16 transposed [C][ldout]
__global__ __launch_bounds__(256) void tc16_k(const u16* __restrict__ in,
    u16* __restrict__ out, int R, int C, int ldin, int ldout,
    long long sIn, long long sOut){
  __shared__ u16 t[32][33];
  in += (long long)blockIdx.z * sIn; out += (long long)blockIdx.z * sOut;
  int c0 = blockIdx.x * 32, r0 = blockIdx.y * 32;
  int x = threadIdx.x & 31, y = threadIdx.x >> 5;
  for (int yy = y; yy < 32; yy += 8){
    int r = r0 + yy, c = c0 + x;
    if (r < R && c < C) t[yy][x] = in[(long long)r * ldin + c];
  }
  __syncthreads();
  for (int yy = y; yy < 32; yy += 8){
    int c = c0 + yy, r = r0 + x;
    if (c < C && r < R) out[(long long)c * ldout + r] = t[x][yy];
  }
}

// ---------------- bf16 MFMA GEMM (m97-style): C = alpha*A@B^T (+bias)(/rowdiv)
// A [M,K] bf16 lda; B [N,K] bf16 ldb. Tile 128x128, BK=64, 4 waves.
// LDS unpadded [128][64]; staging via global_load_lds w/ XOR column swizzle:
// LDS chunk c8 of row r holds global chunk c8^(r&7)  (chunk = 8 bf16 = 16 B).
// Fragment reads land 2-way bank aliased (free, m136).
#define GB_STOREBF 1
#define GB_RELU    2
#define GB_ACCUM   4
#define GB_ATOMIC  8

__global__ __launch_bounds__(256) void gemmbf_k(
    const u16* __restrict__ A, const u16* __restrict__ B, void* __restrict__ Cv,
    int M, int N, int K, int lda, int ldb, int ldc,
    long long sA, long long sB, long long sC,
    const float* __restrict__ bias, const float* __restrict__ rowdiv, int sRow,
    float alpha, int flags, int ksplit)
{
  __shared__ __align__(16) u16 As[128 * 64];
  __shared__ __align__(16) u16 Bs[128 * 64];
  int zb = blockIdx.z / ksplit;
  int ks = blockIdx.z - zb * ksplit;
  A += (long long)zb * sA; B += (long long)zb * sB;
  float* Cf = (float*)Cv + (long long)zb * sC;
  u16*   Ch = (u16*)Cv + (long long)zb * sC;
  int klen = K / ksplit;
  int kbeg = ks * klen, kend = kbeg + klen;
  int tid = threadIdx.x;
  int w = tid >> 6, l = tid & 63;
  int row0 = blockIdx.y * 128, col0 = blockIdx.x * 128;
  int r8 = l >> 3;                 // 0..7 row within 8-row staging slab
  int csrc = ((l & 7) ^ r8) * 8;   // swizzled source column (elems)
  f32x4 acc[2][8];
#pragma unroll
  for (int i = 0; i < 2; i++)
#pragma unroll
    for (int j = 0; j < 8; j++) acc[i][j] = (f32x4){0.f, 0.f, 0.f, 0.f};

  int mrow = l & 15, q = l >> 4;
  for (int k0 = kbeg; k0 < kend; k0 += 64){
#pragma unroll
    for (int c = 0; c < 4; c++){
      int r = w * 32 + c * 8;              // wave-uniform base row of slab
      int gm = row0 + r + r8; if (gm >= M) gm = M - 1;
      gload16(A + (long long)gm * lda + k0 + csrc, &As[r * 64]);
      int gn = col0 + r + r8; if (gn >= N) gn = N - 1;
      gload16(B + (long long)gn * ldb + k0 + csrc, &Bs[r * 64]);
    }
    __syncthreads();
#pragma unroll
    for (int ks2 = 0; ks2 < 2; ks2++){
      int kc = ks2 * 4 + q;                // global chunk wanted
      bf16x8 af[2], bfr[8];
#pragma unroll
      for (int i = 0; i < 2; i++){
        int r = w * 32 + i * 16 + mrow;
        af[i] = *(const bf16x8*)&As[r * 64 + ((kc ^ (r & 7)) * 8)];
      }
#pragma unroll
      for (int j = 0; j < 8; j++){
        int r = j * 16 + mrow;
        bfr[j] = *(const bf16x8*)&Bs[r * 64 + ((kc ^ (r & 7)) * 8)];
      }
#pragma unroll
      for (int i = 0; i < 2; i++)
#pragma unroll
        for (int j = 0; j < 8; j++)
          acc[i][j] = __builtin_amdgcn_mfma_f32_16x16x32_bf16(af[i], bfr[j], acc[i][j], 0, 0, 0);
    }
    __syncthreads();
  }
#pragma unroll
  for (int i = 0; i < 2; i++){
#pragma unroll
    for (int r = 0; r < 4; r++){
      int gm = row0 + w * 32 + i * 16 + q * 4 + r;
      if (gm >= M) continue;
      float rd = rowdiv ? rowdiv[(long long)zb * sRow + gm] : 1.f;
#pragma unroll
      for (int j = 0; j < 8; j++){
        int gn = col0 + j * 16 + mrow;
        if (gn >= N) continue;
        float v = alpha * acc[i][j][r];
        if (rowdiv) v /= rd;
        if (bias) v += bias[gn];
        if (flags & GB_RELU) v = fmaxf(v, 0.f);
        long long ci = (long long)gm * ldc + gn;
        if (flags & GB_ATOMIC) atomicAdd(&Cf[ci], v);
        else if (flags & GB_STOREBF) Ch[ci] = f2b(v);
        else if (flags & GB_ACCUM) Cf[ci] += v;
        else Cf[ci] = v;
      }
    }
  }
}

// ---------------- f32 GEMM (small: a2, Z2) ----------------
#define GF_TRANSB 1
__global__ __launch_bounds__(256) void gemm_k(
    const float* __restrict__ A, const float* __restrict__ B, float* __restrict__ C,
    int M, int N, int K, int lda, int ldb, int ldc,
    long long sA, long long sB, long long sC, float alpha, int flags)
{
  __shared__ __align__(16) float As[16][68];
  __shared__ __align__(16) float Bs[16][68];
  int zb = blockIdx.z;
  A += (long long)zb * sA; B += (long long)zb * sB; C += (long long)zb * sC;
  int tid = threadIdx.x;
  int tx = tid & 15, ty = tid >> 4;
  int row0 = blockIdx.y * 64, col0 = blockIdx.x * 64;
  float acc[4][4] = {};
  for (int k0 = 0; k0 < K; k0 += 16){
#pragma unroll
    for (int i = 0; i < 4; i++){
      int idx = tid + i * 256;
      int mm = idx >> 4, kk = idx & 15;
      int gm = row0 + mm;
      As[kk][mm] = (gm < M) ? A[(long long)gm * lda + (k0 + kk)] : 0.f;
    }
    if (!(flags & GF_TRANSB)){
#pragma unroll
      for (int i = 0; i < 4; i++){
        int idx = tid + i * 256;
        int kk = idx >> 6, nn = idx & 63;
        int gn = col0 + nn;
        Bs[kk][nn] = (gn < N) ? B[(long long)(k0 + kk) * ldb + gn] : 0.f;
      }
    } else {
#pragma unroll
      for (int i = 0; i < 4; i++){
        int idx = tid + i * 256;
        int nn = idx >> 4, kk = idx & 15;
        int gn = col0 + nn;
        Bs[kk][nn] = (gn < N) ? B[(long long)gn * ldb + (k0 + kk)] : 0.f;
      }
    }
    __syncthreads();
#pragma unroll
    for (int kk = 0; kk < 16; kk++){
      float4 av = *(const float4*)&As[kk][ty * 4];
      float4 bv = *(const float4*)&Bs[kk][tx * 4];
      float a[4] = {av.x, av.y, av.z, av.w};
      float b[4] = {bv.x, bv.y, bv.z, bv.w};
#pragma unroll
      for (int i = 0; i < 4; i++)
#pragma unroll
        for (int j = 0; j < 4; j++)
          acc[i][j] = fmaf(a[i], b[j], acc[i][j]);
    }
    __syncthreads();
  }
#pragma unroll
  for (int i = 0; i < 4; i++){
    int gm = row0 + ty * 4 + i;
    if (gm >= M) continue;
#pragma unroll
    for (int j = 0; j < 4; j++){
      int gn = col0 + tx * 4 + j;
      if (gn >= N) continue;
      C[(long long)gm * ldc + gn] = alpha * acc[i][j];
    }
  }
}

// ---------------- batched 256x256x256 f32 GEMM for pinv --------------------
__global__ __launch_bounds__(256) void bgemm256_k(
    const float* __restrict__ A, const float* __restrict__ B, float* __restrict__ C,
    float dterm, float sterm, float eterm)
{
  __shared__ __align__(16) float As[16][68];
  __shared__ __align__(16) float Bs[16][68];
  long long off = (long long)blockIdx.z << 16;
  A += off; B += off; C += off;
  int tid = threadIdx.x;
  int tx = tid & 15, ty = tid >> 4;
  int row0 = blockIdx.y * 64, col0 = blockIdx.x * 64;
  float acc[4][4] = {};
  for (int k0 = 0; k0 < 256; k0 += 16){
#pragma unroll
    for (int i = 0; i < 4; i++){
      int idx = tid + i * 256;
      int mm = idx >> 4, kk = idx & 15;
      As[kk][mm] = A[(row0 + mm) * 256 + k0 + kk];
    }
#pragma unroll
    for (int i = 0; i < 4; i++){
      int idx = tid + i * 256;
      int kk = idx >> 6, nn = idx & 63;
      Bs[kk][nn] = B[(k0 + kk) * 256 + col0 + nn];
    }
    __syncthreads();
#pragma unroll
    for (int kk = 0; kk < 16; kk++){
      float4 av = *(const float4*)&As[kk][ty * 4];
      float4 bv = *(const float4*)&Bs[kk][tx * 4];
      float a[4] = {av.x, av.y, av.z, av.w};
      float b[4] = {bv.x, bv.y, bv.z, bv.w};
#pragma unroll
      for (int i = 0; i < 4; i++)
#pragma unroll
        for (int j = 0; j < 4; j++)
          acc[i][j] = fmaf(a[i], b[j], acc[i][j]);
    }
    __syncthreads();
  }
#pragma unroll
  for (int i = 0; i < 4; i++){
    int gm = row0 + ty * 4 + i;
#pragma unroll
    for (int j = 0; j < 4; j++){
      int gn = col0 + tx * 4 + j;
      float v = sterm * acc[i][j] + eterm * A[gm * 256 + gn];
      if (gm == gn) v += dterm;
      C[gm * 256 + gn] = v;
    }
  }
}

// ---------------- layernorm + front-pad -> bf16 xq (NP x 512) --------------
__global__ __launch_bounds__(256) void ln_pad_k(
    const float* __restrict__ h, const float* __restrict__ g,
    const float* __restrict__ b, u16* __restrict__ out)
{
  __shared__ float sm[4];
  int row = blockIdx.x, tid = threadIdx.x;
  u16* o = out + (long long)row * CDIM;
  if (row < PAD){ o[tid] = 0; o[tid + 256] = 0; return; }
  const float* x = h + (long long)(row - PAD) * CDIM;
  float v0 = x[tid], v1 = x[tid + 256];
  float s = bredSum(v0 + v1, sm);
  float s2 = bredSum(v0 * v0 + v1 * v1, sm);
  float mean = s * (1.f / 512.f);
  float var = s2 * (1.f / 512.f) - mean * mean;
  float rstd = rsqrtf(var + 1e-5f);
  o[tid] = f2b((v0 - mean) * rstd * g[tid] + b[tid]);
  o[tid + 256] = f2b((v1 - mean) * rstd * g[tid + 256] + b[tid + 256]);
}

// ---------------- landmark means (q pre-scaled by 1/8) ----------------
__global__ __launch_bounds__(64) void landmark_k(
    const u16* __restrict__ qkv, float* __restrict__ ql, float* __restrict__ kl,
    u16* __restrict__ qlh, u16* __restrict__ klh)
{
  int m = blockIdx.x, h = blockIdx.y, d = threadIdx.x;
  const u16* base = qkv + (long long)(m * LSEG) * 1536 + h * DH + d;
  float sq = 0.f, sk = 0.f;
  for (int j = 0; j < LSEG; j++){
    sq += b2f(base[(long long)j * 1536]);
    sk += b2f(base[(long long)j * 1536 + 512]);
  }
  float qv = sq * (0.125f / 65.f);
  float kv = sk * (1.f / 65.f);
  int idx = (h * LM + m) * DH + d;
  ql[idx] = qv; kl[idx] = kv;
  qlh[idx] = f2b(qv); klh[idx] = f2b(kv);
}

// ---------------- softmax over rows of 256 f32 (in place) ----------------
__global__ __launch_bounds__(256) void softmax256_k(float* __restrict__ S)
{
  __shared__ float sm[4];
  int i = blockIdx.x, h = blockIdx.y, j = threadIdx.x;
  float* row = S + ((long long)h * LM + i) * 256;
  float v = row[j];
  float m = bredMax(v, sm);
  float e = __expf(v - m);
  float s = bredSum(e, sm);
  row[j] = e / s;
}

// ---------------- bf16 row exp (stable) + f32 rowsum, batched --------------
__global__ __launch_bounds__(256) void expbf_k(
    u16* __restrict__ S, float* __restrict__ rowsum, int ncols,
    long long sBatch, int nrows)
{
  __shared__ float sm[4];
  int row = blockIdx.x, zb = blockIdx.y, tid = threadIdx.x;
  u16* r = S + (long long)zb * sBatch + (long long)row * ncols;
  float lm = -3.0e38f;
  for (int j = tid; j < ncols; j += 256) lm = fmaxf(lm, b2f(r[j]));
  float m = bredMax(lm, sm);
  float ls = 0.f;
  for (int j = tid; j < ncols; j += 256){
    float e = __expf(b2f(r[j]) - m);
    r[j] = f2b(e);
    ls += e;
  }
  float s = bredSum(ls, sm);
  if (tid == 0) rowsum[(long long)zb * nrows + row] = s;
}

// ---------------- pinv scale factors ----------------
__global__ __launch_bounds__(256) void pinv_scal_k(
    const float* __restrict__ a2, float* __restrict__ scal)
{
  __shared__ float sm[4];
  int h = blockIdx.x, i = threadIdx.x;
  const float* Ah = a2 + (long long)h * 65536;
  float rs = 0.f, cs = 0.f;
  for (int j = 0; j < 256; j++){
    rs += fabsf(Ah[i * 256 + j]);
    cs += fabsf(Ah[j * 256 + i]);
  }
  float rmax = bredMax(rs, sm);
  __syncthreads();
  float cmax = bredMax(cs, sm);
  if (i == 0){
    atomicMax((int*)&scal[0], __float_as_int(rmax));
    atomicMax((int*)&scal[1], __float_as_int(cmax));
  }
}

__global__ __launch_bounds__(256) void z0_k(
    const float* __restrict__ a2, float* __restrict__ z, const float* __restrict__ scal)
{
  int j = blockIdx.x, h = blockIdx.y, i = threadIdx.x;
  float inv = 1.f / (scal[0] * scal[1]);
  z[((long long)h * LM + j) * 256 + i] = a2[((long long)h * LM + i) * 256 + j] * inv;
}

// ---------------- depthwise 33-tap residual conv (fully unrolled) ----------
__global__ __launch_bounds__(256) void resconv_k(
    const u16* __restrict__ qkv, const float* __restrict__ rw,
    u16* __restrict__ attn)
{
  int c = blockIdx.x * 256 + threadIdx.x;   // 0..511
  int s0 = blockIdx.y * 8;
  int h = c >> 6;
  float w[33];
#pragma unroll
  for (int t = 0; t < 33; t++) w[t] = rw[h * 33 + t];
  float vr[40];
#pragma unroll
  for (int j = 0; j < 40; j++){
    int s = s0 - 16 + j;
    vr[j] = (s >= 0 && s < NP) ? b2f(qkv[(long long)s * 1536 + 1024 + c]) : 0.f;
  }
#pragma unroll
  for (int i = 0; i < 8; i++){
    float a = 0.f;
#pragma unroll
    for (int t = 0; t < 33; t++) a = fmaf(vr[i + t], w[t], a);
    long long idx = (long long)(s0 + i) * CDIM + c;
    attn[idx] = f2b(b2f(attn[idx]) + a);
  }
}

// ---------------- f32 32x32 transpose ----------------
__global__ __launch_bounds__(256) void transpose_k(
    const float* __restrict__ in, float* __restrict__ out, int R, int Cc)
{
  __shared__ float t[32][33];
  int bx = blockIdx.x * 32, by = blockIdx.y * 32;
  int x = threadIdx.x & 31, y4 = threadIdx.x >> 5;
  for (int yy = y4; yy < 32; yy += 8){
    int r = by + yy, c = bx + x;
    if (r < R && c < Cc) t[yy][x] = in[(long long)r * Cc + c];
  }
  __syncthreads();
  for (int yy = y4; yy < 32; yy += 8){
    int r = bx + yy, c = by + x;
    if (r < Cc && c < R) out[(long long)r * R + c] = t[x][yy];
  }
}

// ---------------- fused PPEG ----------------
__global__ __launch_bounds__(256) void ppeg_k(
    const float* __restrict__ cf, float* __restrict__ yt,
    const float* __restrict__ w7, const float* __restrict__ b7,
    const float* __restrict__ w5, const float* __restrict__ b5,
    const float* __restrict__ w3, const float* __restrict__ b3)
{
  __shared__ float tile[22][23];
  int c = blockIdx.z;
  int ty0 = blockIdx.y * 16, tx0 = blockIdx.x * 16;
  const float* img = cf + (long long)c * 16384;
  for (int i = threadIdx.x; i < 22 * 22; i += 256){
    int yy = i / 22, xx = i - yy * 22;
    int gy = ty0 - 3 + yy, gx = tx0 - 3 + xx;
    tile[yy][xx] = (gy >= 0 && gy < 128 && gx >= 0 && gx < 128) ? img[gy * 128 + gx] : 0.f;
  }
  __syncthreads();
  int lx = threadIdx.x & 15, ly = threadIdx.x >> 4;
  float o = tile[ly + 3][lx + 3] + b7[c] + b5[c] + b3[c];
  const float* W7 = w7 + c * 49;
#pragma unroll
  for (int ky = 0; ky < 7; ky++)
#pragma unroll
    for (int kx = 0; kx < 7; kx++)
      o = fmaf(tile[ly + ky][lx + kx], W7[ky * 7 + kx], o);
  const float* W5 = w5 + c * 25;
#pragma unroll
  for (int ky = 0; ky < 5; ky++)
#pragma unroll
    for (int kx = 0; kx < 5; kx++)
      o = fmaf(tile[ly + 1 + ky][lx + 1 + kx], W5[ky * 5 + kx], o);
  const float* W3 = w3 + c * 9;
#pragma unroll
  for (int ky = 0; ky < 3; ky++)
#pragma unroll
    for (int kx = 0; kx < 3; kx++)
      o = fmaf(tile[ly + 2 + ky][lx + 2 + kx], W3[ky * 3 + kx], o);
  yt[(long long)c * 16384 + (ty0 + ly) * 128 + (tx0 + lx)] = o;
}

// ---------------- final: LN(h[0]) @ fc2 + b ----------------
__global__ __launch_bounds__(256) void final_k(
    const float* __restrict__ h, const float* __restrict__ g,
    const float* __restrict__ b, const float* __restrict__ w,
    const float* __restrict__ bias, float* __restrict__ out)
{
  __shared__ float sm[4];
  __shared__ float pj[256][4];
  int tid = threadIdx.x;
  float v0 = h[tid], v1 = h[tid + 256];
  float s = bredSum(v0 + v1, sm);
  float s2 = bredSum(v0 * v0 + v1 * v1, sm);
  float mean = s * (1.f / 512.f);
  float var = s2 * (1.f / 512.f) - mean * mean;
  float rstd = rsqrtf(var + 1e-5f);
  float n0 = (v0 - mean) * rstd * g[tid] + b[tid];
  float n1 = (v1 - mean) * rstd * g[tid + 256] + b[tid + 256];
#pragma unroll
  for (int j = 0; j < 4; j++)
    pj[tid][j] = n0 * w[tid * 4 + j] + n1 * w[(tid + 256) * 4 + j];
  __syncthreads();
  if (tid < 4){
    float acc = 0.f;
    for (int k = 0; k < 256; k++) acc += pj[k][tid];
    out[tid] = acc + bias[tid];
  }
}

// ===========================================================================
// host side
// ===========================================================================
static inline void gemmbf(hipStream_t st, const u16* A, const u16* B, void* C,
                          int M, int N, int K, int lda, int ldb, int ldc,
                          long long sA, long long sB, long long sC, int batch,
                          const float* bias, const float* rowdiv, int sRow,
                          float alpha, int flags, int ksplit)
{
  dim3 grid((N + 127) / 128, (M + 127) / 128, batch * ksplit);
  gemmbf_k<<<grid, 256, 0, st>>>(A, B, C, M, N, K, lda, ldb, ldc, sA, sB, sC,
                                 bias, rowdiv, sRow, alpha, flags, ksplit);
}

// workspace byte offsets (total 188,750,080 B = 180.0 MiB; 192.3 MiB known ok)
#define B_H     0LL
#define B_XQ    33556480LL
#define B_ATTN  50595840LL
#define B_QKV   67635200LL     /* also xb; also cf/yt for PPEG */
#define B_VT    118753280LL
#define B_SH    135792640LL    /* 4-head score slab */
#define B_QL    169871360LL
#define B_KL    170395648LL
#define B_QLH   170919936LL
#define B_KLH   171182080LL
#define B_A2    171444224LL
#define B_Z0    173541376LL
#define B_Z1    175638528LL
#define B_AZ    177735680LL
#define B_TA    179832832LL
#define B_TB    181929984LL
#define B_A3V   184027136LL
#define B_Z2    184551424LL
#define B_Z2T   185075712LL
#define B_RS    185337856LL
#define B_SCAL  185604096LL
#define B_W1T   185604352LL
#define B_WQT   186652928LL
#define B_WOT   188225792LL
#define WS_REQ  188750080LL

extern "C" void kernel_launch(void* const* d_in, const int* in_sizes, int n_in,
                              void* d_out, int out_size, void* d_ws, size_t ws_size,
                              hipStream_t stream)
{
  (void)in_sizes; (void)n_in; (void)out_size;
  if (ws_size < (size_t)WS_REQ) return;   // fail cleanly, not with a fault

  const float* x      = (const float*)d_in[0];
  const float* fc1_w  = (const float*)d_in[1];
  const float* fc1_b  = (const float*)d_in[2];
  const float* cls    = (const float*)d_in[3];
  const float* l_ng[2]  = {(const float*)d_in[4],  (const float*)d_in[10]};
  const float* l_nb[2]  = {(const float*)d_in[5],  (const float*)d_in[11]};
  const float* l_qkv[2] = {(const float*)d_in[6],  (const float*)d_in[12]};
  const float* l_ow[2]  = {(const float*)d_in[7],  (const float*)d_in[13]};
  const float* l_ob[2]  = {(const float*)d_in[8],  (const float*)d_in[14]};
  const float* l_rw[2]  = {(const float*)d_in[9],  (const float*)d_in[15]};
  const float* w7 = (const float*)d_in[16];
  const float* b7 = (const float*)d_in[17];
  const float* w5 = (const float*)d_in[18];
  const float* b5 = (const float*)d_in[19];
  const float* w3 = (const float*)d_in[20];
  const float* b3 = (const float*)d_in[21];
  const float* norm_g = (const float*)d_in[22];
  const float* norm_b = (const float*)d_in[23];
  const float* fc2_w  = (const float*)d_in[24];
  const float* fc2_b  = (const float*)d_in[25];
  float* out = (float*)d_out;

  char* WB = (char*)d_ws;
  float* h    = (float*)(WB + B_H);
  u16*   xq   = (u16*)(WB + B_XQ);
  u16*   attnb= (u16*)(WB + B_ATTN);
  u16*   qkvb = (u16*)(WB + B_QKV);
  u16*   xb   = (u16*)(WB + B_QKV);        // alias (dead before qkvb written)
  float* cf   = (float*)(WB + B_QKV);      // alias for PPEG
  float* yt   = (float*)(WB + B_QKV + 33554432LL);
  u16*   vT   = (u16*)(WB + B_VT);
  u16*   Sh   = (u16*)(WB + B_SH);
  float* ql   = (float*)(WB + B_QL);
  float* kl   = (float*)(WB + B_KL);
  u16*   qlh  = (u16*)(WB + B_QLH);
  u16*   klh  = (u16*)(WB + B_KLH);
  float* a2   = (float*)(WB + B_A2);
  float* z0b  = (float*)(WB + B_Z0);
  float* z1b  = (float*)(WB + B_Z1);
  float* az   = (float*)(WB + B_AZ);
  float* tA   = (float*)(WB + B_TA);
  float* tB   = (float*)(WB + B_TB);
  float* a3v  = (float*)(WB + B_A3V);
  float* Z2   = (float*)(WB + B_Z2);
  u16*   Z2T  = (u16*)(WB + B_Z2T);
  float* rs   = (float*)(WB + B_RS);
  float* scal = (float*)(WB + B_SCAL);
  u16*   w1T  = (u16*)(WB + B_W1T);
  u16*   wqT  = (u16*)(WB + B_WQT);
  u16*   woT  = (u16*)(WB + B_WOT);

  // ---- fc1: h[0]=cls; h[1..] = relu(x @ fc1_w + b) via bf16 MFMA ----
  copy_cls_k<<<1, 256, 0, stream>>>(cls, h);
  cvtbf_k<<<4096, 256, 0, stream>>>(x, xb, 16384LL * 1024);
  tcbf_k<<<dim3(16, 32, 1), 256, 0, stream>>>(fc1_w, w1T, 1024, 512, 512, 1024, 0, 0);
  gemmbf(stream, xb, w1T, h + CDIM, 16384, 512, 1024, 1024, 1024, 512,
         0, 0, 0, 1, fc1_b, nullptr, 0, 1.f, GB_RELU, 1);

  for (int L = 0; L < 2; L++){
    // xq = pad(LN(h)) in bf16
    ln_pad_k<<<NP, 256, 0, stream>>>(h, l_ng[L], l_nb[L], xq);
    // qkv (bf16 out)
    tcbf_k<<<dim3(48, 16, 1), 256, 0, stream>>>(l_qkv[L], wqT, 512, 1536, 1536, 512, 0, 0);
    gemmbf(stream, xq, wqT, qkvb, NP, 1536, 512, 512, 512, 1536,
           0, 0, 0, 1, nullptr, nullptr, 0, 1.f, GB_STOREBF, 1);
    // landmarks (f32 + bf16)
    landmark_k<<<dim3(LM, HEADS), 64, 0, stream>>>(qkvb, ql, kl, qlh, klh);
    // vT: per-head [64][NP] bf16
    tc16_k<<<dim3(2, 520, 8), 256, 0, stream>>>(qkvb + 1024, vT, NP, 64, 1536, NP,
                                                64, 64LL * NP);
    // a2 = softmax(ql @ kl^T) f32
    gemm_k<<<dim3(4, 4, 8), 256, 0, stream>>>(ql, kl, a2, LM, LM, DH, DH, DH, LM,
                                              16384, 16384, 65536, 1.f, GF_TRANSB);
    softmax256_k<<<dim3(LM, HEADS), 256, 0, stream>>>(a2);
    // pinv init + 6 Newton-Schulz iterations (f32)
    zero_k<<<1, 256, 0, stream>>>(scal, 2);
    pinv_scal_k<<<HEADS, 256, 0, stream>>>(a2, scal);
    z0_k<<<dim3(LM, HEADS), 256, 0, stream>>>(a2, z0b, scal);
    float* zc = z0b; float* za = z1b;
    dim3 bg(4, 4, HEADS);
    for (int it = 0; it < 6; it++){
      bgemm256_k<<<bg, 256, 0, stream>>>(a2, zc, az, 0.f, 1.f, 0.f);
      bgemm256_k<<<bg, 256, 0, stream>>>(az, az, tA, 15.f, 1.f, -7.f);
      bgemm256_k<<<bg, 256, 0, stream>>>(az, tA, tB, 13.f, -1.f, 0.f);
      bgemm256_k<<<bg, 256, 0, stream>>>(zc, tB, za, 0.f, 0.25f, 0.f);
      float* tmp = zc; zc = za; za = tmp;
    }
    // ---- S3 chain, 4 heads per launch: a3v = softmax(ql @ k^T) @ v ----
    zero_k<<<128, 256, 0, stream>>>(a3v, (long long)HEADS * LM * DH);
    for (int g = 0; g < 2; g++){
      int hb = g * 4;
      gemmbf(stream, qlh + hb * 16384, qkvb + 512 + hb * 64, Sh,
             LM, NP, DH, DH, 1536, NP, 16384, 64, (long long)LM * NP, 4,
             nullptr, nullptr, 0, 1.f, GB_STOREBF, 1);
      expbf_k<<<dim3(LM, 4), 256, 0, stream>>>(Sh, rs, NP, (long long)LM * NP, LM);
      gemmbf(stream, Sh, vT + (long long)hb * 64 * NP, a3v + hb * 16384,
             LM, DH, NP, NP, NP, DH,
             (long long)LM * NP, 64LL * NP, 16384, 4,
             nullptr, rs, LM, 1.f, GB_ATOMIC, 13);
    }
    // Z2 = pinv(a2) @ a3v (f32), then bf16 transpose per head
    gemm_k<<<dim3(1, 4, 8), 256, 0, stream>>>(zc, a3v, Z2, LM, DH, LM, LM, DH, DH,
                                              65536, 16384, 16384, 1.f, 0);
    tcbf_k<<<dim3(2, 8, 8), 256, 0, stream>>>(Z2, Z2T, 256, 64, 64, 256, 16384, 16384);
    // ---- S1 chain, 4 heads per launch: attn = softmax(q/8 @ kl^T) @ Z2 ----
    for (int g = 0; g < 2; g++){
      int hb = g * 4;
      gemmbf(stream, qkvb + hb * 64, klh + hb * 16384, Sh,
             NP, LM, DH, 1536, DH, LM, 64, 16384, (long long)NP * LM, 4,
             nullptr, nullptr, 0, 0.125f, GB_STOREBF, 1);
      expbf_k<<<dim3(NP, 4), 256, 0, stream>>>(Sh, rs, LM, (long long)NP * LM, NP);
      gemmbf(stream, Sh, Z2T + hb * 16384, attnb + hb * 64,
             NP, DH, LM, LM, LM, CDIM,
             (long long)NP * LM, 16384, 64, 4,
             nullptr, rs, NP, 1.f, GB_STOREBF, 1);
    }
    // attn += depthwise 33-tap conv of v
    resconv_k<<<dim3(2, NP / 8), 256, 0, stream>>>(qkvb, l_rw[L], attnb);
    // h += attn[-NT:] @ out_w + out_b  (bf16 MFMA, f32 accumulate into h)
    tcbf_k<<<dim3(16, 16, 1), 256, 0, stream>>>(l_ow[L], woT, 512, 512, 512, 512, 0, 0);
    gemmbf(stream, attnb + (long long)PAD * CDIM, woT, h, NT, CDIM, CDIM,
           CDIM, CDIM, CDIM, 0, 0, 0, 1, l_ob[L], nullptr, 0, 1.f, GB_ACCUM, 1);

    if (L == 0){
      // PPEG (f32) — cf/yt alias the now-dead qkvb/vT region
      transpose_k<<<dim3(16, 512), 256, 0, stream>>>(h + CDIM, cf, 16384, CDIM);
      ppeg_k<<<dim3(8, 8, CDIM), 256, 0, stream>>>(cf, yt, w7, b7, w5, b5, w3, b3);
      transpose_k<<<dim3(512, 16), 256, 0, stream>>>(yt, h + CDIM, CDIM, 16384);
    }
  }

  final_k<<<1, 256, 0, stream>>>(h, norm_g, norm_b, fc2_w, fc2_b, out);
}

// Round 6
// 2028.774 us; speedup vs baseline: 4.9655x; 1.3971x over previous
//
#include <hip/hip_runtime.h>

// ---------------------------------------------------------------------------
// TransMIL forward. Round 6: fused flash attention for S1/S3 chains.
// B=1, N=16384, IN=1024, C=512, heads=8, dh=64, NT=16385, NP=16640,
// landmarks M=256, l=65, pinv iters=6 (f32), res conv k=33.
// ---------------------------------------------------------------------------

#define NT 16385
#define NP 16640
#define PAD 255
#define CDIM 512
#define HEADS 8
#define DH 64
#define LM 256
#define LSEG 65

typedef unsigned short u16;
typedef unsigned int u32;
typedef __attribute__((ext_vector_type(8))) short bf16x8;
typedef __attribute__((ext_vector_type(4))) float f32x4;

__device__ __forceinline__ u16 f2b(float f){
  u32 u = __float_as_uint(f);
  u32 r = (u + 0x7FFFu + ((u >> 16) & 1u)) >> 16;
  return (u16)r;
}
__device__ __forceinline__ float b2f(u16 h){ return __uint_as_float(((u32)h) << 16); }

// async global->LDS, 16 B per lane; lds dest = wave-uniform base + lane*16
__device__ __forceinline__ void gload16(const u16* g, u16* l){
  __builtin_amdgcn_global_load_lds(
      (const __attribute__((address_space(1))) u32*)g,
      (__attribute__((address_space(3))) u32*)l, 16, 0, 0);
}

// ---------------- reductions ----------------
__device__ __forceinline__ float wredSum(float v){
#pragma unroll
  for (int o = 32; o > 0; o >>= 1) v += __shfl_xor(v, o, 64);
  return v;
}
__device__ __forceinline__ float wredMax(float v){
#pragma unroll
  for (int o = 32; o > 0; o >>= 1) v = fmaxf(v, __shfl_xor(v, o, 64));
  return v;
}
__device__ __forceinline__ float bredSum(float v, float* sm){
  v = wredSum(v);
  int w = threadIdx.x >> 6, l = threadIdx.x & 63;
  __syncthreads();
  if (l == 0) sm[w] = v;
  __syncthreads();
  return sm[0] + sm[1] + sm[2] + sm[3];
}
__device__ __forceinline__ float bredMax(float v, float* sm){
  v = wredMax(v);
  int w = threadIdx.x >> 6, l = threadIdx.x & 63;
  __syncthreads();
  if (l == 0) sm[w] = v;
  __syncthreads();
  return fmaxf(fmaxf(sm[0], sm[1]), fmaxf(sm[2], sm[3]));
}

// ---------------- utility ----------------
__global__ __launch_bounds__(256) void zero_k(float* __restrict__ p, long long n){
  long long i = (long long)blockIdx.x * 256 + threadIdx.x;
  long long stride = (long long)gridDim.x * 256;
  for (; i < n; i += stride) p[i] = 0.f;
}
__global__ __launch_bounds__(256) void copy_cls_k(const float* __restrict__ cls,
                                                  float* __restrict__ h){
  h[threadIdx.x] = cls[threadIdx.x];
  h[threadIdx.x + 256] = cls[threadIdx.x + 256];
}
__global__ __launch_bounds__(256) void cvtbf_k(const float* __restrict__ in,
                                               u16* __restrict__ out, long long n){
  long long i = ((long long)blockIdx.x * 256 + threadIdx.x) * 4;
  long long stride = (long long)gridDim.x * 256 * 4;
  for (; i < n; i += stride){
    float4 v = *(const float4*)(in + i);
    out[i]     = f2b(v.x);
    out[i + 1] = f2b(v.y);
    out[i + 2] = f2b(v.z);
    out[i + 3] = f2b(v.w);
  }
}
// f32 [R][ldin] -> bf16 transposed [C][ldout]
__global__ __launch_bounds__(256) void tcbf_k(const float* __restrict__ in,
    u16* __restrict__ out, int R, int C, int ldin, int ldout,
    long long sIn, long long sOut){
  __shared__ float t[32][33];
  in += (long long)blockIdx.z * sIn; out += (long long)blockIdx.z * sOut;
  int c0 = blockIdx.x * 32, r0 = blockIdx.y * 32;
  int x = threadIdx.x & 31, y = threadIdx.x >> 5;
  for (int yy = y; yy < 32; yy += 8){
    int r = r0 + yy, c = c0 + x;
    if (r < R && c < C) t[yy][x] = in[(long long)r * ldin + c];
  }
  __syncthreads();
  for (int yy = y; yy < 32; yy += 8){
    int c = c0 + yy, r = r0 + x;
    if (c < C && r < R) out[(long long)c * ldout + r] = f2b(t[x][yy]);
  }
}
// bf16 [R][ldin] -> bf16 transposed [C][ldout]
__global__ __launch_bounds__(256) void tc16_k(const u16* __restrict__ in,
    u16* __restrict__ out, int R, int C, int ldin, int ldout,
    long long sIn, long long sOut){
  __shared__ u16 t[32][33];
  in += (long long)blockIdx.z * sIn; out += (long long)blockIdx.z * sOut;
  int c0 = blockIdx.x * 32, r0 = blockIdx.y * 32;
  int x = threadIdx.x & 31, y = threadIdx.x >> 5;
  for (int yy = y; yy < 32; yy += 8){
    int r = r0 + yy, c = c0 + x;
    if (r < R && c < C) t[yy][x] = in[(long long)r * ldin + c];
  }
  __syncthreads();
  for (int yy = y; yy < 32; yy += 8){
    int c = c0 + yy, r = r0 + x;
    if (c < C && r < R) out[(long long)c * ldout + r] = t[x][yy];
  }
}

// ---------------- bf16 MFMA GEMM (m97-style): C = alpha*A@B^T (+bias)(/rowdiv)
#define GB_STOREBF 1
#define GB_RELU    2
#define GB_ACCUM   4
#define GB_ATOMIC  8
#define GB_QSCALE  16   /* multiply cols < 512 by 0.125 (q pre-scale, exact) */

__global__ __launch_bounds__(256) void gemmbf_k(
    const u16* __restrict__ A, const u16* __restrict__ B, void* __restrict__ Cv,
    int M, int N, int K, int lda, int ldb, int ldc,
    long long sA, long long sB, long long sC,
    const float* __restrict__ bias, const float* __restrict__ rowdiv, int sRow,
    float alpha, int flags, int ksplit)
{
  __shared__ __align__(16) u16 As[128 * 64];
  __shared__ __align__(16) u16 Bs[128 * 64];
  int zb = blockIdx.z / ksplit;
  int ks = blockIdx.z - zb * ksplit;
  A += (long long)zb * sA; B += (long long)zb * sB;
  float* Cf = (float*)Cv + (long long)zb * sC;
  u16*   Ch = (u16*)Cv + (long long)zb * sC;
  int klen = K / ksplit;
  int kbeg = ks * klen, kend = kbeg + klen;
  int tid = threadIdx.x;
  int w = tid >> 6, l = tid & 63;
  int row0 = blockIdx.y * 128, col0 = blockIdx.x * 128;
  int r8 = l >> 3;
  int csrc = ((l & 7) ^ r8) * 8;
  f32x4 acc[2][8];
#pragma unroll
  for (int i = 0; i < 2; i++)
#pragma unroll
    for (int j = 0; j < 8; j++) acc[i][j] = (f32x4){0.f, 0.f, 0.f, 0.f};

  int mrow = l & 15, q = l >> 4;
  for (int k0 = kbeg; k0 < kend; k0 += 64){
#pragma unroll
    for (int c = 0; c < 4; c++){
      int r = w * 32 + c * 8;
      int gm = row0 + r + r8; if (gm >= M) gm = M - 1;
      gload16(A + (long long)gm * lda + k0 + csrc, &As[r * 64]);
      int gn = col0 + r + r8; if (gn >= N) gn = N - 1;
      gload16(B + (long long)gn * ldb + k0 + csrc, &Bs[r * 64]);
    }
    __syncthreads();
#pragma unroll
    for (int ks2 = 0; ks2 < 2; ks2++){
      int kc = ks2 * 4 + q;
      bf16x8 af[2], bfr[8];
#pragma unroll
      for (int i = 0; i < 2; i++){
        int r = w * 32 + i * 16 + mrow;
        af[i] = *(const bf16x8*)&As[r * 64 + ((kc ^ (r & 7)) * 8)];
      }
#pragma unroll
      for (int j = 0; j < 8; j++){
        int r = j * 16 + mrow;
        bfr[j] = *(const bf16x8*)&Bs[r * 64 + ((kc ^ (r & 7)) * 8)];
      }
#pragma unroll
      for (int i = 0; i < 2; i++)
#pragma unroll
        for (int j = 0; j < 8; j++)
          acc[i][j] = __builtin_amdgcn_mfma_f32_16x16x32_bf16(af[i], bfr[j], acc[i][j], 0, 0, 0);
    }
    __syncthreads();
  }
#pragma unroll
  for (int i = 0; i < 2; i++){
#pragma unroll
    for (int r = 0; r < 4; r++){
      int gm = row0 + w * 32 + i * 16 + q * 4 + r;
      if (gm >= M) continue;
      float rd = rowdiv ? rowdiv[(long long)zb * sRow + gm] : 1.f;
#pragma unroll
      for (int j = 0; j < 8; j++){
        int gn = col0 + j * 16 + mrow;
        if (gn >= N) continue;
        float v = alpha * acc[i][j][r];
        if ((flags & GB_QSCALE) && gn < 512) v *= 0.125f;
        if (rowdiv) v /= rd;
        if (bias) v += bias[gn];
        if (flags & GB_RELU) v = fmaxf(v, 0.f);
        long long ci = (long long)gm * ldc + gn;
        if (flags & GB_ATOMIC) atomicAdd(&Cf[ci], v);
        else if (flags & GB_STOREBF) Ch[ci] = f2b(v);
        else if (flags & GB_ACCUM) Cf[ci] += v;
        else Cf[ci] = v;
      }
    }
  }
}

// ---------------- fused flash attention ----------------
// Per block: 64 query rows, loop over key tiles of 128.
// mode 0: exact softmax over keysPerChunk keys (grid.y==1), write bf16 out.
// mode 1: partial (O,m,l) per key-chunk for later combine.
__global__ __launch_bounds__(256) void fattn_k(
    const u16* __restrict__ Qp, int ldq,
    const u16* __restrict__ Kp, int ldk,
    const u16* __restrict__ Vp, int ldv,
    long long sQh, long long sKh, long long sVh,
    int keysPerChunk,
    u16* __restrict__ outB, int ldo,
    float* __restrict__ O3, float* __restrict__ ML3, int nchunks, int qrows,
    int mode)
{
  __shared__ u16 Qs[64][72];
  __shared__ u16 Ks[128][72];
  __shared__ u16 Vs[64][136];
  __shared__ u16 Ps[4][16][136];
  int tid = threadIdx.x;
  int w = tid >> 6, l = tid & 63;
  int mrow = l & 15, q8 = l >> 4;
  int qt = blockIdx.x, ch = blockIdx.y, h = blockIdx.z;
  const u16* Q = Qp + (long long)h * sQh;
  const u16* K = Kp + (long long)h * sKh;
  const u16* V = Vp + (long long)h * sVh;
  int q0 = qt * 64;
  for (int i = tid; i < 512; i += 256){
    int r = i >> 3, c = (i & 7) * 8;
    *(uint4*)&Qs[r][c] = *(const uint4*)(Q + (long long)(q0 + r) * ldq + c);
  }
  float m_st[4], l_st[4];
  f32x4 acc_o[4];
#pragma unroll
  for (int r = 0; r < 4; r++){
    m_st[r] = -3.0e38f; l_st[r] = 0.f;
    acc_o[r] = (f32x4){0.f, 0.f, 0.f, 0.f};
  }
  int kbase = ch * keysPerChunk;
  for (int kt = 0; kt < keysPerChunk; kt += 128){
    for (int i = tid; i < 1024; i += 256){
      int r = i >> 3, c = (i & 7) * 8;
      *(uint4*)&Ks[r][c] = *(const uint4*)(K + (long long)(kbase + kt + r) * ldk + c);
    }
    for (int i = tid; i < 1024; i += 256){
      int r = i >> 4, c = (i & 15) * 8;
      *(uint4*)&Vs[r][c] = *(const uint4*)(V + (long long)r * ldv + kbase + kt + c);
    }
    __syncthreads();
    // S tile: 16 q-rows (band w*16) x 128 keys
    f32x4 accs[8];
#pragma unroll
    for (int j = 0; j < 8; j++) accs[j] = (f32x4){0.f, 0.f, 0.f, 0.f};
#pragma unroll
    for (int ks2 = 0; ks2 < 2; ks2++){
      bf16x8 af = *(const bf16x8*)&Qs[w * 16 + mrow][ks2 * 32 + q8 * 8];
#pragma unroll
      for (int j = 0; j < 8; j++){
        bf16x8 bfv = *(const bf16x8*)&Ks[j * 16 + mrow][ks2 * 32 + q8 * 8];
        accs[j] = __builtin_amdgcn_mfma_f32_16x16x32_bf16(af, bfv, accs[j], 0, 0, 0);
      }
    }
    // online softmax per row (row = q8*4 + r, cols across lanes&15 and j)
#pragma unroll
    for (int r = 0; r < 4; r++){
      float tm = -3.0e38f;
#pragma unroll
      for (int j = 0; j < 8; j++) tm = fmaxf(tm, accs[j][r]);
      tm = fmaxf(tm, __shfl_xor(tm, 1, 64));
      tm = fmaxf(tm, __shfl_xor(tm, 2, 64));
      tm = fmaxf(tm, __shfl_xor(tm, 4, 64));
      tm = fmaxf(tm, __shfl_xor(tm, 8, 64));
      float mn = fmaxf(m_st[r], tm);
      float al = __expf(m_st[r] - mn);
      m_st[r] = mn;
      float rs = 0.f;
#pragma unroll
      for (int j = 0; j < 8; j++){
        float e = __expf(accs[j][r] - mn);
        accs[j][r] = e;
        rs += e;
      }
      rs += __shfl_xor(rs, 1, 64);
      rs += __shfl_xor(rs, 2, 64);
      rs += __shfl_xor(rs, 4, 64);
      rs += __shfl_xor(rs, 8, 64);
      l_st[r] = al * l_st[r] + rs;
#pragma unroll
      for (int j = 0; j < 4; j++) acc_o[j][r] *= al;
    }
    // P (bf16) to per-wave LDS band: C-layout -> A-layout round trip
#pragma unroll
    for (int j = 0; j < 8; j++)
#pragma unroll
      for (int r = 0; r < 4; r++)
        Ps[w][q8 * 4 + r][j * 16 + mrow] = f2b(accs[j][r]);
    __syncthreads();
    // PV accumulate: A = Ps band (16 x 128), B = Vs (64 x 128)
#pragma unroll
    for (int kc = 0; kc < 4; kc++){
      bf16x8 af = *(const bf16x8*)&Ps[w][mrow][kc * 32 + q8 * 8];
#pragma unroll
      for (int j = 0; j < 4; j++){
        bf16x8 bfv = *(const bf16x8*)&Vs[j * 16 + mrow][kc * 32 + q8 * 8];
        acc_o[j] = __builtin_amdgcn_mfma_f32_16x16x32_bf16(af, bfv, acc_o[j], 0, 0, 0);
      }
    }
    __syncthreads();
  }
  if (mode == 0){
#pragma unroll
    for (int r = 0; r < 4; r++){
      int grow = q0 + w * 16 + q8 * 4 + r;
      float inv = 1.f / l_st[r];
#pragma unroll
      for (int j = 0; j < 4; j++)
        outB[(long long)grow * ldo + h * 64 + j * 16 + mrow] = f2b(acc_o[j][r] * inv);
    }
  } else {
#pragma unroll
    for (int r = 0; r < 4; r++){
      int row = q0 + w * 16 + q8 * 4 + r;
      long long b = ((long long)h * nchunks + ch) * qrows + row;
#pragma unroll
      for (int j = 0; j < 4; j++)
        O3[b * 64 + j * 16 + mrow] = acc_o[j][r];
      if (mrow == 0){
        ML3[b * 2] = m_st[r];
        ML3[b * 2 + 1] = l_st[r];
      }
    }
  }
}

// combine S3 partials: a3v = (sum_c e^{m_c-m*} O_c) / (sum_c e^{m_c-m*} l_c)
__global__ __launch_bounds__(256) void comb3_k(
    const float* __restrict__ O3, const float* __restrict__ ML3,
    float* __restrict__ a3v)
{
  int h = blockIdx.y;
  int row = blockIdx.x * 4 + (threadIdx.x >> 6);
  int d = threadIdx.x & 63;
  float m = -3.0e38f;
  for (int c = 0; c < 13; c++)
    m = fmaxf(m, ML3[(((long long)h * 13 + c) * 256 + row) * 2]);
  float l = 0.f, o = 0.f;
  for (int c = 0; c < 13; c++){
    long long b = ((long long)h * 13 + c) * 256 + row;
    float wgt = __expf(ML3[b * 2] - m);
    l += wgt * ML3[b * 2 + 1];
    o += wgt * O3[b * 64 + d];
  }
  a3v[((long long)h * 256 + row) * 64 + d] = o / l;
}

// ---------------- f32 GEMM (small: a2, Z2) ----------------
#define GF_TRANSB 1
__global__ __launch_bounds__(256) void gemm_k(
    const float* __restrict__ A, const float* __restrict__ B, float* __restrict__ C,
    int M, int N, int K, int lda, int ldb, int ldc,
    long long sA, long long sB, long long sC, float alpha, int flags)
{
  __shared__ __align__(16) float As[16][68];
  __shared__ __align__(16) float Bs[16][68];
  int zb = blockIdx.z;
  A += (long long)zb * sA; B += (long long)zb * sB; C += (long long)zb * sC;
  int tid = threadIdx.x;
  int tx = tid & 15, ty = tid >> 4;
  int row0 = blockIdx.y * 64, col0 = blockIdx.x * 64;
  float acc[4][4] = {};
  for (int k0 = 0; k0 < K; k0 += 16){
#pragma unroll
    for (int i = 0; i < 4; i++){
      int idx = tid + i * 256;
      int mm = idx >> 4, kk = idx & 15;
      int gm = row0 + mm;
      As[kk][mm] = (gm < M) ? A[(long long)gm * lda + (k0 + kk)] : 0.f;
    }
    if (!(flags & GF_TRANSB)){
#pragma unroll
      for (int i = 0; i < 4; i++){
        int idx = tid + i * 256;
        int kk = idx >> 6, nn = idx & 63;
        int gn = col0 + nn;
        Bs[kk][nn] = (gn < N) ? B[(long long)(k0 + kk) * ldb + gn] : 0.f;
      }
    } else {
#pragma unroll
      for (int i = 0; i < 4; i++){
        int idx = tid + i * 256;
        int nn = idx >> 4, kk = idx & 15;
        int gn = col0 + nn;
        Bs[kk][nn] = (gn < N) ? B[(long long)gn * ldb + (k0 + kk)] : 0.f;
      }
    }
    __syncthreads();
#pragma unroll
    for (int kk = 0; kk < 16; kk++){
      float4 av = *(const float4*)&As[kk][ty * 4];
      float4 bv = *(const float4*)&Bs[kk][tx * 4];
      float a[4] = {av.x, av.y, av.z, av.w};
      float b[4] = {bv.x, bv.y, bv.z, bv.w};
#pragma unroll
      for (int i = 0; i < 4; i++)
#pragma unroll
        for (int j = 0; j < 4; j++)
          acc[i][j] = fmaf(a[i], b[j], acc[i][j]);
    }
    __syncthreads();
  }
#pragma unroll
  for (int i = 0; i < 4; i++){
    int gm = row0 + ty * 4 + i;
    if (gm >= M) continue;
#pragma unroll
    for (int j = 0; j < 4; j++){
      int gn = col0 + tx * 4 + j;
      if (gn >= N) continue;
      C[(long long)gm * ldc + gn] = alpha * acc[i][j];
    }
  }
}

// ---------------- batched 256x256x256 f32 GEMM for pinv --------------------
__global__ __launch_bounds__(256) void bgemm256_k(
    const float* __restrict__ A, const float* __restrict__ B, float* __restrict__ C,
    float dterm, float sterm, float eterm)
{
  __shared__ __align__(16) float As[16][68];
  __shared__ __align__(16) float Bs[16][68];
  long long off = (long long)blockIdx.z << 16;
  A += off; B += off; C += off;
  int tid = threadIdx.x;
  int tx = tid & 15, ty = tid >> 4;
  int row0 = blockIdx.y * 64, col0 = blockIdx.x * 64;
  float acc[4][4] = {};
  for (int k0 = 0; k0 < 256; k0 += 16){
#pragma unroll
    for (int i = 0; i < 4; i++){
      int idx = tid + i * 256;
      int mm = idx >> 4, kk = idx & 15;
      As[kk][mm] = A[(row0 + mm) * 256 + k0 + kk];
    }
#pragma unroll
    for (int i = 0; i < 4; i++){
      int idx = tid + i * 256;
      int kk = idx >> 6, nn = idx & 63;
      Bs[kk][nn] = B[(k0 + kk) * 256 + col0 + nn];
    }
    __syncthreads();
#pragma unroll
    for (int kk = 0; kk < 16; kk++){
      float4 av = *(const float4*)&As[kk][ty * 4];
      float4 bv = *(const float4*)&Bs[kk][tx * 4];
      float a[4] = {av.x, av.y, av.z, av.w};
      float b[4] = {bv.x, bv.y, bv.z, bv.w};
#pragma unroll
      for (int i = 0; i < 4; i++)
#pragma unroll
        for (int j = 0; j < 4; j++)
          acc[i][j] = fmaf(a[i], b[j], acc[i][j]);
    }
    __syncthreads();
  }
#pragma unroll
  for (int i = 0; i < 4; i++){
    int gm = row0 + ty * 4 + i;
#pragma unroll
    for (int j = 0; j < 4; j++){
      int gn = col0 + tx * 4 + j;
      float v = sterm * acc[i][j] + eterm * A[gm * 256 + gn];
      if (gm == gn) v += dterm;
      C[gm * 256 + gn] = v;
    }
  }
}

// ---------------- layernorm + front-pad -> bf16 xq (NP x 512) --------------
__global__ __launch_bounds__(256) void ln_pad_k(
    const float* __restrict__ h, const float* __restrict__ g,
    const float* __restrict__ b, u16* __restrict__ out)
{
  __shared__ float sm[4];
  int row = blockIdx.x, tid = threadIdx.x;
  u16* o = out + (long long)row * CDIM;
  if (row < PAD){ o[tid] = 0; o[tid + 256] = 0; return; }
  const float* x = h + (long long)(row - PAD) * CDIM;
  float v0 = x[tid], v1 = x[tid + 256];
  float s = bredSum(v0 + v1, sm);
  float s2 = bredSum(v0 * v0 + v1 * v1, sm);
  float mean = s * (1.f / 512.f);
  float var = s2 * (1.f / 512.f) - mean * mean;
  float rstd = rsqrtf(var + 1e-5f);
  o[tid] = f2b((v0 - mean) * rstd * g[tid] + b[tid]);
  o[tid + 256] = f2b((v1 - mean) * rstd * g[tid + 256] + b[tid + 256]);
}

// ---------------- landmark means (q already pre-scaled by 0.125) -----------
__global__ __launch_bounds__(64) void landmark_k(
    const u16* __restrict__ qkv, float* __restrict__ ql, float* __restrict__ kl,
    u16* __restrict__ qlh, u16* __restrict__ klh)
{
  int m = blockIdx.x, h = blockIdx.y, d = threadIdx.x;
  const u16* base = qkv + (long long)(m * LSEG) * 1536 + h * DH + d;
  float sq = 0.f, sk = 0.f;
  for (int j = 0; j < LSEG; j++){
    sq += b2f(base[(long long)j * 1536]);
    sk += b2f(base[(long long)j * 1536 + 512]);
  }
  float qv = sq * (1.f / 65.f);
  float kv = sk * (1.f / 65.f);
  int idx = (h * LM + m) * DH + d;
  ql[idx] = qv; kl[idx] = kv;
  qlh[idx] = f2b(qv); klh[idx] = f2b(kv);
}

// ---------------- softmax over rows of 256 f32 (in place) ----------------
__global__ __launch_bounds__(256) void softmax256_k(float* __restrict__ S)
{
  __shared__ float sm[4];
  int i = blockIdx.x, h = blockIdx.y, j = threadIdx.x;
  float* row = S + ((long long)h * LM + i) * 256;
  float v = row[j];
  float m = bredMax(v, sm);
  float e = __expf(v - m);
  float s = bredSum(e, sm);
  row[j] = e / s;
}

// ---------------- pinv scale factors ----------------
__global__ __launch_bounds__(256) void pinv_scal_k(
    const float* __restrict__ a2, float* __restrict__ scal)
{
  __shared__ float sm[4];
  int h = blockIdx.x, i = threadIdx.x;
  const float* Ah = a2 + (long long)h * 65536;
  float rs = 0.f, cs = 0.f;
  for (int j = 0; j < 256; j++){
    rs += fabsf(Ah[i * 256 + j]);
    cs += fabsf(Ah[j * 256 + i]);
  }
  float rmax = bredMax(rs, sm);
  __syncthreads();
  float cmax = bredMax(cs, sm);
  if (i == 0){
    atomicMax((int*)&scal[0], __float_as_int(rmax));
    atomicMax((int*)&scal[1], __float_as_int(cmax));
  }
}

__global__ __launch_bounds__(256) void z0_k(
    const float* __restrict__ a2, float* __restrict__ z, const float* __restrict__ scal)
{
  int j = blockIdx.x, h = blockIdx.y, i = threadIdx.x;
  float inv = 1.f / (scal[0] * scal[1]);
  z[((long long)h * LM + j) * 256 + i] = a2[((long long)h * LM + i) * 256 + j] * inv;
}

// ---------------- depthwise 33-tap residual conv (fully unrolled) ----------
__global__ __launch_bounds__(256) void resconv_k(
    const u16* __restrict__ qkv, const float* __restrict__ rw,
    u16* __restrict__ attn)
{
  int c = blockIdx.x * 256 + threadIdx.x;
  int s0 = blockIdx.y * 8;
  int h = c >> 6;
  float w[33];
#pragma unroll
  for (int t = 0; t < 33; t++) w[t] = rw[h * 33 + t];
  float vr[40];
#pragma unroll
  for (int j = 0; j < 40; j++){
    int s = s0 - 16 + j;
    vr[j] = (s >= 0 && s < NP) ? b2f(qkv[(long long)s * 1536 + 1024 + c]) : 0.f;
  }
#pragma unroll
  for (int i = 0; i < 8; i++){
    float a = 0.f;
#pragma unroll
    for (int t = 0; t < 33; t++) a = fmaf(vr[i + t], w[t], a);
    long long idx = (long long)(s0 + i) * CDIM + c;
    attn[idx] = f2b(b2f(attn[idx]) + a);
  }
}

// ---------------- f32 32x32 transpose ----------------
__global__ __launch_bounds__(256) void transpose_k(
    const float* __restrict__ in, float* __restrict__ out, int R, int Cc)
{
  __shared__ float t[32][33];
  int bx = blockIdx.x * 32, by = blockIdx.y * 32;
  int x = threadIdx.x & 31, y4 = threadIdx.x >> 5;
  for (int yy = y4; yy < 32; yy += 8){
    int r = by + yy, c = bx + x;
    if (r < R && c < Cc) t[yy][x] = in[(long long)r * Cc + c];
  }
  __syncthreads();
  for (int yy = y4; yy < 32; yy += 8){
    int r = bx + yy, c = by + x;
    if (r < Cc && c < R) out[(long long)r * R + c] = t[x][yy];
  }
}

// ---------------- fused PPEG ----------------
__global__ __launch_bounds__(256) void ppeg_k(
    const float* __restrict__ cf, float* __restrict__ yt,
    const float* __restrict__ w7, const float* __restrict__ b7,
    const float* __restrict__ w5, const float* __restrict__ b5,
    const float* __restrict__ w3, const float* __restrict__ b3)
{
  __shared__ float tile[22][23];
  int c = blockIdx.z;
  int ty0 = blockIdx.y * 16, tx0 = blockIdx.x * 16;
  const float* img = cf + (long long)c * 16384;
  for (int i = threadIdx.x; i < 22 * 22; i += 256){
    int yy = i / 22, xx = i - yy * 22;
    int gy = ty0 - 3 + yy, gx = tx0 - 3 + xx;
    tile[yy][xx] = (gy >= 0 && gy < 128 && gx >= 0 && gx < 128) ? img[gy * 128 + gx] : 0.f;
  }
  __syncthreads();
  int lx = threadIdx.x & 15, ly = threadIdx.x >> 4;
  float o = tile[ly + 3][lx + 3] + b7[c] + b5[c] + b3[c];
  const float* W7 = w7 + c * 49;
#pragma unroll
  for (int ky = 0; ky < 7; ky++)
#pragma unroll
    for (int kx = 0; kx < 7; kx++)
      o = fmaf(tile[ly + ky][lx + kx], W7[ky * 7 + kx], o);
  const float* W5 = w5 + c * 25;
#pragma unroll
  for (int ky = 0; ky < 5; ky++)
#pragma unroll
    for (int kx = 0; kx < 5; kx++)
      o = fmaf(tile[ly + 1 + ky][lx + 1 + kx], W5[ky * 5 + kx], o);
  const float* W3 = w3 + c * 9;
#pragma unroll
  for (int ky = 0; ky < 3; ky++)
#pragma unroll
    for (int kx = 0; kx < 3; kx++)
      o = fmaf(tile[ly + 2 + ky][lx + 2 + kx], W3[ky * 3 + kx], o);
  yt[(long long)c * 16384 + (ty0 + ly) * 128 + (tx0 + lx)] = o;
}

// ---------------- final: LN(h[0]) @ fc2 + b ----------------
__global__ __launch_bounds__(256) void final_k(
    const float* __restrict__ h, const float* __restrict__ g,
    const float* __restrict__ b, const float* __restrict__ w,
    const float* __restrict__ bias, float* __restrict__ out)
{
  __shared__ float sm[4];
  __shared__ float pj[256][4];
  int tid = threadIdx.x;
  float v0 = h[tid], v1 = h[tid + 256];
  float s = bredSum(v0 + v1, sm);
  float s2 = bredSum(v0 * v0 + v1 * v1, sm);
  float mean = s * (1.f / 512.f);
  float var = s2 * (1.f / 512.f) - mean * mean;
  float rstd = rsqrtf(var + 1e-5f);
  float n0 = (v0 - mean) * rstd * g[tid] + b[tid];
  float n1 = (v1 - mean) * rstd * g[tid + 256] + b[tid + 256];
#pragma unroll
  for (int j = 0; j < 4; j++)
    pj[tid][j] = n0 * w[tid * 4 + j] + n1 * w[(tid + 256) * 4 + j];
  __syncthreads();
  if (tid < 4){
    float acc = 0.f;
    for (int k = 0; k < 256; k++) acc += pj[k][tid];
    out[tid] = acc + bias[tid];
  }
}

// ===========================================================================
// host side
// ===========================================================================
static inline void gemmbf(hipStream_t st, const u16* A, const u16* B, void* C,
                          int M, int N, int K, int lda, int ldb, int ldc,
                          long long sA, long long sB, long long sC, int batch,
                          const float* bias, const float* rowdiv, int sRow,
                          float alpha, int flags, int ksplit)
{
  dim3 grid((N + 127) / 128, (M + 127) / 128, batch * ksplit);
  gemmbf_k<<<grid, 256, 0, st>>>(A, B, C, M, N, K, lda, ldb, ldc, sA, sB, sC,
                                 bias, rowdiv, sRow, alpha, flags, ksplit);
}

// workspace byte offsets
#define B_H     0LL
#define B_XQ    33556480LL
#define B_ATTN  50595840LL
#define B_QKV   67635200LL     /* also xb; also cf/yt for PPEG */
#define B_VT    118753280LL
#define B_O3    135792640LL    /* 8*13*256*64 f32 = 6,815,744 B */
#define B_ML3   142608384LL    /* 8*13*256*2 f32 = 425,984 B */
#define B_QL    169871360LL
#define B_KL    170395648LL
#define B_QLH   170919936LL
#define B_KLH   171182080LL
#define B_A2    171444224LL
#define B_Z0    173541376LL
#define B_Z1    175638528LL
#define B_AZ    177735680LL
#define B_TA    179832832LL
#define B_TB    181929984LL
#define B_A3V   184027136LL
#define B_Z2    184551424LL
#define B_Z2T   185075712LL
#define B_RS    185337856LL
#define B_SCAL  185604096LL
#define B_W1T   185604352LL
#define B_WQT   186652928LL
#define B_WOT   188225792LL
#define WS_REQ  188750080LL

extern "C" void kernel_launch(void* const* d_in, const int* in_sizes, int n_in,
                              void* d_out, int out_size, void* d_ws, size_t ws_size,
                              hipStream_t stream)
{
  (void)in_sizes; (void)n_in; (void)out_size;
  if (ws_size < (size_t)WS_REQ) return;

  const float* x      = (const float*)d_in[0];
  const float* fc1_w  = (const float*)d_in[1];
  const float* fc1_b  = (const float*)d_in[2];
  const float* cls    = (const float*)d_in[3];
  const float* l_ng[2]  = {(const float*)d_in[4],  (const float*)d_in[10]};
  const float* l_nb[2]  = {(const float*)d_in[5],  (const float*)d_in[11]};
  const float* l_qkv[2] = {(const float*)d_in[6],  (const float*)d_in[12]};
  const float* l_ow[2]  = {(const float*)d_in[7],  (const float*)d_in[13]};
  const float* l_ob[2]  = {(const float*)d_in[8],  (const float*)d_in[14]};
  const float* l_rw[2]  = {(const float*)d_in[9],  (const float*)d_in[15]};
  const float* w7 = (const float*)d_in[16];
  const float* b7 = (const float*)d_in[17];
  const float* w5 = (const float*)d_in[18];
  const float* b5 = (const float*)d_in[19];
  const float* w3 = (const float*)d_in[20];
  const float* b3 = (const float*)d_in[21];
  const float* norm_g = (const float*)d_in[22];
  const float* norm_b = (const float*)d_in[23];
  const float* fc2_w  = (const float*)d_in[24];
  const float* fc2_b  = (const float*)d_in[25];
  float* out = (float*)d_out;

  char* WB = (char*)d_ws;
  float* h    = (float*)(WB + B_H);
  u16*   xq   = (u16*)(WB + B_XQ);
  u16*   attnb= (u16*)(WB + B_ATTN);
  u16*   qkvb = (u16*)(WB + B_QKV);
  u16*   xb   = (u16*)(WB + B_QKV);
  float* cf   = (float*)(WB + B_QKV);
  float* yt   = (float*)(WB + B_QKV + 33554432LL);
  u16*   vT   = (u16*)(WB + B_VT);
  float* O3   = (float*)(WB + B_O3);
  float* ML3  = (float*)(WB + B_ML3);
  float* ql   = (float*)(WB + B_QL);
  float* kl   = (float*)(WB + B_KL);
  u16*   qlh  = (u16*)(WB + B_QLH);
  u16*   klh  = (u16*)(WB + B_KLH);
  float* a2   = (float*)(WB + B_A2);
  float* z0b  = (float*)(WB + B_Z0);
  float* z1b  = (float*)(WB + B_Z1);
  float* az   = (float*)(WB + B_AZ);
  float* tA   = (float*)(WB + B_TA);
  float* tB   = (float*)(WB + B_TB);
  float* a3v  = (float*)(WB + B_A3V);
  float* Z2   = (float*)(WB + B_Z2);
  u16*   Z2T  = (u16*)(WB + B_Z2T);
  float* scal = (float*)(WB + B_SCAL);
  u16*   w1T  = (u16*)(WB + B_W1T);
  u16*   wqT  = (u16*)(WB + B_WQT);
  u16*   woT  = (u16*)(WB + B_WOT);

  // ---- fc1 ----
  copy_cls_k<<<1, 256, 0, stream>>>(cls, h);
  cvtbf_k<<<4096, 256, 0, stream>>>(x, xb, 16384LL * 1024);
  tcbf_k<<<dim3(16, 32, 1), 256, 0, stream>>>(fc1_w, w1T, 1024, 512, 512, 1024, 0, 0);
  gemmbf(stream, xb, w1T, h + CDIM, 16384, 512, 1024, 1024, 1024, 512,
         0, 0, 0, 1, fc1_b, nullptr, 0, 1.f, GB_RELU, 1);

  for (int L = 0; L < 2; L++){
    ln_pad_k<<<NP, 256, 0, stream>>>(h, l_ng[L], l_nb[L], xq);
    tcbf_k<<<dim3(48, 16, 1), 256, 0, stream>>>(l_qkv[L], wqT, 512, 1536, 1536, 512, 0, 0);
    // qkv; q columns pre-scaled by 0.125 (exact bf16 exponent shift)
    gemmbf(stream, xq, wqT, qkvb, NP, 1536, 512, 512, 512, 1536,
           0, 0, 0, 1, nullptr, nullptr, 0, 1.f, GB_STOREBF | GB_QSCALE, 1);
    landmark_k<<<dim3(LM, HEADS), 64, 0, stream>>>(qkvb, ql, kl, qlh, klh);
    // vT: per-head [64][NP]
    tc16_k<<<dim3(2, 520, 8), 256, 0, stream>>>(qkvb + 1024, vT, NP, 64, 1536, NP,
                                                64, 64LL * NP);
    // a2 = softmax(ql @ kl^T)
    gemm_k<<<dim3(4, 4, 8), 256, 0, stream>>>(ql, kl, a2, LM, LM, DH, DH, DH, LM,
                                              16384, 16384, 65536, 1.f, GF_TRANSB);
    softmax256_k<<<dim3(LM, HEADS), 256, 0, stream>>>(a2);
    // pinv (f32)
    zero_k<<<1, 256, 0, stream>>>(scal, 2);
    pinv_scal_k<<<HEADS, 256, 0, stream>>>(a2, scal);
    z0_k<<<dim3(LM, HEADS), 256, 0, stream>>>(a2, z0b, scal);
    float* zc = z0b; float* za = z1b;
    dim3 bg(4, 4, HEADS);
    for (int it = 0; it < 6; it++){
      bgemm256_k<<<bg, 256, 0, stream>>>(a2, zc, az, 0.f, 1.f, 0.f);
      bgemm256_k<<<bg, 256, 0, stream>>>(az, az, tA, 15.f, 1.f, -7.f);
      bgemm256_k<<<bg, 256, 0, stream>>>(az, tA, tB, 13.f, -1.f, 0.f);
      bgemm256_k<<<bg, 256, 0, stream>>>(zc, tB, za, 0.f, 0.25f, 0.f);
      float* tmp = zc; zc = za; za = tmp;
    }
    // ---- S3 flash: partials over 13 key chunks, then combine -> a3v ----
    fattn_k<<<dim3(4, 13, 8), 256, 0, stream>>>(
        qlh, 64, qkvb + 512, 1536, vT, NP,
        16384, 64, 64LL * NP, 1280,
        nullptr, 0, O3, ML3, 13, 256, 1);
    comb3_k<<<dim3(64, 8), 256, 0, stream>>>(O3, ML3, a3v);
    // Z2 = pinv(a2) @ a3v, then Z2T bf16 per head
    gemm_k<<<dim3(1, 4, 8), 256, 0, stream>>>(zc, a3v, Z2, LM, DH, LM, LM, DH, DH,
                                              65536, 16384, 16384, 1.f, 0);
    tcbf_k<<<dim3(2, 8, 8), 256, 0, stream>>>(Z2, Z2T, 256, 64, 64, 256, 16384, 16384);
    // ---- S1 flash: attn = softmax(q @ kl^T) @ Z2, exact (256 keys) ----
    fattn_k<<<dim3(260, 1, 8), 256, 0, stream>>>(
        qkvb, 1536, klh, 64, Z2T, 256,
        64, 16384, 16384, 256,
        attnb, CDIM, nullptr, nullptr, 1, NP, 0);
    // attn += depthwise 33-tap conv of v
    resconv_k<<<dim3(2, NP / 8), 256, 0, stream>>>(qkvb, l_rw[L], attnb);
    // h += attn[-NT:] @ out_w + out_b
    tcbf_k<<<dim3(16, 16, 1), 256, 0, stream>>>(l_ow[L], woT, 512, 512, 512, 512, 0, 0);
    gemmbf(stream, attnb + (long long)PAD * CDIM, woT, h, NT, CDIM, CDIM,
           CDIM, CDIM, CDIM, 0, 0, 0, 1, l_ob[L], nullptr, 0, 1.f, GB_ACCUM, 1);

    if (L == 0){
      transpose_k<<<dim3(16, 512), 256, 0, stream>>>(h + CDIM, cf, 16384, CDIM);
      ppeg_k<<<dim3(8, 8, CDIM), 256, 0, stream>>>(cf, yt, w7, b7, w5, b5, w3, b3);
      transpose_k<<<dim3(512, 16), 256, 0, stream>>>(yt, h + CDIM, CDIM, 16384);
    }
  }

  final_k<<<1, 256, 0, stream>>>(h, norm_g, norm_b, fc2_w, fc2_b, out);
}

// Round 7
// 1957.727 us; speedup vs baseline: 5.1457x; 1.0363x over previous
//
#include <hip/hip_runtime.h>

// ---------------------------------------------------------------------------
// TransMIL forward. Round 7: hi/lo bf16 MFMA Newton-Schulz pinv.
// B=1, N=16384, IN=1024, C=512, heads=8, dh=64, NT=16385, NP=16640,
// landmarks M=256, l=65, pinv iters=6 (hi/lo bf16 MFMA), res conv k=33.
// ---------------------------------------------------------------------------

#define NT 16385
#define NP 16640
#define PAD 255
#define CDIM 512
#define HEADS 8
#define DH 64
#define LM 256
#define LSEG 65

typedef unsigned short u16;
typedef unsigned int u32;
typedef __attribute__((ext_vector_type(8))) short bf16x8;
typedef __attribute__((ext_vector_type(4))) float f32x4;

__device__ __forceinline__ u16 f2b(float f){
  u32 u = __float_as_uint(f);
  u32 r = (u + 0x7FFFu + ((u >> 16) & 1u)) >> 16;
  return (u16)r;
}
__device__ __forceinline__ float b2f(u16 h){ return __uint_as_float(((u32)h) << 16); }

// async global->LDS, 16 B per lane; lds dest = wave-uniform base + lane*16
__device__ __forceinline__ void gload16(const u16* g, u16* l){
  __builtin_amdgcn_global_load_lds(
      (const __attribute__((address_space(1))) u32*)g,
      (__attribute__((address_space(3))) u32*)l, 16, 0, 0);
}

// ---------------- reductions ----------------
__device__ __forceinline__ float wredSum(float v){
#pragma unroll
  for (int o = 32; o > 0; o >>= 1) v += __shfl_xor(v, o, 64);
  return v;
}
__device__ __forceinline__ float wredMax(float v){
#pragma unroll
  for (int o = 32; o > 0; o >>= 1) v = fmaxf(v, __shfl_xor(v, o, 64));
  return v;
}
__device__ __forceinline__ float bredSum(float v, float* sm){
  v = wredSum(v);
  int w = threadIdx.x >> 6, l = threadIdx.x & 63;
  __syncthreads();
  if (l == 0) sm[w] = v;
  __syncthreads();
  return sm[0] + sm[1] + sm[2] + sm[3];
}
__device__ __forceinline__ float bredMax(float v, float* sm){
  v = wredMax(v);
  int w = threadIdx.x >> 6, l = threadIdx.x & 63;
  __syncthreads();
  if (l == 0) sm[w] = v;
  __syncthreads();
  return fmaxf(fmaxf(sm[0], sm[1]), fmaxf(sm[2], sm[3]));
}

// ---------------- utility ----------------
__global__ __launch_bounds__(256) void zero_k(float* __restrict__ p, long long n){
  long long i = (long long)blockIdx.x * 256 + threadIdx.x;
  long long stride = (long long)gridDim.x * 256;
  for (; i < n; i += stride) p[i] = 0.f;
}
__global__ __launch_bounds__(256) void copy_cls_k(const float* __restrict__ cls,
                                                  float* __restrict__ h){
  h[threadIdx.x] = cls[threadIdx.x];
  h[threadIdx.x + 256] = cls[threadIdx.x + 256];
}
__global__ __launch_bounds__(256) void cvtbf_k(const float* __restrict__ in,
                                               u16* __restrict__ out, long long n){
  long long i = ((long long)blockIdx.x * 256 + threadIdx.x) * 4;
  long long stride = (long long)gridDim.x * 256 * 4;
  for (; i < n; i += stride){
    float4 v = *(const float4*)(in + i);
    out[i]     = f2b(v.x);
    out[i + 1] = f2b(v.y);
    out[i + 2] = f2b(v.z);
    out[i + 3] = f2b(v.w);
  }
}
// f32 [R][ldin] -> bf16 transposed [C][ldout]
__global__ __launch_bounds__(256) void tcbf_k(const float* __restrict__ in,
    u16* __restrict__ out, int R, int C, int ldin, int ldout,
    long long sIn, long long sOut){
  __shared__ float t[32][33];
  in += (long long)blockIdx.z * sIn; out += (long long)blockIdx.z * sOut;
  int c0 = blockIdx.x * 32, r0 = blockIdx.y * 32;
  int x = threadIdx.x & 31, y = threadIdx.x >> 5;
  for (int yy = y; yy < 32; yy += 8){
    int r = r0 + yy, c = c0 + x;
    if (r < R && c < C) t[yy][x] = in[(long long)r * ldin + c];
  }
  __syncthreads();
  for (int yy = y; yy < 32; yy += 8){
    int c = c0 + yy, r = r0 + x;
    if (c < C && r < R) out[(long long)c * ldout + r] = f2b(t[x][yy]);
  }
}
// bf16 [R][ldin] -> bf16 transposed [C][ldout]
__global__ __launch_bounds__(256) void tc16_k(const u16* __restrict__ in,
    u16* __restrict__ out, int R, int C, int ldin, int ldout,
    long long sIn, long long sOut){
  __shared__ u16 t[32][33];
  in += (long long)blockIdx.z * sIn; out += (long long)blockIdx.z * sOut;
  int c0 = blockIdx.x * 32, r0 = blockIdx.y * 32;
  int x = threadIdx.x & 31, y = threadIdx.x >> 5;
  for (int yy = y; yy < 32; yy += 8){
    int r = r0 + yy, c = c0 + x;
    if (r < R && c < C) t[yy][x] = in[(long long)r * ldin + c];
  }
  __syncthreads();
  for (int yy = y; yy < 32; yy += 8){
    int c = c0 + yy, r = r0 + x;
    if (c < C && r < R) out[(long long)c * ldout + r] = t[x][yy];
  }
}

// ---------------- bf16 MFMA GEMM (m97-style): C = alpha*A@B^T (+bias)(/rowdiv)
#define GB_STOREBF 1
#define GB_RELU    2
#define GB_ACCUM   4
#define GB_ATOMIC  8
#define GB_QSCALE  16   /* multiply cols < 512 by 0.125 (q pre-scale, exact) */

__global__ __launch_bounds__(256) void gemmbf_k(
    const u16* __restrict__ A, const u16* __restrict__ B, void* __restrict__ Cv,
    int M, int N, int K, int lda, int ldb, int ldc,
    long long sA, long long sB, long long sC,
    const float* __restrict__ bias, const float* __restrict__ rowdiv, int sRow,
    float alpha, int flags, int ksplit)
{
  __shared__ __align__(16) u16 As[128 * 64];
  __shared__ __align__(16) u16 Bs[128 * 64];
  int zb = blockIdx.z / ksplit;
  int ks = blockIdx.z - zb * ksplit;
  A += (long long)zb * sA; B += (long long)zb * sB;
  float* Cf = (float*)Cv + (long long)zb * sC;
  u16*   Ch = (u16*)Cv + (long long)zb * sC;
  int klen = K / ksplit;
  int kbeg = ks * klen, kend = kbeg + klen;
  int tid = threadIdx.x;
  int w = tid >> 6, l = tid & 63;
  int row0 = blockIdx.y * 128, col0 = blockIdx.x * 128;
  int r8 = l >> 3;
  int csrc = ((l & 7) ^ r8) * 8;
  f32x4 acc[2][8];
#pragma unroll
  for (int i = 0; i < 2; i++)
#pragma unroll
    for (int j = 0; j < 8; j++) acc[i][j] = (f32x4){0.f, 0.f, 0.f, 0.f};

  int mrow = l & 15, q = l >> 4;
  for (int k0 = kbeg; k0 < kend; k0 += 64){
#pragma unroll
    for (int c = 0; c < 4; c++){
      int r = w * 32 + c * 8;
      int gm = row0 + r + r8; if (gm >= M) gm = M - 1;
      gload16(A + (long long)gm * lda + k0 + csrc, &As[r * 64]);
      int gn = col0 + r + r8; if (gn >= N) gn = N - 1;
      gload16(B + (long long)gn * ldb + k0 + csrc, &Bs[r * 64]);
    }
    __syncthreads();
#pragma unroll
    for (int ks2 = 0; ks2 < 2; ks2++){
      int kc = ks2 * 4 + q;
      bf16x8 af[2], bfr[8];
#pragma unroll
      for (int i = 0; i < 2; i++){
        int r = w * 32 + i * 16 + mrow;
        af[i] = *(const bf16x8*)&As[r * 64 + ((kc ^ (r & 7)) * 8)];
      }
#pragma unroll
      for (int j = 0; j < 8; j++){
        int r = j * 16 + mrow;
        bfr[j] = *(const bf16x8*)&Bs[r * 64 + ((kc ^ (r & 7)) * 8)];
      }
#pragma unroll
      for (int i = 0; i < 2; i++)
#pragma unroll
        for (int j = 0; j < 8; j++)
          acc[i][j] = __builtin_amdgcn_mfma_f32_16x16x32_bf16(af[i], bfr[j], acc[i][j], 0, 0, 0);
    }
    __syncthreads();
  }
#pragma unroll
  for (int i = 0; i < 2; i++){
#pragma unroll
    for (int r = 0; r < 4; r++){
      int gm = row0 + w * 32 + i * 16 + q * 4 + r;
      if (gm >= M) continue;
      float rd = rowdiv ? rowdiv[(long long)zb * sRow + gm] : 1.f;
#pragma unroll
      for (int j = 0; j < 8; j++){
        int gn = col0 + j * 16 + mrow;
        if (gn >= N) continue;
        float v = alpha * acc[i][j][r];
        if ((flags & GB_QSCALE) && gn < 512) v *= 0.125f;
        if (rowdiv) v /= rd;
        if (bias) v += bias[gn];
        if (flags & GB_RELU) v = fmaxf(v, 0.f);
        long long ci = (long long)gm * ldc + gn;
        if (flags & GB_ATOMIC) atomicAdd(&Cf[ci], v);
        else if (flags & GB_STOREBF) Ch[ci] = f2b(v);
        else if (flags & GB_ACCUM) Cf[ci] += v;
        else Cf[ci] = v;
      }
    }
  }
}

// ---------------- hi/lo bf16 MFMA pinv stage ----------------
// Per head (blockIdx.z): C = dterm*I + sterm*(A@B) + eterm*Av, all 256x256.
// A given as row-major hi/lo (Ah,Al); B given as TRANSPOSED row-major hi/lo
// (BTh,BTl = B^T). Product via 3-term hi/lo MFMA (error ~2^-17).
// Outputs: optional row-major hi/lo (Chh,Cll), always transposed hi/lo
// (CTh,CTl), optional f32 (Cf).
__global__ __launch_bounds__(256) void pinvh_k(
    const u16* __restrict__ Ah, const u16* __restrict__ Al,
    const u16* __restrict__ BTh, const u16* __restrict__ BTl,
    u16* __restrict__ Chh, u16* __restrict__ Cll,
    u16* __restrict__ CTh, u16* __restrict__ CTl,
    float* __restrict__ Cf,
    const u16* __restrict__ Avh, const u16* __restrict__ Avl,
    float dterm, float sterm, float eterm)
{
  __shared__ __align__(16) u16 lds[32768];   // 64 KB
  u16* Ash = lds;
  u16* Asl = lds + 8192;
  u16* Bsh = lds + 16384;
  u16* Bsl = lds + 24576;
  long long off = (long long)blockIdx.z << 16;
  int tid = threadIdx.x, w = tid >> 6, l = tid & 63;
  int row0 = blockIdx.y * 128, col0 = blockIdx.x * 128;
  int r8 = l >> 3;
  int csrc = ((l & 7) ^ r8) * 8;
  int mrow = l & 15, q8 = l >> 4;
  f32x4 acc[2][8];
#pragma unroll
  for (int i = 0; i < 2; i++)
#pragma unroll
    for (int j = 0; j < 8; j++) acc[i][j] = (f32x4){0.f, 0.f, 0.f, 0.f};

  for (int k0 = 0; k0 < 256; k0 += 64){
#pragma unroll
    for (int c = 0; c < 4; c++){
      int r = w * 32 + c * 8;
      long long ga = off + (long long)(row0 + r + r8) * 256 + k0 + csrc;
      long long gb = off + (long long)(col0 + r + r8) * 256 + k0 + csrc;
      gload16(Ah + ga, &Ash[r * 64]);
      gload16(Al + ga, &Asl[r * 64]);
      gload16(BTh + gb, &Bsh[r * 64]);
      gload16(BTl + gb, &Bsl[r * 64]);
    }
    __syncthreads();
#pragma unroll
    for (int ks2 = 0; ks2 < 2; ks2++){
      int kc = ks2 * 4 + q8;
      bf16x8 ah[2], al[2], bh[8], bl[8];
#pragma unroll
      for (int i = 0; i < 2; i++){
        int r = w * 32 + i * 16 + mrow;
        int idx = r * 64 + ((kc ^ (r & 7)) * 8);
        ah[i] = *(const bf16x8*)&Ash[idx];
        al[i] = *(const bf16x8*)&Asl[idx];
      }
#pragma unroll
      for (int j = 0; j < 8; j++){
        int r = j * 16 + mrow;
        int idx = r * 64 + ((kc ^ (r & 7)) * 8);
        bh[j] = *(const bf16x8*)&Bsh[idx];
        bl[j] = *(const bf16x8*)&Bsl[idx];
      }
#pragma unroll
      for (int i = 0; i < 2; i++)
#pragma unroll
        for (int j = 0; j < 8; j++){
          acc[i][j] = __builtin_amdgcn_mfma_f32_16x16x32_bf16(ah[i], bh[j], acc[i][j], 0, 0, 0);
          acc[i][j] = __builtin_amdgcn_mfma_f32_16x16x32_bf16(ah[i], bl[j], acc[i][j], 0, 0, 0);
          acc[i][j] = __builtin_amdgcn_mfma_f32_16x16x32_bf16(al[i], bh[j], acc[i][j], 0, 0, 0);
        }
    }
    __syncthreads();
  }
  // finalize values in acc; row-major + f32 stores
#pragma unroll
  for (int i = 0; i < 2; i++){
#pragma unroll
    for (int r = 0; r < 4; r++){
      int gm = row0 + w * 32 + i * 16 + q8 * 4 + r;
#pragma unroll
      for (int j = 0; j < 8; j++){
        int gn = col0 + j * 16 + mrow;
        float v = sterm * acc[i][j][r];
        if (Avh){
          long long ai = off + (long long)gm * 256 + gn;
          v += eterm * (b2f(Avh[ai]) + b2f(Avl[ai]));
        }
        if (gm == gn) v += dterm;
        acc[i][j][r] = v;
        long long ci = off + (long long)gm * 256 + gn;
        if (Cf) Cf[ci] = v;
        if (Chh){
          u16 hi = f2b(v);
          Chh[ci] = hi;
          Cll[ci] = f2b(v - b2f(hi));
        }
      }
    }
  }
  // transposed hi/lo via LDS repack (stride 136 u16: 16B-aligned, 2-way banks)
  u16* ldsT = lds;
#pragma unroll
  for (int pass = 0; pass < 2; pass++){
    __syncthreads();
#pragma unroll
    for (int i = 0; i < 2; i++){
#pragma unroll
      for (int r = 0; r < 4; r++){
        int lm = w * 32 + i * 16 + q8 * 4 + r;
#pragma unroll
        for (int j = 0; j < 8; j++){
          int ln = j * 16 + mrow;
          float v = acc[i][j][r];
          u16 hi = f2b(v);
          ldsT[ln * 136 + lm] = (pass == 0) ? hi : f2b(v - b2f(hi));
        }
      }
    }
    __syncthreads();
    u16* dst = (pass == 0) ? CTh : CTl;
#pragma unroll
    for (int p = 0; p < 8; p++){
      int rr = p * 16 + (tid >> 4);
      int cc = (tid & 15) * 8;
      *(uint4*)(dst + off + (long long)(col0 + rr) * 256 + row0 + cc) =
          *(const uint4*)&ldsT[rr * 136 + cc];
    }
  }
}

// ---------------- f32 GEMM (small: a2, Z2) ----------------
#define GF_TRANSB 1
__global__ __launch_bounds__(256) void gemm_k(
    const float* __restrict__ A, const float* __restrict__ B, float* __restrict__ C,
    int M, int N, int K, int lda, int ldb, int ldc,
    long long sA, long long sB, long long sC, float alpha, int flags)
{
  __shared__ __align__(16) float As[16][68];
  __shared__ __align__(16) float Bs[16][68];
  int zb = blockIdx.z;
  A += (long long)zb * sA; B += (long long)zb * sB; C += (long long)zb * sC;
  int tid = threadIdx.x;
  int tx = tid & 15, ty = tid >> 4;
  int row0 = blockIdx.y * 64, col0 = blockIdx.x * 64;
  float acc[4][4] = {};
  for (int k0 = 0; k0 < K; k0 += 16){
#pragma unroll
    for (int i = 0; i < 4; i++){
      int idx = tid + i * 256;
      int mm = idx >> 4, kk = idx & 15;
      int gm = row0 + mm;
      As[kk][mm] = (gm < M) ? A[(long long)gm * lda + (k0 + kk)] : 0.f;
    }
    if (!(flags & GF_TRANSB)){
#pragma unroll
      for (int i = 0; i < 4; i++){
        int idx = tid + i * 256;
        int kk = idx >> 6, nn = idx & 63;
        int gn = col0 + nn;
        Bs[kk][nn] = (gn < N) ? B[(long long)(k0 + kk) * ldb + gn] : 0.f;
      }
    } else {
#pragma unroll
      for (int i = 0; i < 4; i++){
        int idx = tid + i * 256;
        int nn = idx >> 4, kk = idx & 15;
        int gn = col0 + nn;
        Bs[kk][nn] = (gn < N) ? B[(long long)gn * ldb + (k0 + kk)] : 0.f;
      }
    }
    __syncthreads();
#pragma unroll
    for (int kk = 0; kk < 16; kk++){
      float4 av = *(const float4*)&As[kk][ty * 4];
      float4 bv = *(const float4*)&Bs[kk][tx * 4];
      float a[4] = {av.x, av.y, av.z, av.w};
      float b[4] = {bv.x, bv.y, bv.z, bv.w};
#pragma unroll
      for (int i = 0; i < 4; i++)
#pragma unroll
        for (int j = 0; j < 4; j++)
          acc[i][j] = fmaf(a[i], b[j], acc[i][j]);
    }
    __syncthreads();
  }
#pragma unroll
  for (int i = 0; i < 4; i++){
    int gm = row0 + ty * 4 + i;
    if (gm >= M) continue;
#pragma unroll
    for (int j = 0; j < 4; j++){
      int gn = col0 + tx * 4 + j;
      if (gn >= N) continue;
      C[(long long)gm * ldc + gn] = alpha * acc[i][j];
    }
  }
}

// ---------------- fused flash attention ----------------
__global__ __launch_bounds__(256) void fattn_k(
    const u16* __restrict__ Qp, int ldq,
    const u16* __restrict__ Kp, int ldk,
    const u16* __restrict__ Vp, int ldv,
    long long sQh, long long sKh, long long sVh,
    int keysPerChunk,
    u16* __restrict__ outB, int ldo,
    float* __restrict__ O3, float* __restrict__ ML3, int nchunks, int qrows,
    int mode)
{
  __shared__ u16 Qs[64][72];
  __shared__ u16 Ks[128][72];
  __shared__ u16 Vs[64][136];
  __shared__ u16 Ps[4][16][136];
  int tid = threadIdx.x;
  int w = tid >> 6, l = tid & 63;
  int mrow = l & 15, q8 = l >> 4;
  int qt = blockIdx.x, ch = blockIdx.y, h = blockIdx.z;
  const u16* Q = Qp + (long long)h * sQh;
  const u16* K = Kp + (long long)h * sKh;
  const u16* V = Vp + (long long)h * sVh;
  int q0 = qt * 64;
  for (int i = tid; i < 512; i += 256){
    int r = i >> 3, c = (i & 7) * 8;
    *(uint4*)&Qs[r][c] = *(const uint4*)(Q + (long long)(q0 + r) * ldq + c);
  }
  float m_st[4], l_st[4];
  f32x4 acc_o[4];
#pragma unroll
  for (int r = 0; r < 4; r++){
    m_st[r] = -3.0e38f; l_st[r] = 0.f;
    acc_o[r] = (f32x4){0.f, 0.f, 0.f, 0.f};
  }
  int kbase = ch * keysPerChunk;
  for (int kt = 0; kt < keysPerChunk; kt += 128){
    for (int i = tid; i < 1024; i += 256){
      int r = i >> 3, c = (i & 7) * 8;
      *(uint4*)&Ks[r][c] = *(const uint4*)(K + (long long)(kbase + kt + r) * ldk + c);
    }
    for (int i = tid; i < 1024; i += 256){
      int r = i >> 4, c = (i & 15) * 8;
      *(uint4*)&Vs[r][c] = *(const uint4*)(V + (long long)r * ldv + kbase + kt + c);
    }
    __syncthreads();
    f32x4 accs[8];
#pragma unroll
    for (int j = 0; j < 8; j++) accs[j] = (f32x4){0.f, 0.f, 0.f, 0.f};
#pragma unroll
    for (int ks2 = 0; ks2 < 2; ks2++){
      bf16x8 af = *(const bf16x8*)&Qs[w * 16 + mrow][ks2 * 32 + q8 * 8];
#pragma unroll
      for (int j = 0; j < 8; j++){
        bf16x8 bfv = *(const bf16x8*)&Ks[j * 16 + mrow][ks2 * 32 + q8 * 8];
        accs[j] = __builtin_amdgcn_mfma_f32_16x16x32_bf16(af, bfv, accs[j], 0, 0, 0);
      }
    }
#pragma unroll
    for (int r = 0; r < 4; r++){
      float tm = -3.0e38f;
#pragma unroll
      for (int j = 0; j < 8; j++) tm = fmaxf(tm, accs[j][r]);
      tm = fmaxf(tm, __shfl_xor(tm, 1, 64));
      tm = fmaxf(tm, __shfl_xor(tm, 2, 64));
      tm = fmaxf(tm, __shfl_xor(tm, 4, 64));
      tm = fmaxf(tm, __shfl_xor(tm, 8, 64));
      float mn = fmaxf(m_st[r], tm);
      float al = __expf(m_st[r] - mn);
      m_st[r] = mn;
      float rs = 0.f;
#pragma unroll
      for (int j = 0; j < 8; j++){
        float e = __expf(accs[j][r] - mn);
        accs[j][r] = e;
        rs += e;
      }
      rs += __shfl_xor(rs, 1, 64);
      rs += __shfl_xor(rs, 2, 64);
      rs += __shfl_xor(rs, 4, 64);
      rs += __shfl_xor(rs, 8, 64);
      l_st[r] = al * l_st[r] + rs;
#pragma unroll
      for (int j = 0; j < 4; j++) acc_o[j][r] *= al;
    }
#pragma unroll
    for (int j = 0; j < 8; j++)
#pragma unroll
      for (int r = 0; r < 4; r++)
        Ps[w][q8 * 4 + r][j * 16 + mrow] = f2b(accs[j][r]);
    __syncthreads();
#pragma unroll
    for (int kc = 0; kc < 4; kc++){
      bf16x8 af = *(const bf16x8*)&Ps[w][mrow][kc * 32 + q8 * 8];
#pragma unroll
      for (int j = 0; j < 4; j++){
        bf16x8 bfv = *(const bf16x8*)&Vs[j * 16 + mrow][kc * 32 + q8 * 8];
        acc_o[j] = __builtin_amdgcn_mfma_f32_16x16x32_bf16(af, bfv, acc_o[j], 0, 0, 0);
      }
    }
    __syncthreads();
  }
  if (mode == 0){
#pragma unroll
    for (int r = 0; r < 4; r++){
      int grow = q0 + w * 16 + q8 * 4 + r;
      float inv = 1.f / l_st[r];
#pragma unroll
      for (int j = 0; j < 4; j++)
        outB[(long long)grow * ldo + h * 64 + j * 16 + mrow] = f2b(acc_o[j][r] * inv);
    }
  } else {
#pragma unroll
    for (int r = 0; r < 4; r++){
      int row = q0 + w * 16 + q8 * 4 + r;
      long long b = ((long long)h * nchunks + ch) * qrows + row;
#pragma unroll
      for (int j = 0; j < 4; j++)
        O3[b * 64 + j * 16 + mrow] = acc_o[j][r];
      if (mrow == 0){
        ML3[b * 2] = m_st[r];
        ML3[b * 2 + 1] = l_st[r];
      }
    }
  }
}

// combine S3 partials
__global__ __launch_bounds__(256) void comb3_k(
    const float* __restrict__ O3, const float* __restrict__ ML3,
    float* __restrict__ a3v)
{
  int h = blockIdx.y;
  int row = blockIdx.x * 4 + (threadIdx.x >> 6);
  int d = threadIdx.x & 63;
  float m = -3.0e38f;
  for (int c = 0; c < 13; c++)
    m = fmaxf(m, ML3[(((long long)h * 13 + c) * 256 + row) * 2]);
  float l = 0.f, o = 0.f;
  for (int c = 0; c < 13; c++){
    long long b = ((long long)h * 13 + c) * 256 + row;
    float wgt = __expf(ML3[b * 2] - m);
    l += wgt * ML3[b * 2 + 1];
    o += wgt * O3[b * 64 + d];
  }
  a3v[((long long)h * 256 + row) * 64 + d] = o / l;
}

// ---------------- layernorm + front-pad -> bf16 xq (NP x 512) --------------
__global__ __launch_bounds__(256) void ln_pad_k(
    const float* __restrict__ h, const float* __restrict__ g,
    const float* __restrict__ b, u16* __restrict__ out)
{
  __shared__ float sm[4];
  int row = blockIdx.x, tid = threadIdx.x;
  u16* o = out + (long long)row * CDIM;
  if (row < PAD){ o[tid] = 0; o[tid + 256] = 0; return; }
  const float* x = h + (long long)(row - PAD) * CDIM;
  float v0 = x[tid], v1 = x[tid + 256];
  float s = bredSum(v0 + v1, sm);
  float s2 = bredSum(v0 * v0 + v1 * v1, sm);
  float mean = s * (1.f / 512.f);
  float var = s2 * (1.f / 512.f) - mean * mean;
  float rstd = rsqrtf(var + 1e-5f);
  o[tid] = f2b((v0 - mean) * rstd * g[tid] + b[tid]);
  o[tid + 256] = f2b((v1 - mean) * rstd * g[tid + 256] + b[tid + 256]);
}

// ---------------- landmark means (q already pre-scaled by 0.125) -----------
__global__ __launch_bounds__(64) void landmark_k(
    const u16* __restrict__ qkv, float* __restrict__ ql, float* __restrict__ kl,
    u16* __restrict__ qlh, u16* __restrict__ klh)
{
  int m = blockIdx.x, h = blockIdx.y, d = threadIdx.x;
  const u16* base = qkv + (long long)(m * LSEG) * 1536 + h * DH + d;
  float sq = 0.f, sk = 0.f;
  for (int j = 0; j < LSEG; j++){
    sq += b2f(base[(long long)j * 1536]);
    sk += b2f(base[(long long)j * 1536 + 512]);
  }
  float qv = sq * (1.f / 65.f);
  float kv = sk * (1.f / 65.f);
  int idx = (h * LM + m) * DH + d;
  ql[idx] = qv; kl[idx] = kv;
  qlh[idx] = f2b(qv); klh[idx] = f2b(kv);
}

// ---------------- softmax over rows of 256 (f32 + hi/lo bf16 out) ----------
__global__ __launch_bounds__(256) void softmax256_k(float* __restrict__ S,
    u16* __restrict__ a2h, u16* __restrict__ a2l)
{
  __shared__ float sm[4];
  int i = blockIdx.x, h = blockIdx.y, j = threadIdx.x;
  long long idx = ((long long)h * LM + i) * 256 + j;
  float v = S[idx];
  float m = bredMax(v, sm);
  float e = __expf(v - m);
  float s = bredSum(e, sm);
  float p = e / s;
  S[idx] = p;
  u16 hi = f2b(p);
  a2h[idx] = hi;
  a2l[idx] = f2b(p - b2f(hi));
}

// ---------------- pinv scale factors ----------------
__global__ __launch_bounds__(256) void pinv_scal_k(
    const float* __restrict__ a2, float* __restrict__ scal)
{
  __shared__ float sm[4];
  int h = blockIdx.x, i = threadIdx.x;
  const float* Ah = a2 + (long long)h * 65536;
  float rs = 0.f, cs = 0.f;
  for (int j = 0; j < 256; j++){
    rs += fabsf(Ah[i * 256 + j]);
    cs += fabsf(Ah[j * 256 + i]);
  }
  float rmax = bredMax(rs, sm);
  __syncthreads();
  float cmax = bredMax(cs, sm);
  if (i == 0){
    atomicMax((int*)&scal[0], __float_as_int(rmax));
    atomicMax((int*)&scal[1], __float_as_int(cmax));
  }
}

// z0 = a2^T * inv (hi/lo + transposed hi/lo). Block (row i, head h), thread j.
__global__ __launch_bounds__(256) void z0_k(
    const float* __restrict__ a2, const float* __restrict__ scal,
    u16* __restrict__ zh, u16* __restrict__ zl,
    u16* __restrict__ zTh, u16* __restrict__ zTl)
{
  int ri = blockIdx.x, h = blockIdx.y, j = threadIdx.x;
  float inv = 1.f / (scal[0] * scal[1]);
  long long base = ((long long)h * LM + ri) * 256;
  float v = a2[base + j] * inv;
  u16 hi = f2b(v), lo = f2b(v - b2f(hi));
  // z0T = (a2^T)^T * inv = a2 * inv  -> row ri coalesced
  zTh[base + j] = hi; zTl[base + j] = lo;
  // z0[j][ri] = a2[ri][j] * inv  -> scattered
  long long tb = ((long long)h * LM + j) * 256 + ri;
  zh[tb] = hi; zl[tb] = lo;
}

// ---------------- depthwise 33-tap residual conv (fully unrolled) ----------
__global__ __launch_bounds__(256) void resconv_k(
    const u16* __restrict__ qkv, const float* __restrict__ rw,
    u16* __restrict__ attn)
{
  int c = blockIdx.x * 256 + threadIdx.x;
  int s0 = blockIdx.y * 8;
  int h = c >> 6;
  float w[33];
#pragma unroll
  for (int t = 0; t < 33; t++) w[t] = rw[h * 33 + t];
  float vr[40];
#pragma unroll
  for (int j = 0; j < 40; j++){
    int s = s0 - 16 + j;
    vr[j] = (s >= 0 && s < NP) ? b2f(qkv[(long long)s * 1536 + 1024 + c]) : 0.f;
  }
#pragma unroll
  for (int i = 0; i < 8; i++){
    float a = 0.f;
#pragma unroll
    for (int t = 0; t < 33; t++) a = fmaf(vr[i + t], w[t], a);
    long long idx = (long long)(s0 + i) * CDIM + c;
    attn[idx] = f2b(b2f(attn[idx]) + a);
  }
}

// ---------------- f32 32x32 transpose ----------------
__global__ __launch_bounds__(256) void transpose_k(
    const float* __restrict__ in, float* __restrict__ out, int R, int Cc)
{
  __shared__ float t[32][33];
  int bx = blockIdx.x * 32, by = blockIdx.y * 32;
  int x = threadIdx.x & 31, y4 = threadIdx.x >> 5;
  for (int yy = y4; yy < 32; yy += 8){
    int r = by + yy, c = bx + x;
    if (r < R && c < Cc) t[yy][x] = in[(long long)r * Cc + c];
  }
  __syncthreads();
  for (int yy = y4; yy < 32; yy += 8){
    int r = bx + yy, c = by + x;
    if (r < Cc && c < R) out[(long long)r * R + c] = t[x][yy];
  }
}

// ---------------- fused PPEG ----------------
__global__ __launch_bounds__(256) void ppeg_k(
    const float* __restrict__ cf, float* __restrict__ yt,
    const float* __restrict__ w7, const float* __restrict__ b7,
    const float* __restrict__ w5, const float* __restrict__ b5,
    const float* __restrict__ w3, const float* __restrict__ b3)
{
  __shared__ float tile[22][23];
  int c = blockIdx.z;
  int ty0 = blockIdx.y * 16, tx0 = blockIdx.x * 16;
  const float* img = cf + (long long)c * 16384;
  for (int i = threadIdx.x; i < 22 * 22; i += 256){
    int yy = i / 22, xx = i - yy * 22;
    int gy = ty0 - 3 + yy, gx = tx0 - 3 + xx;
    tile[yy][xx] = (gy >= 0 && gy < 128 && gx >= 0 && gx < 128) ? img[gy * 128 + gx] : 0.f;
  }
  __syncthreads();
  int lx = threadIdx.x & 15, ly = threadIdx.x >> 4;
  float o = tile[ly + 3][lx + 3] + b7[c] + b5[c] + b3[c];
  const float* W7 = w7 + c * 49;
#pragma unroll
  for (int ky = 0; ky < 7; ky++)
#pragma unroll
    for (int kx = 0; kx < 7; kx++)
      o = fmaf(tile[ly + ky][lx + kx], W7[ky * 7 + kx], o);
  const float* W5 = w5 + c * 25;
#pragma unroll
  for (int ky = 0; ky < 5; ky++)
#pragma unroll
    for (int kx = 0; kx < 5; kx++)
      o = fmaf(tile[ly + 1 + ky][lx + 1 + kx], W5[ky * 5 + kx], o);
  const float* W3 = w3 + c * 9;
#pragma unroll
  for (int ky = 0; ky < 3; ky++)
#pragma unroll
    for (int kx = 0; kx < 3; kx++)
      o = fmaf(tile[ly + 2 + ky][lx + 2 + kx], W3[ky * 3 + kx], o);
  yt[(long long)c * 16384 + (ty0 + ly) * 128 + (tx0 + lx)] = o;
}

// ---------------- final: LN(h[0]) @ fc2 + b ----------------
__global__ __launch_bounds__(256) void final_k(
    const float* __restrict__ h, const float* __restrict__ g,
    const float* __restrict__ b, const float* __restrict__ w,
    const float* __restrict__ bias, float* __restrict__ out)
{
  __shared__ float sm[4];
  __shared__ float pj[256][4];
  int tid = threadIdx.x;
  float v0 = h[tid], v1 = h[tid + 256];
  float s = bredSum(v0 + v1, sm);
  float s2 = bredSum(v0 * v0 + v1 * v1, sm);
  float mean = s * (1.f / 512.f);
  float var = s2 * (1.f / 512.f) - mean * mean;
  float rstd = rsqrtf(var + 1e-5f);
  float n0 = (v0 - mean) * rstd * g[tid] + b[tid];
  float n1 = (v1 - mean) * rstd * g[tid + 256] + b[tid + 256];
#pragma unroll
  for (int j = 0; j < 4; j++)
    pj[tid][j] = n0 * w[tid * 4 + j] + n1 * w[(tid + 256) * 4 + j];
  __syncthreads();
  if (tid < 4){
    float acc = 0.f;
    for (int k = 0; k < 256; k++) acc += pj[k][tid];
    out[tid] = acc + bias[tid];
  }
}

// ===========================================================================
// host side
// ===========================================================================
static inline void gemmbf(hipStream_t st, const u16* A, const u16* B, void* C,
                          int M, int N, int K, int lda, int ldb, int ldc,
                          long long sA, long long sB, long long sC, int batch,
                          const float* bias, const float* rowdiv, int sRow,
                          float alpha, int flags, int ksplit)
{
  dim3 grid((N + 127) / 128, (M + 127) / 128, batch * ksplit);
  gemmbf_k<<<grid, 256, 0, st>>>(A, B, C, M, N, K, lda, ldb, ldc, sA, sB, sC,
                                 bias, rowdiv, sRow, alpha, flags, ksplit);
}

// workspace byte offsets
#define B_H     0LL
#define B_XQ    33556480LL     /* xq; after qkv, hosts pinv hi/lo arrays (16MB) */
#define B_ATTN  50595840LL
#define B_QKV   67635200LL     /* also xb; also cf/yt for PPEG */
#define B_VT    118753280LL
#define B_O3    135792640LL
#define B_ML3   142608384LL
#define B_QL    169871360LL
#define B_KL    170395648LL
#define B_QLH   170919936LL
#define B_KLH   171182080LL
#define B_A2    171444224LL
#define B_PV2   173541376LL    /* tBTh(1M), tBTl(1M), zf f32(2M) */
#define B_A3V   184027136LL
#define B_Z2    184551424LL
#define B_Z2T   185075712LL
#define B_SCAL  185604096LL
#define B_W1T   185604352LL
#define B_WQT   186652928LL
#define B_WOT   188225792LL
#define WS_REQ  188750080LL
#define MB1     1048576LL

extern "C" void kernel_launch(void* const* d_in, const int* in_sizes, int n_in,
                              void* d_out, int out_size, void* d_ws, size_t ws_size,
                              hipStream_t stream)
{
  (void)in_sizes; (void)n_in; (void)out_size;
  if (ws_size < (size_t)WS_REQ) return;

  const float* x      = (const float*)d_in[0];
  const float* fc1_w  = (const float*)d_in[1];
  const float* fc1_b  = (const float*)d_in[2];
  const float* cls    = (const float*)d_in[3];
  const float* l_ng[2]  = {(const float*)d_in[4],  (const float*)d_in[10]};
  const float* l_nb[2]  = {(const float*)d_in[5],  (const float*)d_in[11]};
  const float* l_qkv[2] = {(const float*)d_in[6],  (const float*)d_in[12]};
  const float* l_ow[2]  = {(const float*)d_in[7],  (const float*)d_in[13]};
  const float* l_ob[2]  = {(const float*)d_in[8],  (const float*)d_in[14]};
  const float* l_rw[2]  = {(const float*)d_in[9],  (const float*)d_in[15]};
  const float* w7 = (const float*)d_in[16];
  const float* b7 = (const float*)d_in[17];
  const float* w5 = (const float*)d_in[18];
  const float* b5 = (const float*)d_in[19];
  const float* w3 = (const float*)d_in[20];
  const float* b3 = (const float*)d_in[21];
  const float* norm_g = (const float*)d_in[22];
  const float* norm_b = (const float*)d_in[23];
  const float* fc2_w  = (const float*)d_in[24];
  const float* fc2_b  = (const float*)d_in[25];
  float* out = (float*)d_out;

  char* WB = (char*)d_ws;
  float* h    = (float*)(WB + B_H);
  u16*   xq   = (u16*)(WB + B_XQ);
  u16*   attnb= (u16*)(WB + B_ATTN);
  u16*   qkvb = (u16*)(WB + B_QKV);
  u16*   xb   = (u16*)(WB + B_QKV);
  float* cf   = (float*)(WB + B_QKV);
  float* yt   = (float*)(WB + B_QKV + 33554432LL);
  u16*   vT   = (u16*)(WB + B_VT);
  float* O3   = (float*)(WB + B_O3);
  float* ML3  = (float*)(WB + B_ML3);
  float* ql   = (float*)(WB + B_QL);
  float* kl   = (float*)(WB + B_KL);
  u16*   qlh  = (u16*)(WB + B_QLH);
  u16*   klh  = (u16*)(WB + B_KLH);
  float* a2   = (float*)(WB + B_A2);
  float* a3v  = (float*)(WB + B_A3V);
  float* Z2   = (float*)(WB + B_Z2);
  u16*   Z2T  = (u16*)(WB + B_Z2T);
  float* scal = (float*)(WB + B_SCAL);
  u16*   w1T  = (u16*)(WB + B_W1T);
  u16*   wqT  = (u16*)(WB + B_WQT);
  u16*   woT  = (u16*)(WB + B_WOT);

  // pinv hi/lo arrays (1 MB each) overlaid on dead-xq region
  u16* a2h  = (u16*)(WB + B_XQ + 0 * MB1);
  u16* a2l  = (u16*)(WB + B_XQ + 1 * MB1);
  u16* z0h  = (u16*)(WB + B_XQ + 2 * MB1);
  u16* z0l  = (u16*)(WB + B_XQ + 3 * MB1);
  u16* z0Th = (u16*)(WB + B_XQ + 4 * MB1);
  u16* z0Tl = (u16*)(WB + B_XQ + 5 * MB1);
  u16* z1h  = (u16*)(WB + B_XQ + 6 * MB1);
  u16* z1l  = (u16*)(WB + B_XQ + 7 * MB1);
  u16* z1Th = (u16*)(WB + B_XQ + 8 * MB1);
  u16* z1Tl = (u16*)(WB + B_XQ + 9 * MB1);
  u16* azh  = (u16*)(WB + B_XQ + 10 * MB1);
  u16* azl  = (u16*)(WB + B_XQ + 11 * MB1);
  u16* azTh = (u16*)(WB + B_XQ + 12 * MB1);
  u16* azTl = (u16*)(WB + B_XQ + 13 * MB1);
  u16* tATh = (u16*)(WB + B_XQ + 14 * MB1);
  u16* tATl = (u16*)(WB + B_XQ + 15 * MB1);
  u16* tBTh = (u16*)(WB + B_PV2 + 0 * MB1);
  u16* tBTl = (u16*)(WB + B_PV2 + 1 * MB1);
  float* zf = (float*)(WB + B_PV2 + 2 * MB1);   // 2 MB f32

  // ---- fc1 ----
  copy_cls_k<<<1, 256, 0, stream>>>(cls, h);
  cvtbf_k<<<4096, 256, 0, stream>>>(x, xb, 16384LL * 1024);
  tcbf_k<<<dim3(16, 32, 1), 256, 0, stream>>>(fc1_w, w1T, 1024, 512, 512, 1024, 0, 0);
  gemmbf(stream, xb, w1T, h + CDIM, 16384, 512, 1024, 1024, 1024, 512,
         0, 0, 0, 1, fc1_b, nullptr, 0, 1.f, GB_RELU, 1);

  for (int L = 0; L < 2; L++){
    ln_pad_k<<<NP, 256, 0, stream>>>(h, l_ng[L], l_nb[L], xq);
    tcbf_k<<<dim3(48, 16, 1), 256, 0, stream>>>(l_qkv[L], wqT, 512, 1536, 1536, 512, 0, 0);
    gemmbf(stream, xq, wqT, qkvb, NP, 1536, 512, 512, 512, 1536,
           0, 0, 0, 1, nullptr, nullptr, 0, 1.f, GB_STOREBF | GB_QSCALE, 1);
    landmark_k<<<dim3(LM, HEADS), 64, 0, stream>>>(qkvb, ql, kl, qlh, klh);
    tc16_k<<<dim3(2, 520, 8), 256, 0, stream>>>(qkvb + 1024, vT, NP, 64, 1536, NP,
                                                64, 64LL * NP);
    // a2 = softmax(ql @ kl^T): f32 + hi/lo
    gemm_k<<<dim3(4, 4, 8), 256, 0, stream>>>(ql, kl, a2, LM, LM, DH, DH, DH, LM,
                                              16384, 16384, 65536, 1.f, GF_TRANSB);
    softmax256_k<<<dim3(LM, HEADS), 256, 0, stream>>>(a2, a2h, a2l);
    // pinv init
    zero_k<<<1, 256, 0, stream>>>(scal, 2);
    pinv_scal_k<<<HEADS, 256, 0, stream>>>(a2, scal);
    z0_k<<<dim3(LM, HEADS), 256, 0, stream>>>(a2, scal, z0h, z0l, z0Th, z0Tl);
    // 6 Newton-Schulz iterations, hi/lo bf16 MFMA
    u16 *zh = z0h, *zl = z0l, *zTh = z0Th, *zTl = z0Tl;
    u16 *nzh = z1h, *nzl = z1l, *nzTh = z1Th, *nzTl = z1Tl;
    dim3 pg(2, 2, HEADS);
    for (int it = 0; it < 6; it++){
      // az = a2 @ z
      pinvh_k<<<pg, 256, 0, stream>>>(a2h, a2l, zTh, zTl,
                                      azh, azl, azTh, azTl, nullptr,
                                      nullptr, nullptr, 0.f, 1.f, 0.f);
      // tA = 15I - 7 az + az@az   (transposed-only output)
      pinvh_k<<<pg, 256, 0, stream>>>(azh, azl, azTh, azTl,
                                      nullptr, nullptr, tATh, tATl, nullptr,
                                      azh, azl, 15.f, 1.f, -7.f);
      // tB = 13I - az@tA          (transposed-only output)
      pinvh_k<<<pg, 256, 0, stream>>>(azh, azl, tATh, tATl,
                                      nullptr, nullptr, tBTh, tBTl, nullptr,
                                      nullptr, nullptr, 13.f, -1.f, 0.f);
      // z' = 0.25 z@tB            (+ f32 copy for Z2 gemm)
      pinvh_k<<<pg, 256, 0, stream>>>(zh, zl, tBTh, tBTl,
                                      nzh, nzl, nzTh, nzTl, zf,
                                      nullptr, nullptr, 0.f, 0.25f, 0.f);
      u16* t;
      t = zh; zh = nzh; nzh = t;   t = zl; zl = nzl; nzl = t;
      t = zTh; zTh = nzTh; nzTh = t; t = zTl; zTl = nzTl; nzTl = t;
    }
    // ---- S3 flash: partials over 13 key chunks, then combine -> a3v ----
    fattn_k<<<dim3(4, 13, 8), 256, 0, stream>>>(
        qlh, 64, qkvb + 512, 1536, vT, NP,
        16384, 64, 64LL * NP, 1280,
        nullptr, 0, O3, ML3, 13, 256, 1);
    comb3_k<<<dim3(64, 8), 256, 0, stream>>>(O3, ML3, a3v);
    // Z2 = pinv(a2) @ a3v (zf f32), then Z2T bf16 per head
    gemm_k<<<dim3(1, 4, 8), 256, 0, stream>>>(zf, a3v, Z2, LM, DH, LM, LM, DH, DH,
                                              65536, 16384, 16384, 1.f, 0);
    tcbf_k<<<dim3(2, 8, 8), 256, 0, stream>>>(Z2, Z2T, 256, 64, 64, 256, 16384, 16384);
    // ---- S1 flash: attn = softmax(q @ kl^T) @ Z2, exact (256 keys) ----
    fattn_k<<<dim3(260, 1, 8), 256, 0, stream>>>(
        qkvb, 1536, klh, 64, Z2T, 256,
        64, 16384, 16384, 256,
        attnb, CDIM, nullptr, nullptr, 1, NP, 0);
    // attn += depthwise 33-tap conv of v
    resconv_k<<<dim3(2, NP / 8), 256, 0, stream>>>(qkvb, l_rw[L], attnb);
    // h += attn[-NT:] @ out_w + out_b
    tcbf_k<<<dim3(16, 16, 1), 256, 0, stream>>>(l_ow[L], woT, 512, 512, 512, 512, 0, 0);
    gemmbf(stream, attnb + (long long)PAD * CDIM, woT, h, NT, CDIM, CDIM,
           CDIM, CDIM, CDIM, 0, 0, 0, 1, l_ob[L], nullptr, 0, 1.f, GB_ACCUM, 1);

    if (L == 0){
      transpose_k<<<dim3(16, 512), 256, 0, stream>>>(h + CDIM, cf, 16384, CDIM);
      ppeg_k<<<dim3(8, 8, CDIM), 256, 0, stream>>>(cf, yt, w7, b7, w5, b5, w3, b3);
      transpose_k<<<dim3(512, 16), 256, 0, stream>>>(yt, h + CDIM, CDIM, 16384);
    }
  }

  final_k<<<1, 256, 0, stream>>>(h, norm_g, norm_b, fc2_w, fc2_b, out);
}

// Round 8
// 1884.158 us; speedup vs baseline: 5.3466x; 1.0390x over previous
//
#include <hip/hip_runtime.h>

// ---------------------------------------------------------------------------
// TransMIL forward. Round 8: vectorized epilogues (LDS repack), vT fused into
// qkv epilogue, vectorized landmark kernel.
// B=1, N=16384, IN=1024, C=512, heads=8, dh=64, NT=16385, NP=16640,
// landmarks M=256, l=65, pinv iters=6 (hi/lo bf16 MFMA), res conv k=33.
// ---------------------------------------------------------------------------

#define NT 16385
#define NP 16640
#define PAD 255
#define CDIM 512
#define HEADS 8
#define DH 64
#define LM 256
#define LSEG 65

typedef unsigned short u16;
typedef unsigned int u32;
typedef __attribute__((ext_vector_type(8))) short bf16x8;
typedef __attribute__((ext_vector_type(4))) float f32x4;

__device__ __forceinline__ u16 f2b(float f){
  u32 u = __float_as_uint(f);
  u32 r = (u + 0x7FFFu + ((u >> 16) & 1u)) >> 16;
  return (u16)r;
}
__device__ __forceinline__ float b2f(u16 h){ return __uint_as_float(((u32)h) << 16); }

// async global->LDS, 16 B per lane; lds dest = wave-uniform base + lane*16
__device__ __forceinline__ void gload16(const u16* g, u16* l){
  __builtin_amdgcn_global_load_lds(
      (const __attribute__((address_space(1))) u32*)g,
      (__attribute__((address_space(3))) u32*)l, 16, 0, 0);
}

// ---------------- reductions ----------------
__device__ __forceinline__ float wredSum(float v){
#pragma unroll
  for (int o = 32; o > 0; o >>= 1) v += __shfl_xor(v, o, 64);
  return v;
}
__device__ __forceinline__ float wredMax(float v){
#pragma unroll
  for (int o = 32; o > 0; o >>= 1) v = fmaxf(v, __shfl_xor(v, o, 64));
  return v;
}
__device__ __forceinline__ float bredSum(float v, float* sm){
  v = wredSum(v);
  int w = threadIdx.x >> 6, l = threadIdx.x & 63;
  __syncthreads();
  if (l == 0) sm[w] = v;
  __syncthreads();
  return sm[0] + sm[1] + sm[2] + sm[3];
}
__device__ __forceinline__ float bredMax(float v, float* sm){
  v = wredMax(v);
  int w = threadIdx.x >> 6, l = threadIdx.x & 63;
  __syncthreads();
  if (l == 0) sm[w] = v;
  __syncthreads();
  return fmaxf(fmaxf(sm[0], sm[1]), fmaxf(sm[2], sm[3]));
}

// ---------------- utility ----------------
__global__ __launch_bounds__(256) void zero_k(float* __restrict__ p, long long n){
  long long i = (long long)blockIdx.x * 256 + threadIdx.x;
  long long stride = (long long)gridDim.x * 256;
  for (; i < n; i += stride) p[i] = 0.f;
}
__global__ __launch_bounds__(256) void copy_cls_k(const float* __restrict__ cls,
                                                  float* __restrict__ h){
  h[threadIdx.x] = cls[threadIdx.x];
  h[threadIdx.x + 256] = cls[threadIdx.x + 256];
}
__global__ __launch_bounds__(256) void cvtbf_k(const float* __restrict__ in,
                                               u16* __restrict__ out, long long n){
  long long i = ((long long)blockIdx.x * 256 + threadIdx.x) * 4;
  long long stride = (long long)gridDim.x * 256 * 4;
  for (; i < n; i += stride){
    float4 v = *(const float4*)(in + i);
    out[i]     = f2b(v.x);
    out[i + 1] = f2b(v.y);
    out[i + 2] = f2b(v.z);
    out[i + 3] = f2b(v.w);
  }
}
// f32 [R][ldin] -> bf16 transposed [C][ldout]
__global__ __launch_bounds__(256) void tcbf_k(const float* __restrict__ in,
    u16* __restrict__ out, int R, int C, int ldin, int ldout,
    long long sIn, long long sOut){
  __shared__ float t[32][33];
  in += (long long)blockIdx.z * sIn; out += (long long)blockIdx.z * sOut;
  int c0 = blockIdx.x * 32, r0 = blockIdx.y * 32;
  int x = threadIdx.x & 31, y = threadIdx.x >> 5;
  for (int yy = y; yy < 32; yy += 8){
    int r = r0 + yy, c = c0 + x;
    if (r < R && c < C) t[yy][x] = in[(long long)r * ldin + c];
  }
  __syncthreads();
  for (int yy = y; yy < 32; yy += 8){
    int c = c0 + yy, r = r0 + x;
    if (c < C && r < R) out[(long long)c * ldout + r] = f2b(t[x][yy]);
  }
}

// ---------------- bf16 MFMA GEMM (m97-style): C = alpha*A@B^T (+bias)(/rowdiv)
// STOREBF path uses LDS-repacked uint4 stores (requires N%128==0).
// If vt != nullptr, column-blocks with col0>=1024 additionally emit the
// transposed per-head v layout vT[(gn-1024)][gm] (ld NP) — fuses tc16.
#define GB_STOREBF 1
#define GB_RELU    2
#define GB_ACCUM   4
#define GB_ATOMIC  8
#define GB_QSCALE  16   /* multiply cols < 512 by 0.125 (q pre-scale, exact) */

__global__ __launch_bounds__(256) void gemmbf_k(
    const u16* __restrict__ A, const u16* __restrict__ B, void* __restrict__ Cv,
    int M, int N, int K, int lda, int ldb, int ldc,
    long long sA, long long sB, long long sC,
    const float* __restrict__ bias, const float* __restrict__ rowdiv, int sRow,
    float alpha, int flags, int ksplit, u16* __restrict__ vt)
{
  __shared__ __align__(16) u16 sh[16384];   // 32 KB: As | Bs, reused for repack
  u16* As = sh;
  u16* Bs = sh + 8192;
  int zb = blockIdx.z / ksplit;
  int ks = blockIdx.z - zb * ksplit;
  A += (long long)zb * sA; B += (long long)zb * sB;
  float* Cf = (float*)Cv + (long long)zb * sC;
  u16*   Ch = (u16*)Cv + (long long)zb * sC;
  int klen = K / ksplit;
  int kbeg = ks * klen, kend = kbeg + klen;
  int tid = threadIdx.x;
  int w = tid >> 6, l = tid & 63;
  int row0 = blockIdx.y * 128, col0 = blockIdx.x * 128;
  int r8 = l >> 3;
  int csrc = ((l & 7) ^ r8) * 8;
  f32x4 acc[2][8];
#pragma unroll
  for (int i = 0; i < 2; i++)
#pragma unroll
    for (int j = 0; j < 8; j++) acc[i][j] = (f32x4){0.f, 0.f, 0.f, 0.f};

  int mrow = l & 15, q8 = l >> 4;
  for (int k0 = kbeg; k0 < kend; k0 += 64){
#pragma unroll
    for (int c = 0; c < 4; c++){
      int r = w * 32 + c * 8;
      int gm = row0 + r + r8; if (gm >= M) gm = M - 1;
      gload16(A + (long long)gm * lda + k0 + csrc, &As[r * 64]);
      int gn = col0 + r + r8; if (gn >= N) gn = N - 1;
      gload16(B + (long long)gn * ldb + k0 + csrc, &Bs[r * 64]);
    }
    __syncthreads();
#pragma unroll
    for (int ks2 = 0; ks2 < 2; ks2++){
      int kc = ks2 * 4 + q8;
      bf16x8 af[2], bfr[8];
#pragma unroll
      for (int i = 0; i < 2; i++){
        int r = w * 32 + i * 16 + mrow;
        af[i] = *(const bf16x8*)&As[r * 64 + ((kc ^ (r & 7)) * 8)];
      }
#pragma unroll
      for (int j = 0; j < 8; j++){
        int r = j * 16 + mrow;
        bfr[j] = *(const bf16x8*)&Bs[r * 64 + ((kc ^ (r & 7)) * 8)];
      }
#pragma unroll
      for (int i = 0; i < 2; i++)
#pragma unroll
        for (int j = 0; j < 8; j++)
          acc[i][j] = __builtin_amdgcn_mfma_f32_16x16x32_bf16(af[i], bfr[j], acc[i][j], 0, 0, 0);
    }
    __syncthreads();
  }

  if (flags & GB_STOREBF){
    // row-major bf16 via LDS repack: 2 passes of 64 columns, stride 72
#pragma unroll
    for (int p = 0; p < 2; p++){
      __syncthreads();
#pragma unroll
      for (int i = 0; i < 2; i++)
#pragma unroll
        for (int r = 0; r < 4; r++){
          int lrow = w * 32 + i * 16 + q8 * 4 + r;
          int gm = row0 + lrow;
          float rd = rowdiv ? rowdiv[(long long)zb * sRow + gm] : 1.f;
#pragma unroll
          for (int jj = 0; jj < 4; jj++){
            int j = p * 4 + jj;
            int gn = col0 + j * 16 + mrow;
            float v = alpha * acc[i][j][r];
            if ((flags & GB_QSCALE) && gn < 512) v *= 0.125f;
            if (rowdiv) v /= rd;
            if (bias) v += bias[gn];
            if (flags & GB_RELU) v = fmaxf(v, 0.f);
            sh[lrow * 72 + (j * 16 + mrow - p * 64)] = f2b(v);
          }
        }
      __syncthreads();
#pragma unroll
      for (int it = 0; it < 4; it++){
        int cidx = tid + it * 256;
        int rr = cidx >> 3, c8 = (cidx & 7) * 8;
        int gm = row0 + rr;
        if (gm < M)
          *(uint4*)(Ch + (long long)gm * ldc + col0 + p * 64 + c8) =
              *(const uint4*)&sh[rr * 72 + c8];
      }
    }
    // fused vT output for v column-blocks: vT[(gn-1024)][gm], ld NP
    if (vt && col0 >= 1024){
      int gc0 = col0 - 1024;
#pragma unroll
      for (int p = 0; p < 2; p++){
        __syncthreads();
#pragma unroll
        for (int i = 0; i < 2; i++)
#pragma unroll
          for (int r = 0; r < 4; r++){
            int lrow = w * 32 + i * 16 + q8 * 4 + r;
#pragma unroll
            for (int jj = 0; jj < 4; jj++){
              int j = p * 4 + jj;
              int lcol = j * 16 + mrow - p * 64;
              sh[lcol * 136 + lrow] = f2b(alpha * acc[i][j][r]);
            }
          }
        __syncthreads();
#pragma unroll
        for (int it = 0; it < 4; it++){
          int cidx = tid + it * 256;
          int cc = cidx >> 4, rc = (cidx & 15) * 8;
          *(uint4*)(vt + (long long)(gc0 + p * 64 + cc) * NP + row0 + rc) =
              *(const uint4*)&sh[cc * 136 + rc];
        }
      }
    }
    return;
  }

  // scalar epilogue (f32 store / accum / atomic)
#pragma unroll
  for (int i = 0; i < 2; i++){
#pragma unroll
    for (int r = 0; r < 4; r++){
      int gm = row0 + w * 32 + i * 16 + q8 * 4 + r;
      if (gm >= M) continue;
      float rd = rowdiv ? rowdiv[(long long)zb * sRow + gm] : 1.f;
#pragma unroll
      for (int j = 0; j < 8; j++){
        int gn = col0 + j * 16 + mrow;
        if (gn >= N) continue;
        float v = alpha * acc[i][j][r];
        if ((flags & GB_QSCALE) && gn < 512) v *= 0.125f;
        if (rowdiv) v /= rd;
        if (bias) v += bias[gn];
        if (flags & GB_RELU) v = fmaxf(v, 0.f);
        long long ci = (long long)gm * ldc + gn;
        if (flags & GB_ATOMIC) atomicAdd(&Cf[ci], v);
        else if (flags & GB_ACCUM) Cf[ci] += v;
        else Cf[ci] = v;
      }
    }
  }
}

// ---------------- hi/lo bf16 MFMA pinv stage ----------------
__global__ __launch_bounds__(256) void pinvh_k(
    const u16* __restrict__ Ah, const u16* __restrict__ Al,
    const u16* __restrict__ BTh, const u16* __restrict__ BTl,
    u16* __restrict__ Chh, u16* __restrict__ Cll,
    u16* __restrict__ CTh, u16* __restrict__ CTl,
    float* __restrict__ Cf,
    const u16* __restrict__ Avh, const u16* __restrict__ Avl,
    float dterm, float sterm, float eterm)
{
  __shared__ __align__(16) u16 lds[32768];   // 64 KB
  u16* Ash = lds;
  u16* Asl = lds + 8192;
  u16* Bsh = lds + 16384;
  u16* Bsl = lds + 24576;
  long long off = (long long)blockIdx.z << 16;
  int tid = threadIdx.x, w = tid >> 6, l = tid & 63;
  int row0 = blockIdx.y * 128, col0 = blockIdx.x * 128;
  int r8 = l >> 3;
  int csrc = ((l & 7) ^ r8) * 8;
  int mrow = l & 15, q8 = l >> 4;
  f32x4 acc[2][8];
#pragma unroll
  for (int i = 0; i < 2; i++)
#pragma unroll
    for (int j = 0; j < 8; j++) acc[i][j] = (f32x4){0.f, 0.f, 0.f, 0.f};

  for (int k0 = 0; k0 < 256; k0 += 64){
#pragma unroll
    for (int c = 0; c < 4; c++){
      int r = w * 32 + c * 8;
      long long ga = off + (long long)(row0 + r + r8) * 256 + k0 + csrc;
      long long gb = off + (long long)(col0 + r + r8) * 256 + k0 + csrc;
      gload16(Ah + ga, &Ash[r * 64]);
      gload16(Al + ga, &Asl[r * 64]);
      gload16(BTh + gb, &Bsh[r * 64]);
      gload16(BTl + gb, &Bsl[r * 64]);
    }
    __syncthreads();
#pragma unroll
    for (int ks2 = 0; ks2 < 2; ks2++){
      int kc = ks2 * 4 + q8;
      bf16x8 ah[2], al[2], bh[8], bl[8];
#pragma unroll
      for (int i = 0; i < 2; i++){
        int r = w * 32 + i * 16 + mrow;
        int idx = r * 64 + ((kc ^ (r & 7)) * 8);
        ah[i] = *(const bf16x8*)&Ash[idx];
        al[i] = *(const bf16x8*)&Asl[idx];
      }
#pragma unroll
      for (int j = 0; j < 8; j++){
        int r = j * 16 + mrow;
        int idx = r * 64 + ((kc ^ (r & 7)) * 8);
        bh[j] = *(const bf16x8*)&Bsh[idx];
        bl[j] = *(const bf16x8*)&Bsl[idx];
      }
#pragma unroll
      for (int i = 0; i < 2; i++)
#pragma unroll
        for (int j = 0; j < 8; j++){
          acc[i][j] = __builtin_amdgcn_mfma_f32_16x16x32_bf16(ah[i], bh[j], acc[i][j], 0, 0, 0);
          acc[i][j] = __builtin_amdgcn_mfma_f32_16x16x32_bf16(ah[i], bl[j], acc[i][j], 0, 0, 0);
          acc[i][j] = __builtin_amdgcn_mfma_f32_16x16x32_bf16(al[i], bh[j], acc[i][j], 0, 0, 0);
        }
    }
    __syncthreads();
  }
#pragma unroll
  for (int i = 0; i < 2; i++){
#pragma unroll
    for (int r = 0; r < 4; r++){
      int gm = row0 + w * 32 + i * 16 + q8 * 4 + r;
#pragma unroll
      for (int j = 0; j < 8; j++){
        int gn = col0 + j * 16 + mrow;
        float v = sterm * acc[i][j][r];
        if (Avh){
          long long ai = off + (long long)gm * 256 + gn;
          v += eterm * (b2f(Avh[ai]) + b2f(Avl[ai]));
        }
        if (gm == gn) v += dterm;
        acc[i][j][r] = v;
        long long ci = off + (long long)gm * 256 + gn;
        if (Cf) Cf[ci] = v;
        if (Chh){
          u16 hi = f2b(v);
          Chh[ci] = hi;
          Cll[ci] = f2b(v - b2f(hi));
        }
      }
    }
  }
  u16* ldsT = lds;
#pragma unroll
  for (int pass = 0; pass < 2; pass++){
    __syncthreads();
#pragma unroll
    for (int i = 0; i < 2; i++){
#pragma unroll
      for (int r = 0; r < 4; r++){
        int lm = w * 32 + i * 16 + q8 * 4 + r;
#pragma unroll
        for (int j = 0; j < 8; j++){
          int ln = j * 16 + mrow;
          float v = acc[i][j][r];
          u16 hi = f2b(v);
          ldsT[ln * 136 + lm] = (pass == 0) ? hi : f2b(v - b2f(hi));
        }
      }
    }
    __syncthreads();
    u16* dst = (pass == 0) ? CTh : CTl;
#pragma unroll
    for (int p = 0; p < 8; p++){
      int rr = p * 16 + (tid >> 4);
      int cc = (tid & 15) * 8;
      *(uint4*)(dst + off + (long long)(col0 + rr) * 256 + row0 + cc) =
          *(const uint4*)&ldsT[rr * 136 + cc];
    }
  }
}

// ---------------- f32 GEMM (small: a2, Z2) ----------------
#define GF_TRANSB 1
__global__ __launch_bounds__(256) void gemm_k(
    const float* __restrict__ A, const float* __restrict__ B, float* __restrict__ C,
    int M, int N, int K, int lda, int ldb, int ldc,
    long long sA, long long sB, long long sC, float alpha, int flags)
{
  __shared__ __align__(16) float As[16][68];
  __shared__ __align__(16) float Bs[16][68];
  int zb = blockIdx.z;
  A += (long long)zb * sA; B += (long long)zb * sB; C += (long long)zb * sC;
  int tid = threadIdx.x;
  int tx = tid & 15, ty = tid >> 4;
  int row0 = blockIdx.y * 64, col0 = blockIdx.x * 64;
  float acc[4][4] = {};
  for (int k0 = 0; k0 < K; k0 += 16){
#pragma unroll
    for (int i = 0; i < 4; i++){
      int idx = tid + i * 256;
      int mm = idx >> 4, kk = idx & 15;
      int gm = row0 + mm;
      As[kk][mm] = (gm < M) ? A[(long long)gm * lda + (k0 + kk)] : 0.f;
    }
    if (!(flags & GF_TRANSB)){
#pragma unroll
      for (int i = 0; i < 4; i++){
        int idx = tid + i * 256;
        int kk = idx >> 6, nn = idx & 63;
        int gn = col0 + nn;
        Bs[kk][nn] = (gn < N) ? B[(long long)(k0 + kk) * ldb + gn] : 0.f;
      }
    } else {
#pragma unroll
      for (int i = 0; i < 4; i++){
        int idx = tid + i * 256;
        int nn = idx >> 4, kk = idx & 15;
        int gn = col0 + nn;
        Bs[kk][nn] = (gn < N) ? B[(long long)gn * ldb + (k0 + kk)] : 0.f;
      }
    }
    __syncthreads();
#pragma unroll
    for (int kk = 0; kk < 16; kk++){
      float4 av = *(const float4*)&As[kk][ty * 4];
      float4 bv = *(const float4*)&Bs[kk][tx * 4];
      float a[4] = {av.x, av.y, av.z, av.w};
      float b[4] = {bv.x, bv.y, bv.z, bv.w};
#pragma unroll
      for (int i = 0; i < 4; i++)
#pragma unroll
        for (int j = 0; j < 4; j++)
          acc[i][j] = fmaf(a[i], b[j], acc[i][j]);
    }
    __syncthreads();
  }
#pragma unroll
  for (int i = 0; i < 4; i++){
    int gm = row0 + ty * 4 + i;
    if (gm >= M) continue;
#pragma unroll
    for (int j = 0; j < 4; j++){
      int gn = col0 + tx * 4 + j;
      if (gn >= N) continue;
      C[(long long)gm * ldc + gn] = alpha * acc[i][j];
    }
  }
}

// ---------------- fused flash attention ----------------
__global__ __launch_bounds__(256) void fattn_k(
    const u16* __restrict__ Qp, int ldq,
    const u16* __restrict__ Kp, int ldk,
    const u16* __restrict__ Vp, int ldv,
    long long sQh, long long sKh, long long sVh,
    int keysPerChunk,
    u16* __restrict__ outB, int ldo,
    float* __restrict__ O3, float* __restrict__ ML3, int nchunks, int qrows,
    int mode)
{
  __shared__ u16 Qs[64][72];
  __shared__ u16 Ks[128][72];
  __shared__ u16 Vs[64][136];
  __shared__ u16 Ps[4][16][136];
  int tid = threadIdx.x;
  int w = tid >> 6, l = tid & 63;
  int mrow = l & 15, q8 = l >> 4;
  int qt = blockIdx.x, ch = blockIdx.y, h = blockIdx.z;
  const u16* Q = Qp + (long long)h * sQh;
  const u16* K = Kp + (long long)h * sKh;
  const u16* V = Vp + (long long)h * sVh;
  int q0 = qt * 64;
  for (int i = tid; i < 512; i += 256){
    int r = i >> 3, c = (i & 7) * 8;
    *(uint4*)&Qs[r][c] = *(const uint4*)(Q + (long long)(q0 + r) * ldq + c);
  }
  float m_st[4], l_st[4];
  f32x4 acc_o[4];
#pragma unroll
  for (int r = 0; r < 4; r++){
    m_st[r] = -3.0e38f; l_st[r] = 0.f;
    acc_o[r] = (f32x4){0.f, 0.f, 0.f, 0.f};
  }
  int kbase = ch * keysPerChunk;
  for (int kt = 0; kt < keysPerChunk; kt += 128){
    for (int i = tid; i < 1024; i += 256){
      int r = i >> 3, c = (i & 7) * 8;
      *(uint4*)&Ks[r][c] = *(const uint4*)(K + (long long)(kbase + kt + r) * ldk + c);
    }
    for (int i = tid; i < 1024; i += 256){
      int r = i >> 4, c = (i & 15) * 8;
      *(uint4*)&Vs[r][c] = *(const uint4*)(V + (long long)r * ldv + kbase + kt + c);
    }
    __syncthreads();
    f32x4 accs[8];
#pragma unroll
    for (int j = 0; j < 8; j++) accs[j] = (f32x4){0.f, 0.f, 0.f, 0.f};
#pragma unroll
    for (int ks2 = 0; ks2 < 2; ks2++){
      bf16x8 af = *(const bf16x8*)&Qs[w * 16 + mrow][ks2 * 32 + q8 * 8];
#pragma unroll
      for (int j = 0; j < 8; j++){
        bf16x8 bfv = *(const bf16x8*)&Ks[j * 16 + mrow][ks2 * 32 + q8 * 8];
        accs[j] = __builtin_amdgcn_mfma_f32_16x16x32_bf16(af, bfv, accs[j], 0, 0, 0);
      }
    }
#pragma unroll
    for (int r = 0; r < 4; r++){
      float tm = -3.0e38f;
#pragma unroll
      for (int j = 0; j < 8; j++) tm = fmaxf(tm, accs[j][r]);
      tm = fmaxf(tm, __shfl_xor(tm, 1, 64));
      tm = fmaxf(tm, __shfl_xor(tm, 2, 64));
      tm = fmaxf(tm, __shfl_xor(tm, 4, 64));
      tm = fmaxf(tm, __shfl_xor(tm, 8, 64));
      float mn = fmaxf(m_st[r], tm);
      float al = __expf(m_st[r] - mn);
      m_st[r] = mn;
      float rs = 0.f;
#pragma unroll
      for (int j = 0; j < 8; j++){
        float e = __expf(accs[j][r] - mn);
        accs[j][r] = e;
        rs += e;
      }
      rs += __shfl_xor(rs, 1, 64);
      rs += __shfl_xor(rs, 2, 64);
      rs += __shfl_xor(rs, 4, 64);
      rs += __shfl_xor(rs, 8, 64);
      l_st[r] = al * l_st[r] + rs;
#pragma unroll
      for (int j = 0; j < 4; j++) acc_o[j][r] *= al;
    }
#pragma unroll
    for (int j = 0; j < 8; j++)
#pragma unroll
      for (int r = 0; r < 4; r++)
        Ps[w][q8 * 4 + r][j * 16 + mrow] = f2b(accs[j][r]);
    __syncthreads();
#pragma unroll
    for (int kc = 0; kc < 4; kc++){
      bf16x8 af = *(const bf16x8*)&Ps[w][mrow][kc * 32 + q8 * 8];
#pragma unroll
      for (int j = 0; j < 4; j++){
        bf16x8 bfv = *(const bf16x8*)&Vs[j * 16 + mrow][kc * 32 + q8 * 8];
        acc_o[j] = __builtin_amdgcn_mfma_f32_16x16x32_bf16(af, bfv, acc_o[j], 0, 0, 0);
      }
    }
    __syncthreads();
  }
  if (mode == 0){
#pragma unroll
    for (int r = 0; r < 4; r++){
      int grow = q0 + w * 16 + q8 * 4 + r;
      float inv = 1.f / l_st[r];
#pragma unroll
      for (int j = 0; j < 4; j++)
        outB[(long long)grow * ldo + h * 64 + j * 16 + mrow] = f2b(acc_o[j][r] * inv);
    }
  } else {
#pragma unroll
    for (int r = 0; r < 4; r++){
      int row = q0 + w * 16 + q8 * 4 + r;
      long long b = ((long long)h * nchunks + ch) * qrows + row;
#pragma unroll
      for (int j = 0; j < 4; j++)
        O3[b * 64 + j * 16 + mrow] = acc_o[j][r];
      if (mrow == 0){
        ML3[b * 2] = m_st[r];
        ML3[b * 2 + 1] = l_st[r];
      }
    }
  }
}

// combine S3 partials
__global__ __launch_bounds__(256) void comb3_k(
    const float* __restrict__ O3, const float* __restrict__ ML3,
    float* __restrict__ a3v)
{
  int h = blockIdx.y;
  int row = blockIdx.x * 4 + (threadIdx.x >> 6);
  int d = threadIdx.x & 63;
  float m = -3.0e38f;
  for (int c = 0; c < 13; c++)
    m = fmaxf(m, ML3[(((long long)h * 13 + c) * 256 + row) * 2]);
  float l = 0.f, o = 0.f;
  for (int c = 0; c < 13; c++){
    long long b = ((long long)h * 13 + c) * 256 + row;
    float wgt = __expf(ML3[b * 2] - m);
    l += wgt * ML3[b * 2 + 1];
    o += wgt * O3[b * 64 + d];
  }
  a3v[((long long)h * 256 + row) * 64 + d] = o / l;
}

// ---------------- layernorm + front-pad -> bf16 xq (NP x 512) --------------
__global__ __launch_bounds__(256) void ln_pad_k(
    const float* __restrict__ h, const float* __restrict__ g,
    const float* __restrict__ b, u16* __restrict__ out)
{
  __shared__ float sm[4];
  int row = blockIdx.x, tid = threadIdx.x;
  u16* o = out + (long long)row * CDIM;
  if (row < PAD){ o[tid] = 0; o[tid + 256] = 0; return; }
  const float* x = h + (long long)(row - PAD) * CDIM;
  float v0 = x[tid], v1 = x[tid + 256];
  float s = bredSum(v0 + v1, sm);
  float s2 = bredSum(v0 * v0 + v1 * v1, sm);
  float mean = s * (1.f / 512.f);
  float var = s2 * (1.f / 512.f) - mean * mean;
  float rstd = rsqrtf(var + 1e-5f);
  o[tid] = f2b((v0 - mean) * rstd * g[tid] + b[tid]);
  o[tid + 256] = f2b((v1 - mean) * rstd * g[tid + 256] + b[tid + 256]);
}

// ---------------- landmark means (vectorized; q pre-scaled by 0.125) -------
// grid(LM/2); block: 2 landmarks x 128 threads; thread covers 8 cols (uint4).
__global__ __launch_bounds__(256) void landmark_k(
    const u16* __restrict__ qkv, float* __restrict__ ql, float* __restrict__ kl,
    u16* __restrict__ qlh, u16* __restrict__ klh)
{
  int m = blockIdx.x * 2 + (threadIdx.x >> 7);
  int c8 = (threadIdx.x & 127) * 8;     // 0..1016, covers q (0-511) + k (512-1023)
  const u16* base = qkv + (long long)(m * LSEG) * 1536 + c8;
  float s[8] = {};
  for (int j = 0; j < LSEG; j++){
    uint4 pk = *(const uint4*)(base + (long long)j * 1536);
    const u16* pv = (const u16*)&pk;
#pragma unroll
    for (int e = 0; e < 8; e++) s[e] += b2f(pv[e]);
  }
#pragma unroll
  for (int e = 0; e < 8; e++){
    int col = c8 + e;
    float v = s[e] * (1.f / 65.f);
    int h = (col & 511) >> 6, d = col & 63;
    int idx = (h * LM + m) * DH + d;
    if (col < 512){ ql[idx] = v; qlh[idx] = f2b(v); }
    else          { kl[idx] = v; klh[idx] = f2b(v); }
  }
}

// ---------------- softmax over rows of 256 (f32 + hi/lo bf16 out) ----------
__global__ __launch_bounds__(256) void softmax256_k(float* __restrict__ S,
    u16* __restrict__ a2h, u16* __restrict__ a2l)
{
  __shared__ float sm[4];
  int i = blockIdx.x, h = blockIdx.y, j = threadIdx.x;
  long long idx = ((long long)h * LM + i) * 256 + j;
  float v = S[idx];
  float m = bredMax(v, sm);
  float e = __expf(v - m);
  float s = bredSum(e, sm);
  float p = e / s;
  S[idx] = p;
  u16 hi = f2b(p);
  a2h[idx] = hi;
  a2l[idx] = f2b(p - b2f(hi));
}

// ---------------- pinv scale factors ----------------
__global__ __launch_bounds__(256) void pinv_scal_k(
    const float* __restrict__ a2, float* __restrict__ scal)
{
  __shared__ float sm[4];
  int h = blockIdx.x, i = threadIdx.x;
  const float* Ah = a2 + (long long)h * 65536;
  float rs = 0.f, cs = 0.f;
  for (int j = 0; j < 256; j++){
    rs += fabsf(Ah[i * 256 + j]);
    cs += fabsf(Ah[j * 256 + i]);
  }
  float rmax = bredMax(rs, sm);
  __syncthreads();
  float cmax = bredMax(cs, sm);
  if (i == 0){
    atomicMax((int*)&scal[0], __float_as_int(rmax));
    atomicMax((int*)&scal[1], __float_as_int(cmax));
  }
}

// z0 = a2^T * inv (hi/lo + transposed hi/lo)
__global__ __launch_bounds__(256) void z0_k(
    const float* __restrict__ a2, const float* __restrict__ scal,
    u16* __restrict__ zh, u16* __restrict__ zl,
    u16* __restrict__ zTh, u16* __restrict__ zTl)
{
  int ri = blockIdx.x, h = blockIdx.y, j = threadIdx.x;
  float inv = 1.f / (scal[0] * scal[1]);
  long long base = ((long long)h * LM + ri) * 256;
  float v = a2[base + j] * inv;
  u16 hi = f2b(v), lo = f2b(v - b2f(hi));
  zTh[base + j] = hi; zTl[base + j] = lo;
  long long tb = ((long long)h * LM + j) * 256 + ri;
  zh[tb] = hi; zl[tb] = lo;
}

// ---------------- depthwise 33-tap residual conv (fully unrolled) ----------
__global__ __launch_bounds__(256) void resconv_k(
    const u16* __restrict__ qkv, const float* __restrict__ rw,
    u16* __restrict__ attn)
{
  int c = blockIdx.x * 256 + threadIdx.x;
  int s0 = blockIdx.y * 8;
  int h = c >> 6;
  float w[33];
#pragma unroll
  for (int t = 0; t < 33; t++) w[t] = rw[h * 33 + t];
  float vr[40];
#pragma unroll
  for (int j = 0; j < 40; j++){
    int s = s0 - 16 + j;
    vr[j] = (s >= 0 && s < NP) ? b2f(qkv[(long long)s * 1536 + 1024 + c]) : 0.f;
  }
#pragma unroll
  for (int i = 0; i < 8; i++){
    float a = 0.f;
#pragma unroll
    for (int t = 0; t < 33; t++) a = fmaf(vr[i + t], w[t], a);
    long long idx = (long long)(s0 + i) * CDIM + c;
    attn[idx] = f2b(b2f(attn[idx]) + a);
  }
}

// ---------------- f32 32x32 transpose ----------------
__global__ __launch_bounds__(256) void transpose_k(
    const float* __restrict__ in, float* __restrict__ out, int R, int Cc)
{
  __shared__ float t[32][33];
  int bx = blockIdx.x * 32, by = blockIdx.y * 32;
  int x = threadIdx.x & 31, y4 = threadIdx.x >> 5;
  for (int yy = y4; yy < 32; yy += 8){
    int r = by + yy, c = bx + x;
    if (r < R && c < Cc) t[yy][x] = in[(long long)r * Cc + c];
  }
  __syncthreads();
  for (int yy = y4; yy < 32; yy += 8){
    int r = bx + yy, c = by + x;
    if (r < Cc && c < R) out[(long long)r * R + c] = t[x][yy];
  }
}

// ---------------- fused PPEG ----------------
__global__ __launch_bounds__(256) void ppeg_k(
    const float* __restrict__ cf, float* __restrict__ yt,
    const float* __restrict__ w7, const float* __restrict__ b7,
    const float* __restrict__ w5, const float* __restrict__ b5,
    const float* __restrict__ w3, const float* __restrict__ b3)
{
  __shared__ float tile[22][23];
  int c = blockIdx.z;
  int ty0 = blockIdx.y * 16, tx0 = blockIdx.x * 16;
  const float* img = cf + (long long)c * 16384;
  for (int i = threadIdx.x; i < 22 * 22; i += 256){
    int yy = i / 22, xx = i - yy * 22;
    int gy = ty0 - 3 + yy, gx = tx0 - 3 + xx;
    tile[yy][xx] = (gy >= 0 && gy < 128 && gx >= 0 && gx < 128) ? img[gy * 128 + gx] : 0.f;
  }
  __syncthreads();
  int lx = threadIdx.x & 15, ly = threadIdx.x >> 4;
  float o = tile[ly + 3][lx + 3] + b7[c] + b5[c] + b3[c];
  const float* W7 = w7 + c * 49;
#pragma unroll
  for (int ky = 0; ky < 7; ky++)
#pragma unroll
    for (int kx = 0; kx < 7; kx++)
      o = fmaf(tile[ly + ky][lx + kx], W7[ky * 7 + kx], o);
  const float* W5 = w5 + c * 25;
#pragma unroll
  for (int ky = 0; ky < 5; ky++)
#pragma unroll
    for (int kx = 0; kx < 5; kx++)
      o = fmaf(tile[ly + 1 + ky][lx + 1 + kx], W5[ky * 5 + kx], o);
  const float* W3 = w3 + c * 9;
#pragma unroll
  for (int ky = 0; ky < 3; ky++)
#pragma unroll
    for (int kx = 0; kx < 3; kx++)
      o = fmaf(tile[ly + 2 + ky][lx + 2 + kx], W3[ky * 3 + kx], o);
  yt[(long long)c * 16384 + (ty0 + ly) * 128 + (tx0 + lx)] = o;
}

// ---------------- final: LN(h[0]) @ fc2 + b ----------------
__global__ __launch_bounds__(256) void final_k(
    const float* __restrict__ h, const float* __restrict__ g,
    const float* __restrict__ b, const float* __restrict__ w,
    const float* __restrict__ bias, float* __restrict__ out)
{
  __shared__ float sm[4];
  __shared__ float pj[256][4];
  int tid = threadIdx.x;
  float v0 = h[tid], v1 = h[tid + 256];
  float s = bredSum(v0 + v1, sm);
  float s2 = bredSum(v0 * v0 + v1 * v1, sm);
  float mean = s * (1.f / 512.f);
  float var = s2 * (1.f / 512.f) - mean * mean;
  float rstd = rsqrtf(var + 1e-5f);
  float n0 = (v0 - mean) * rstd * g[tid] + b[tid];
  float n1 = (v1 - mean) * rstd * g[tid + 256] + b[tid + 256];
#pragma unroll
  for (int j = 0; j < 4; j++)
    pj[tid][j] = n0 * w[tid * 4 + j] + n1 * w[(tid + 256) * 4 + j];
  __syncthreads();
  if (tid < 4){
    float acc = 0.f;
    for (int k = 0; k < 256; k++) acc += pj[k][tid];
    out[tid] = acc + bias[tid];
  }
}

// ===========================================================================
// host side
// ===========================================================================
static inline void gemmbf(hipStream_t st, const u16* A, const u16* B, void* C,
                          int M, int N, int K, int lda, int ldb, int ldc,
                          long long sA, long long sB, long long sC, int batch,
                          const float* bias, const float* rowdiv, int sRow,
                          float alpha, int flags, int ksplit, u16* vt)
{
  dim3 grid((N + 127) / 128, (M + 127) / 128, batch * ksplit);
  gemmbf_k<<<grid, 256, 0, st>>>(A, B, C, M, N, K, lda, ldb, ldc, sA, sB, sC,
                                 bias, rowdiv, sRow, alpha, flags, ksplit, vt);
}

// workspace byte offsets
#define B_H     0LL
#define B_XQ    33556480LL     /* xq; after qkv, hosts pinv hi/lo arrays (16MB) */
#define B_ATTN  50595840LL
#define B_QKV   67635200LL     /* also xb; also cf/yt for PPEG */
#define B_VT    118753280LL
#define B_O3    135792640LL
#define B_ML3   142608384LL
#define B_QL    169871360LL
#define B_KL    170395648LL
#define B_QLH   170919936LL
#define B_KLH   171182080LL
#define B_A2    171444224LL
#define B_PV2   173541376LL    /* tBTh(1M), tBTl(1M), zf f32(2M) */
#define B_A3V   184027136LL
#define B_Z2    184551424LL
#define B_Z2T   185075712LL
#define B_SCAL  185604096LL
#define B_W1T   185604352LL
#define B_WQT   186652928LL
#define B_WOT   188225792LL
#define WS_REQ  188750080LL
#define MB1     1048576LL

extern "C" void kernel_launch(void* const* d_in, const int* in_sizes, int n_in,
                              void* d_out, int out_size, void* d_ws, size_t ws_size,
                              hipStream_t stream)
{
  (void)in_sizes; (void)n_in; (void)out_size;
  if (ws_size < (size_t)WS_REQ) return;

  const float* x      = (const float*)d_in[0];
  const float* fc1_w  = (const float*)d_in[1];
  const float* fc1_b  = (const float*)d_in[2];
  const float* cls    = (const float*)d_in[3];
  const float* l_ng[2]  = {(const float*)d_in[4],  (const float*)d_in[10]};
  const float* l_nb[2]  = {(const float*)d_in[5],  (const float*)d_in[11]};
  const float* l_qkv[2] = {(const float*)d_in[6],  (const float*)d_in[12]};
  const float* l_ow[2]  = {(const float*)d_in[7],  (const float*)d_in[13]};
  const float* l_ob[2]  = {(const float*)d_in[8],  (const float*)d_in[14]};
  const float* l_rw[2]  = {(const float*)d_in[9],  (const float*)d_in[15]};
  const float* w7 = (const float*)d_in[16];
  const float* b7 = (const float*)d_in[17];
  const float* w5 = (const float*)d_in[18];
  const float* b5 = (const float*)d_in[19];
  const float* w3 = (const float*)d_in[20];
  const float* b3 = (const float*)d_in[21];
  const float* norm_g = (const float*)d_in[22];
  const float* norm_b = (const float*)d_in[23];
  const float* fc2_w  = (const float*)d_in[24];
  const float* fc2_b  = (const float*)d_in[25];
  float* out = (float*)d_out;

  char* WB = (char*)d_ws;
  float* h    = (float*)(WB + B_H);
  u16*   xq   = (u16*)(WB + B_XQ);
  u16*   attnb= (u16*)(WB + B_ATTN);
  u16*   qkvb = (u16*)(WB + B_QKV);
  u16*   xb   = (u16*)(WB + B_QKV);
  float* cf   = (float*)(WB + B_QKV);
  float* yt   = (float*)(WB + B_QKV + 33554432LL);
  u16*   vT   = (u16*)(WB + B_VT);
  float* O3   = (float*)(WB + B_O3);
  float* ML3  = (float*)(WB + B_ML3);
  float* ql   = (float*)(WB + B_QL);
  float* kl   = (float*)(WB + B_KL);
  u16*   qlh  = (u16*)(WB + B_QLH);
  u16*   klh  = (u16*)(WB + B_KLH);
  float* a2   = (float*)(WB + B_A2);
  float* a3v  = (float*)(WB + B_A3V);
  float* Z2   = (float*)(WB + B_Z2);
  u16*   Z2T  = (u16*)(WB + B_Z2T);
  float* scal = (float*)(WB + B_SCAL);
  u16*   w1T  = (u16*)(WB + B_W1T);
  u16*   wqT  = (u16*)(WB + B_WQT);
  u16*   woT  = (u16*)(WB + B_WOT);

  u16* a2h  = (u16*)(WB + B_XQ + 0 * MB1);
  u16* a2l  = (u16*)(WB + B_XQ + 1 * MB1);
  u16* z0h  = (u16*)(WB + B_XQ + 2 * MB1);
  u16* z0l  = (u16*)(WB + B_XQ + 3 * MB1);
  u16* z0Th = (u16*)(WB + B_XQ + 4 * MB1);
  u16* z0Tl = (u16*)(WB + B_XQ + 5 * MB1);
  u16* z1h  = (u16*)(WB + B_XQ + 6 * MB1);
  u16* z1l  = (u16*)(WB + B_XQ + 7 * MB1);
  u16* z1Th = (u16*)(WB + B_XQ + 8 * MB1);
  u16* z1Tl = (u16*)(WB + B_XQ + 9 * MB1);
  u16* azh  = (u16*)(WB + B_XQ + 10 * MB1);
  u16* azl  = (u16*)(WB + B_XQ + 11 * MB1);
  u16* azTh = (u16*)(WB + B_XQ + 12 * MB1);
  u16* azTl = (u16*)(WB + B_XQ + 13 * MB1);
  u16* tATh = (u16*)(WB + B_XQ + 14 * MB1);
  u16* tATl = (u16*)(WB + B_XQ + 15 * MB1);
  u16* tBTh = (u16*)(WB + B_PV2 + 0 * MB1);
  u16* tBTl = (u16*)(WB + B_PV2 + 1 * MB1);
  float* zf = (float*)(WB + B_PV2 + 2 * MB1);

  // ---- fc1 ----
  copy_cls_k<<<1, 256, 0, stream>>>(cls, h);
  cvtbf_k<<<4096, 256, 0, stream>>>(x, xb, 16384LL * 1024);
  tcbf_k<<<dim3(16, 32, 1), 256, 0, stream>>>(fc1_w, w1T, 1024, 512, 512, 1024, 0, 0);
  gemmbf(stream, xb, w1T, h + CDIM, 16384, 512, 1024, 1024, 1024, 512,
         0, 0, 0, 1, fc1_b, nullptr, 0, 1.f, GB_RELU, 1, nullptr);

  for (int L = 0; L < 2; L++){
    ln_pad_k<<<NP, 256, 0, stream>>>(h, l_ng[L], l_nb[L], xq);
    tcbf_k<<<dim3(48, 16, 1), 256, 0, stream>>>(l_qkv[L], wqT, 512, 1536, 1536, 512, 0, 0);
    // qkv: bf16 out, q pre-scaled 0.125, v additionally emitted transposed (vT)
    gemmbf(stream, xq, wqT, qkvb, NP, 1536, 512, 512, 512, 1536,
           0, 0, 0, 1, nullptr, nullptr, 0, 1.f, GB_STOREBF | GB_QSCALE, 1, vT);
    landmark_k<<<LM / 2, 256, 0, stream>>>(qkvb, ql, kl, qlh, klh);
    // a2 = softmax(ql @ kl^T): f32 + hi/lo
    gemm_k<<<dim3(4, 4, 8), 256, 0, stream>>>(ql, kl, a2, LM, LM, DH, DH, DH, LM,
                                              16384, 16384, 65536, 1.f, GF_TRANSB);
    softmax256_k<<<dim3(LM, HEADS), 256, 0, stream>>>(a2, a2h, a2l);
    // pinv init
    zero_k<<<1, 256, 0, stream>>>(scal, 2);
    pinv_scal_k<<<HEADS, 256, 0, stream>>>(a2, scal);
    z0_k<<<dim3(LM, HEADS), 256, 0, stream>>>(a2, scal, z0h, z0l, z0Th, z0Tl);
    // 6 Newton-Schulz iterations, hi/lo bf16 MFMA
    u16 *zh = z0h, *zl = z0l, *zTh = z0Th, *zTl = z0Tl;
    u16 *nzh = z1h, *nzl = z1l, *nzTh = z1Th, *nzTl = z1Tl;
    dim3 pg(2, 2, HEADS);
    for (int it = 0; it < 6; it++){
      pinvh_k<<<pg, 256, 0, stream>>>(a2h, a2l, zTh, zTl,
                                      azh, azl, azTh, azTl, nullptr,
                                      nullptr, nullptr, 0.f, 1.f, 0.f);
      pinvh_k<<<pg, 256, 0, stream>>>(azh, azl, azTh, azTl,
                                      nullptr, nullptr, tATh, tATl, nullptr,
                                      azh, azl, 15.f, 1.f, -7.f);
      pinvh_k<<<pg, 256, 0, stream>>>(azh, azl, tATh, tATl,
                                      nullptr, nullptr, tBTh, tBTl, nullptr,
                                      nullptr, nullptr, 13.f, -1.f, 0.f);
      pinvh_k<<<pg, 256, 0, stream>>>(zh, zl, tBTh, tBTl,
                                      nzh, nzl, nzTh, nzTl, zf,
                                      nullptr, nullptr, 0.f, 0.25f, 0.f);
      u16* t;
      t = zh; zh = nzh; nzh = t;   t = zl; zl = nzl; nzl = t;
      t = zTh; zTh = nzTh; nzTh = t; t = zTl; zTl = nzTl; nzTl = t;
    }
    // ---- S3 flash: partials over 13 key chunks, then combine -> a3v ----
    fattn_k<<<dim3(4, 13, 8), 256, 0, stream>>>(
        qlh, 64, qkvb + 512, 1536, vT, NP,
        16384, 64, 64LL * NP, 1280,
        nullptr, 0, O3, ML3, 13, 256, 1);
    comb3_k<<<dim3(64, 8), 256, 0, stream>>>(O3, ML3, a3v);
    // Z2 = pinv(a2) @ a3v (zf f32), then Z2T bf16 per head
    gemm_k<<<dim3(1, 4, 8), 256, 0, stream>>>(zf, a3v, Z2, LM, DH, LM, LM, DH, DH,
                                              65536, 16384, 16384, 1.f, 0);
    tcbf_k<<<dim3(2, 8, 8), 256, 0, stream>>>(Z2, Z2T, 256, 64, 64, 256, 16384, 16384);
    // ---- S1 flash: attn = softmax(q @ kl^T) @ Z2, exact (256 keys) ----
    fattn_k<<<dim3(260, 1, 8), 256, 0, stream>>>(
        qkvb, 1536, klh, 64, Z2T, 256,
        64, 16384, 16384, 256,
        attnb, CDIM, nullptr, nullptr, 1, NP, 0);
    // attn += depthwise 33-tap conv of v
    resconv_k<<<dim3(2, NP / 8), 256, 0, stream>>>(qkvb, l_rw[L], attnb);
    // h += attn[-NT:] @ out_w + out_b
    tcbf_k<<<dim3(16, 16, 1), 256, 0, stream>>>(l_ow[L], woT, 512, 512, 512, 512, 0, 0);
    gemmbf(stream, attnb + (long long)PAD * CDIM, woT, h, NT, CDIM, CDIM,
           CDIM, CDIM, CDIM, 0, 0, 0, 1, l_ob[L], nullptr, 0, 1.f, GB_ACCUM, 1, nullptr);

    if (L == 0){
      transpose_k<<<dim3(16, 512), 256, 0, stream>>>(h + CDIM, cf, 16384, CDIM);
      ppeg_k<<<dim3(8, 8, CDIM), 256, 0, stream>>>(cf, yt, w7, b7, w5, b5, w3, b3);
      transpose_k<<<dim3(512, 16), 256, 0, stream>>>(yt, h + CDIM, CDIM, 16384);
    }
  }

  final_k<<<1, 256, 0, stream>>>(h, norm_g, norm_b, fc2_w, fc2_b, out);
}